// Round 1
// baseline (1150.648 us; speedup 1.0000x reference)
//
#include <hip/hip_runtime.h>

#define N_NODES 10000
#define N_EDGES 160000

typedef float f32x4 __attribute__((ext_vector_type(4)));
typedef short s8v __attribute__((ext_vector_type(8)));

__device__ __forceinline__ unsigned short f2b(float f) {
    unsigned u = __builtin_bit_cast(unsigned, f);
    u += 0x7FFFu + ((u >> 16) & 1u);
    return (unsigned short)(u >> 16);
}
__device__ __forceinline__ float b2f(unsigned short s) {
    unsigned u = ((unsigned)s) << 16;
    return __builtin_bit_cast(float, u);
}

// ---------------- prep: transpose + bf16-convert weight matrices ----------------
// dst[c*K + k] = src[k*Nc + c]
__global__ void k_prep(const float* s0, const float* s1, const float* s2, const float* s3,
                       const float* s4, const float* s5, const float* s6,
                       unsigned short* d0, unsigned short* d1, unsigned short* d2, unsigned short* d3,
                       unsigned short* d4, unsigned short* d5, unsigned short* d6) {
    const float* src; unsigned short* dst; int K, Nc;
    switch (blockIdx.y) {
        case 0: src = s0; dst = d0; K = 1280; Nc = 128; break;
        case 1: src = s1; dst = d1; K = 1280; Nc = 128; break;
        case 2: src = s2; dst = d2; K = 128;  Nc = 128; break;
        case 3: src = s3; dst = d3; K = 128;  Nc = 128; break;
        case 4: src = s4; dst = d4; K = 256;  Nc = 128; break;
        case 5: src = s5; dst = d5; K = 384;  Nc = 128; break;
        default: src = s6; dst = d6; K = 64;  Nc = 640; break;
    }
    int idx = blockIdx.x * 256 + threadIdx.x;
    if (idx < K * Nc) {
        int k = idx / Nc, c = idx - k * Nc;
        dst[c * K + k] = f2b(src[idx]);
    }
}

// ---------------- generic MFMA GEMM: C[row, col] = scale * sum_k A[row,k] * B[k,col] ----------------
struct GemmZ {
    int amode;                 // 0 = strided plain, 1 = tensor-product (S x attr)
    const float* Ap;           // A base (plain) or S base (tp)
    int ars, aks;              // A strides (row, k) ; tp: S strides (row, c)
    const float* attr;         // tp only: [row*10 + a]
    const unsigned short* Bt;  // B^T bf16: [col*K + k]
    float* Cp;                 // C base (offset pre-folded)
    int crs, ccs;              // C strides (row, col)
    int K;
    float scale;
    int M;
};

__global__ __launch_bounds__(256) void k_gemm(GemmZ g0, GemmZ g1, GemmZ g2, GemmZ g3) {
    GemmZ g;
    switch (blockIdx.z) { case 0: g = g0; break; case 1: g = g1; break; case 2: g = g2; break; default: g = g3; }
    __shared__ unsigned short As[64][40];  // 64 rows x 32 k, pad->40 elems (80B stride)
    const int t = threadIdx.x;
    const int wv = t >> 6, lane = t & 63;
    const int lr = lane & 15, lkg = lane >> 4;
    const int row0 = blockIdx.x * 64;
    const int br = t >> 2;            // 0..63 : row this thread stages
    const int bk0 = (t & 3) * 8;      // 0,8,16,24
    const int arow = row0 + br;

    f32x4 acc[8];
#pragma unroll
    for (int i = 0; i < 8; i++) acc[i] = (f32x4){0.f, 0.f, 0.f, 0.f};

    for (int k0 = 0; k0 < g.K; k0 += 32) {
        s8v av;
        if (arow < g.M) {
            if (g.amode == 0) {
#pragma unroll
                for (int j = 0; j < 8; j++)
                    av[j] = (short)f2b(g.Ap[(long)arow * g.ars + (long)(k0 + bk0 + j) * g.aks]);
            } else {
#pragma unroll
                for (int j = 0; j < 8; j++) {
                    int k = k0 + bk0 + j;
                    int c = k / 10, a = k - c * 10;
                    av[j] = (short)f2b(g.Ap[(long)arow * g.ars + c * g.aks] * g.attr[arow * 10 + a]);
                }
            }
        } else {
#pragma unroll
            for (int j = 0; j < 8; j++) av[j] = 0;
        }
        __syncthreads();
        *reinterpret_cast<s8v*>(&As[br][bk0]) = av;
        __syncthreads();
        s8v af = *reinterpret_cast<const s8v*>(&As[wv * 16 + lr][lkg * 8]);
#pragma unroll
        for (int ct = 0; ct < 8; ct++) {
            const unsigned short* bp = g.Bt + (long)(ct * 16 + lr) * g.K + k0 + lkg * 8;
            s8v bf = *reinterpret_cast<const s8v*>(bp);
            acc[ct] = __builtin_amdgcn_mfma_f32_16x16x32_bf16(af, bf, acc[ct], 0, 0, 0);
        }
    }
#pragma unroll
    for (int ct = 0; ct < 8; ct++) {
#pragma unroll
        for (int r = 0; r < 4; r++) {
            int row = row0 + wv * 16 + lkg * 4 + r;
            if (row < g.M) {
                int col = ct * 16 + lr;
                g.Cp[(long)row * g.crs + col * g.ccs] = acc[ct][r] * g.scale;
            }
        }
    }
}

// ---------------- MLP layers 0..2 (E x 8 -> 64 -> 64 -> 64), VALU in LDS ----------------
__global__ __launch_bounds__(256) void k_mlp012(const float* __restrict__ ef, const float* __restrict__ w0,
                                                const float* __restrict__ w1, const float* __restrict__ w2,
                                                unsigned short* __restrict__ h2out) {
    __shared__ float efs[64][8];
    __shared__ float ha[64][64];
    __shared__ float hb[64][64];
    __shared__ float wl[64][64];
    __shared__ float w0l[8][64];
    const int t = threadIdx.x;
    const long e0 = (long)blockIdx.x * 64;
#pragma unroll
    for (int j = 0; j < 2; j++) { int idx = t + j * 256; ((float*)efs)[idx] = ef[e0 * 8 + idx]; }
#pragma unroll
    for (int j = 0; j < 2; j++) { int idx = t + j * 256; ((float*)w0l)[idx] = w0[idx]; }
#pragma unroll
    for (int j = 0; j < 16; j++) { int idx = t + j * 256; ((float*)wl)[idx] = w1[idx]; }
    __syncthreads();
    const int o = t & 63, ebase = t >> 6;
#pragma unroll
    for (int j = 0; j < 16; j++) {
        int e = ebase * 16 + j;
        float acc = 0.f;
#pragma unroll
        for (int k = 0; k < 8; k++) acc += efs[e][k] * w0l[k][o];
        acc *= 0.35355339059f;  // 1/sqrt(8)
        ha[e][o] = acc / (1.f + __expf(-acc));
    }
    __syncthreads();
#pragma unroll
    for (int j = 0; j < 16; j++) {
        int e = ebase * 16 + j;
        float acc = 0.f;
        for (int k = 0; k < 64; k++) acc += ha[e][k] * wl[k][o];
        acc *= 0.125f;          // 1/sqrt(64)
        hb[e][o] = acc / (1.f + __expf(-acc));
    }
    __syncthreads();
#pragma unroll
    for (int j = 0; j < 16; j++) { int idx = t + j * 256; ((float*)wl)[idx] = w2[idx]; }
    __syncthreads();
#pragma unroll
    for (int j = 0; j < 16; j++) {
        int e = ebase * 16 + j;
        float acc = 0.f;
        for (int k = 0; k < 64; k++) acc += hb[e][k] * wl[k][o];
        acc *= 0.125f;
        float h = acc / (1.f + __expf(-acc));
        h2out[(e0 + e) * 64 + o] = f2b(h);
    }
}

// ---------------- per-edge: last MLP layer (MFMA) + message formation + atomic scatter ----------------
__global__ __launch_bounds__(256) void k_edge(const unsigned short* __restrict__ h2,
                                              const unsigned short* __restrict__ w3T,
                                              const float* __restrict__ eattr,
                                              const int* __restrict__ snd, const int* __restrict__ rcv,
                                              const float* __restrict__ xs, const float* __restrict__ xv,
                                              float* __restrict__ msg_s, float* __restrict__ msg_v) {
    __shared__ unsigned short h2s[32][72];    // pad 64 -> 72
    __shared__ unsigned short tpw[32][644];   // pad 640 -> 644
    __shared__ float es_l[32];
    __shared__ float ev_l[32][3];
    __shared__ int sn_l[32], rc_l[32];
    const int t = threadIdx.x;
    const int e0 = blockIdx.x * 32;
    {
        int r = t >> 3, kk = (t & 7) * 8;
        s8v v = *reinterpret_cast<const s8v*>(h2 + (long)(e0 + r) * 64 + kk);
        *reinterpret_cast<s8v*>(&h2s[r][kk]) = v;
    }
    if (t < 32) {
        es_l[t] = eattr[(e0 + t) * 4 + 0];
        ev_l[t][0] = eattr[(e0 + t) * 4 + 1];
        ev_l[t][1] = eattr[(e0 + t) * 4 + 2];
        ev_l[t][2] = eattr[(e0 + t) * 4 + 3];
        sn_l[t] = snd[e0 + t];
        rc_l[t] = rcv[e0 + t];
    }
    __syncthreads();
    const int wv = t >> 6, lane = t & 63, lr = lane & 15, lkg = lane >> 4;
#pragma unroll
    for (int p = 0; p < 20; p++) {
        int ct = wv + 4 * (p % 10);
        int rt = p / 10;
        f32x4 acc = (f32x4){0.f, 0.f, 0.f, 0.f};
#pragma unroll
        for (int ks = 0; ks < 2; ks++) {
            s8v a = *reinterpret_cast<const s8v*>(&h2s[rt * 16 + lr][ks * 32 + lkg * 8]);
            s8v b = *reinterpret_cast<const s8v*>(w3T + (long)(ct * 16 + lr) * 64 + ks * 32 + lkg * 8);
            acc = __builtin_amdgcn_mfma_f32_16x16x32_bf16(a, b, acc, 0, 0, 0);
        }
#pragma unroll
        for (int r = 0; r < 4; r++)
            tpw[rt * 16 + lkg * 4 + r][ct * 16 + lr] = f2b(acc[r] * 0.125f);
    }
    __syncthreads();
    const int c = t & 127, eb = t >> 7;
#pragma unroll 4
    for (int it = 0; it < 16; it++) {
        int e = eb + 2 * it;
        int s = sn_l[e], rc = rc_l[e];
        float es = es_l[e], ev0 = ev_l[e][0], ev1 = ev_l[e][1], ev2 = ev_l[e][2];
        float w1 = b2f(tpw[e][c]);
        float w2 = b2f(tpw[e][128 + c]);
        float w3 = b2f(tpw[e][256 + c]);
        float w4 = b2f(tpw[e][384 + c]);
        float w5 = b2f(tpw[e][512 + c]);
        float xsv = xs[s * 128 + c];
        float x0 = xv[s * 384 + c], x1 = xv[s * 384 + 128 + c], x2 = xv[s * 384 + 256 + c];
        float m0a = w1 * xsv * es;
        float dve = x0 * ev0 + x1 * ev1 + x2 * ev2;
        float m0b = w4 * dve * 0.57735026919f;   // 1/sqrt(3)
        float a2 = w2 * xsv;
        float cr0 = x1 * ev2 - x2 * ev1;
        float cr1 = x2 * ev0 - x0 * ev2;
        float cr2 = x0 * ev1 - x1 * ev0;
        float* ms = msg_s + (long)rc * 256 + c;
        unsafeAtomicAdd(ms, m0a);
        unsafeAtomicAdd(ms + 128, m0b);
        float* mv = msg_v + (long)rc * 1152 + c;
        unsafeAtomicAdd(mv + 0,    a2 * ev0);
        unsafeAtomicAdd(mv + 128,  w3 * x0 * es);
        unsafeAtomicAdd(mv + 256,  w5 * cr0 * 0.70710678119f);
        unsafeAtomicAdd(mv + 384,  a2 * ev1);
        unsafeAtomicAdd(mv + 512,  w3 * x1 * es);
        unsafeAtomicAdd(mv + 640,  w5 * cr1 * 0.70710678119f);
        unsafeAtomicAdd(mv + 768,  a2 * ev2);
        unsafeAtomicAdd(mv + 896,  w3 * x2 * es);
        unsafeAtomicAdd(mv + 1024, w5 * cr2 * 0.70710678119f);
    }
}

extern "C" void kernel_launch(void* const* d_in, const int* in_sizes, int n_in,
                              void* d_out, int out_size, void* d_ws, size_t ws_size,
                              hipStream_t stream) {
    const float* node_attrs = (const float*)d_in[0];
    const float* nfs        = (const float*)d_in[1];
    const float* nfv        = (const float*)d_in[2];
    const float* edge_attrs = (const float*)d_in[3];
    const float* edge_feats = (const float*)d_in[4];
    const float* W_sc_s     = (const float*)d_in[5];
    const float* W_sc_v     = (const float*)d_in[6];
    const float* W_lin_s    = (const float*)d_in[7];
    const float* W_lin_v    = (const float*)d_in[8];
    const float* mlp_w0     = (const float*)d_in[9];
    const float* mlp_w1     = (const float*)d_in[10];
    const float* mlp_w2     = (const float*)d_in[11];
    const float* mlp_w3     = (const float*)d_in[12];
    const float* W_out_s    = (const float*)d_in[13];
    const float* W_out_v    = (const float*)d_in[14];
    const int* senders      = (const int*)d_in[15];
    const int* receivers    = (const int*)d_in[16];
    float* dout = (float*)d_out;

    char* W = (char*)d_ws;
    float* xs_ws   = (float*)(W + 0);          // N*128 f32  = 5,120,000 B
    float* xv_ws   = (float*)(W + 5120000);    // N*3*128    = 15,360,000 B   [n][i][c]
    float* msgs_ws = (float*)(W + 20480000);   // N*256      = 10,240,000 B
    float* msgv_ws = (float*)(W + 30720000);   // N*3*384    = 46,080,000 B   [n][i][k]
    unsigned short* h2_ws   = (unsigned short*)(W + 76800000);  // E*64 bf16 = 20,480,000 B
    unsigned short* wsc_sT  = (unsigned short*)(W + 97280000);  // 128x1280
    unsigned short* wsc_vT  = (unsigned short*)(W + 97607680);  // 128x1280
    unsigned short* wlin_sT = (unsigned short*)(W + 97935360);  // 128x128
    unsigned short* wlin_vT = (unsigned short*)(W + 97968128);  // 128x128
    unsigned short* wout_sT = (unsigned short*)(W + 98000896);  // 128x256
    unsigned short* wout_vT = (unsigned short*)(W + 98066432);  // 128x384
    unsigned short* w3T     = (unsigned short*)(W + 98164736);  // 640x64

    const float inv1280 = 0.02795084972f;  // 1/sqrt(1280)
    const float inv128  = 0.08838834765f;  // 1/sqrt(128)
    const float scO_s   = 1.f / 256.f;                 // 1/sqrt(256)/16
    const float scO_v   = 1.f / (19.5959179423f * 16.f); // 1/sqrt(384)/16

    k_prep<<<dim3(640, 7, 1), 256, 0, stream>>>(W_sc_s, W_sc_v, W_lin_s, W_lin_v, W_out_s, W_out_v, mlp_w3,
                                                wsc_sT, wsc_vT, wlin_sT, wlin_vT, wout_sT, wout_vT, w3T);
    hipMemsetAsync(msgs_ws, 0, 56320000, stream);  // msg_s + msg_v
    k_mlp012<<<dim3(2500), 256, 0, stream>>>(edge_feats, mlp_w0, mlp_w1, mlp_w2, h2_ws);

    // sc = tp @ W_sc * inv  -> d_out second half
    {
        GemmZ g0{1, nfs,     128, 1, node_attrs, wsc_sT, dout + 5120000,           512, 1, 1280, inv1280, N_NODES};
        GemmZ g1{1, nfv + 0, 384, 3, node_attrs, wsc_vT, dout + 5120000 + 128 + 0, 512, 3, 1280, inv1280, N_NODES};
        GemmZ g2{1, nfv + 1, 384, 3, node_attrs, wsc_vT, dout + 5120000 + 128 + 1, 512, 3, 1280, inv1280, N_NODES};
        GemmZ g3{1, nfv + 2, 384, 3, node_attrs, wsc_vT, dout + 5120000 + 128 + 2, 512, 3, 1280, inv1280, N_NODES};
        k_gemm<<<dim3(157, 1, 4), 256, 0, stream>>>(g0, g1, g2, g3);
    }
    // x_s / x_v -> ws
    {
        GemmZ g0{0, nfs,     128, 1, nullptr, wlin_sT, xs_ws,       128, 1, 128, inv128, N_NODES};
        GemmZ g1{0, nfv + 0, 384, 3, nullptr, wlin_vT, xv_ws + 0,   384, 1, 128, inv128, N_NODES};
        GemmZ g2{0, nfv + 1, 384, 3, nullptr, wlin_vT, xv_ws + 128, 384, 1, 128, inv128, N_NODES};
        GemmZ g3{0, nfv + 2, 384, 3, nullptr, wlin_vT, xv_ws + 256, 384, 1, 128, inv128, N_NODES};
        k_gemm<<<dim3(157, 1, 4), 256, 0, stream>>>(g0, g1, g2, g3);
    }
    // edge messages + scatter
    k_edge<<<dim3(5000), 256, 0, stream>>>(h2_ws, w3T, edge_attrs, senders, receivers,
                                           xs_ws, xv_ws, msgs_ws, msgv_ws);
    // out = msg @ W_out -> d_out first half
    {
        GemmZ g0{0, msgs_ws,       256,  1, nullptr, wout_sT, dout,           512, 1, 256, scO_s, N_NODES};
        GemmZ g1{0, msgv_ws + 0,   1152, 1, nullptr, wout_vT, dout + 128 + 0, 512, 3, 384, scO_v, N_NODES};
        GemmZ g2{0, msgv_ws + 384, 1152, 1, nullptr, wout_vT, dout + 128 + 1, 512, 3, 384, scO_v, N_NODES};
        GemmZ g3{0, msgv_ws + 768, 1152, 1, nullptr, wout_vT, dout + 128 + 2, 512, 3, 384, scO_v, N_NODES};
        k_gemm<<<dim3(157, 1, 4), 256, 0, stream>>>(g0, g1, g2, g3);
    }
}

// Round 2
// 1144.708 us; speedup vs baseline: 1.0052x; 1.0052x over previous
//
#include <hip/hip_runtime.h>

#define N_NODES 10000
#define N_EDGES 160000

typedef float f32x4 __attribute__((ext_vector_type(4)));
typedef short s8v __attribute__((ext_vector_type(8)));

__device__ __forceinline__ unsigned short f2b(float f) {
    unsigned u = __builtin_bit_cast(unsigned, f);
    u += 0x7FFFu + ((u >> 16) & 1u);
    return (unsigned short)(u >> 16);
}
__device__ __forceinline__ float b2f(unsigned short s) {
    unsigned u = ((unsigned)s) << 16;
    return __builtin_bit_cast(float, u);
}

// ---------------- prep: transpose + bf16-convert weight matrices ----------------
__global__ void k_prep(const float* s0, const float* s1, const float* s2, const float* s3,
                       const float* s4, const float* s5, const float* s6,
                       unsigned short* d0, unsigned short* d1, unsigned short* d2, unsigned short* d3,
                       unsigned short* d4, unsigned short* d5, unsigned short* d6) {
    const float* src; unsigned short* dst; int K, Nc;
    switch (blockIdx.y) {
        case 0: src = s0; dst = d0; K = 1280; Nc = 128; break;
        case 1: src = s1; dst = d1; K = 1280; Nc = 128; break;
        case 2: src = s2; dst = d2; K = 128;  Nc = 128; break;
        case 3: src = s3; dst = d3; K = 128;  Nc = 128; break;
        case 4: src = s4; dst = d4; K = 256;  Nc = 128; break;
        case 5: src = s5; dst = d5; K = 384;  Nc = 128; break;
        default: src = s6; dst = d6; K = 64;  Nc = 640; break;
    }
    int idx = blockIdx.x * 256 + threadIdx.x;
    if (idx < K * Nc) {
        int k = idx / Nc, c = idx - k * Nc;
        dst[c * K + k] = f2b(src[idx]);
    }
}

// ---------------- generic MFMA GEMM ----------------
struct GemmZ {
    int amode;
    const float* Ap;
    int ars, aks;
    const float* attr;
    const unsigned short* Bt;
    float* Cp;
    int crs, ccs;
    int K;
    float scale;
    int M;
};

__global__ __launch_bounds__(256) void k_gemm(GemmZ g0, GemmZ g1, GemmZ g2, GemmZ g3) {
    GemmZ g;
    switch (blockIdx.z) { case 0: g = g0; break; case 1: g = g1; break; case 2: g = g2; break; default: g = g3; }
    __shared__ unsigned short As[64][40];
    const int t = threadIdx.x;
    const int wv = t >> 6, lane = t & 63;
    const int lr = lane & 15, lkg = lane >> 4;
    const int row0 = blockIdx.x * 64;
    const int br = t >> 2;
    const int bk0 = (t & 3) * 8;
    const int arow = row0 + br;

    f32x4 acc[8];
#pragma unroll
    for (int i = 0; i < 8; i++) acc[i] = (f32x4){0.f, 0.f, 0.f, 0.f};

    for (int k0 = 0; k0 < g.K; k0 += 32) {
        s8v av;
        if (arow < g.M) {
            if (g.amode == 0) {
#pragma unroll
                for (int j = 0; j < 8; j++)
                    av[j] = (short)f2b(g.Ap[(long)arow * g.ars + (long)(k0 + bk0 + j) * g.aks]);
            } else {
#pragma unroll
                for (int j = 0; j < 8; j++) {
                    int k = k0 + bk0 + j;
                    int c = k / 10, a = k - c * 10;
                    av[j] = (short)f2b(g.Ap[(long)arow * g.ars + c * g.aks] * g.attr[arow * 10 + a]);
                }
            }
        } else {
#pragma unroll
            for (int j = 0; j < 8; j++) av[j] = 0;
        }
        __syncthreads();
        *reinterpret_cast<s8v*>(&As[br][bk0]) = av;
        __syncthreads();
        s8v af = *reinterpret_cast<const s8v*>(&As[wv * 16 + lr][lkg * 8]);
#pragma unroll
        for (int ct = 0; ct < 8; ct++) {
            const unsigned short* bp = g.Bt + (long)(ct * 16 + lr) * g.K + k0 + lkg * 8;
            s8v bf = *reinterpret_cast<const s8v*>(bp);
            acc[ct] = __builtin_amdgcn_mfma_f32_16x16x32_bf16(af, bf, acc[ct], 0, 0, 0);
        }
    }
#pragma unroll
    for (int ct = 0; ct < 8; ct++) {
#pragma unroll
        for (int r = 0; r < 4; r++) {
            int row = row0 + wv * 16 + lkg * 4 + r;
            if (row < g.M) {
                int col = ct * 16 + lr;
                g.Cp[(long)row * g.crs + col * g.ccs] = acc[ct][r] * g.scale;
            }
        }
    }
}

// ---------------- MLP layers 0..2 ----------------
__global__ __launch_bounds__(256) void k_mlp012(const float* __restrict__ ef, const float* __restrict__ w0,
                                                const float* __restrict__ w1, const float* __restrict__ w2,
                                                unsigned short* __restrict__ h2out) {
    __shared__ float efs[64][8];
    __shared__ float ha[64][64];
    __shared__ float hb[64][64];
    __shared__ float wl[64][64];
    __shared__ float w0l[8][64];
    const int t = threadIdx.x;
    const long e0 = (long)blockIdx.x * 64;
#pragma unroll
    for (int j = 0; j < 2; j++) { int idx = t + j * 256; ((float*)efs)[idx] = ef[e0 * 8 + idx]; }
#pragma unroll
    for (int j = 0; j < 2; j++) { int idx = t + j * 256; ((float*)w0l)[idx] = w0[idx]; }
#pragma unroll
    for (int j = 0; j < 16; j++) { int idx = t + j * 256; ((float*)wl)[idx] = w1[idx]; }
    __syncthreads();
    const int o = t & 63, ebase = t >> 6;
#pragma unroll
    for (int j = 0; j < 16; j++) {
        int e = ebase * 16 + j;
        float acc = 0.f;
#pragma unroll
        for (int k = 0; k < 8; k++) acc += efs[e][k] * w0l[k][o];
        acc *= 0.35355339059f;
        ha[e][o] = acc / (1.f + __expf(-acc));
    }
    __syncthreads();
#pragma unroll
    for (int j = 0; j < 16; j++) {
        int e = ebase * 16 + j;
        float acc = 0.f;
        for (int k = 0; k < 64; k++) acc += ha[e][k] * wl[k][o];
        acc *= 0.125f;
        hb[e][o] = acc / (1.f + __expf(-acc));
    }
    __syncthreads();
#pragma unroll
    for (int j = 0; j < 16; j++) { int idx = t + j * 256; ((float*)wl)[idx] = w2[idx]; }
    __syncthreads();
#pragma unroll
    for (int j = 0; j < 16; j++) {
        int e = ebase * 16 + j;
        float acc = 0.f;
        for (int k = 0; k < 64; k++) acc += hb[e][k] * wl[k][o];
        acc *= 0.125f;
        float h = acc / (1.f + __expf(-acc));
        h2out[(e0 + e) * 64 + o] = f2b(h);
    }
}

// ---------------- tpw = (h2 @ w3)/8 : E x 640 bf16, MFMA ----------------
__global__ __launch_bounds__(256) void k_tpw(const unsigned short* __restrict__ h2,
                                             const unsigned short* __restrict__ w3T,
                                             unsigned short* __restrict__ tpw) {
    __shared__ unsigned short cs[64][132];
    const int t = threadIdx.x;
    const int wv = t >> 6, lane = t & 63, lr = lane & 15, lkg = lane >> 4;
    const long e0 = (long)blockIdx.x * 64;
    s8v a0 = *reinterpret_cast<const s8v*>(h2 + (e0 + wv * 16 + lr) * 64 + lkg * 8);
    s8v a1 = *reinterpret_cast<const s8v*>(h2 + (e0 + wv * 16 + lr) * 64 + 32 + lkg * 8);
#pragma unroll
    for (int ch = 0; ch < 5; ch++) {
        f32x4 acc[8];
#pragma unroll
        for (int i = 0; i < 8; i++) acc[i] = (f32x4){0.f, 0.f, 0.f, 0.f};
#pragma unroll
        for (int ct = 0; ct < 8; ct++) {
            long col = ch * 128 + ct * 16 + lr;
            s8v b0 = *reinterpret_cast<const s8v*>(w3T + col * 64 + lkg * 8);
            s8v b1 = *reinterpret_cast<const s8v*>(w3T + col * 64 + 32 + lkg * 8);
            acc[ct] = __builtin_amdgcn_mfma_f32_16x16x32_bf16(a0, b0, acc[ct], 0, 0, 0);
            acc[ct] = __builtin_amdgcn_mfma_f32_16x16x32_bf16(a1, b1, acc[ct], 0, 0, 0);
        }
        if (ch) __syncthreads();
#pragma unroll
        for (int ct = 0; ct < 8; ct++)
#pragma unroll
            for (int r = 0; r < 4; r++)
                cs[wv * 16 + lkg * 4 + r][ct * 16 + lr] = f2b(acc[ct][r] * 0.125f);
        __syncthreads();
        int row = t >> 2, c0 = (t & 3) * 32;
#pragma unroll
        for (int j = 0; j < 4; j++) {
            s8v v = *reinterpret_cast<const s8v*>(&cs[row][c0 + j * 8]);
            *reinterpret_cast<s8v*>(tpw + (e0 + row) * 640 + ch * 128 + c0 + j * 8) = v;
        }
    }
}

// ---------------- CSR build ----------------
__global__ void k_hist(const int* __restrict__ rcv, int* __restrict__ cnt) {
    int e = blockIdx.x * 256 + threadIdx.x;
    if (e < N_EDGES) atomicAdd(&cnt[rcv[e]], 1);
}

__global__ __launch_bounds__(256) void k_scan(const int* __restrict__ cnt, int* __restrict__ base, int* __restrict__ cur) {
    __shared__ int s[256];
    const int t = threadIdx.x;
    const int c0 = t * 40;
    int sum = 0;
    for (int i = 0; i < 40; i++) sum += cnt[c0 + i];
    s[t] = sum;
    __syncthreads();
    for (int off = 1; off < 256; off <<= 1) {
        int v = (t >= off) ? s[t - off] : 0;
        __syncthreads();
        s[t] += v;
        __syncthreads();
    }
    int run = t ? s[t - 1] : 0;
    for (int i = 0; i < 40; i++) {
        int idx = c0 + i;
        if (idx <= N_NODES) { base[idx] = run; cur[idx] = run; }
        run += cnt[idx];
    }
}

__global__ void k_scatter(const int* __restrict__ rcv, int* __restrict__ cur, int* __restrict__ order) {
    int e = blockIdx.x * 256 + threadIdx.x;
    if (e < N_EDGES) {
        int p = atomicAdd(&cur[rcv[e]], 1);
        order[p] = e;
    }
}

// ---------------- CSR accumulate: no atomics ----------------
__global__ __launch_bounds__(256) void k_accum(const unsigned short* __restrict__ tpw,
                                               const float* __restrict__ eattr,
                                               const int* __restrict__ snd,
                                               const int* __restrict__ order,
                                               const int* __restrict__ base,
                                               const float* __restrict__ xs, const float* __restrict__ xv,
                                               float* __restrict__ msg_s, float* __restrict__ msg_v) {
    const int t = threadIdx.x;
    const int half = t >> 7;
    const int c = t & 127;
    const int n = blockIdx.x * 2 + half;
    const int b0 = base[n], b1 = base[n + 1];
    float a_s0 = 0.f, a_s1 = 0.f;
    float av0 = 0.f, av1 = 0.f, av2 = 0.f, av3 = 0.f, av4 = 0.f, av5 = 0.f, av6 = 0.f, av7 = 0.f, av8 = 0.f;
#pragma unroll 2
    for (int j = b0; j < b1; j++) {
        int e = order[j];
        int s = snd[e];
        float es = eattr[e * 4 + 0], ev0 = eattr[e * 4 + 1], ev1 = eattr[e * 4 + 2], ev2 = eattr[e * 4 + 3];
        const unsigned short* tp = tpw + (long)e * 640 + c;
        float w1 = b2f(tp[0]), w2 = b2f(tp[128]), w3 = b2f(tp[256]), w4 = b2f(tp[384]), w5 = b2f(tp[512]);
        float xsv = xs[s * 128 + c];
        float x0 = xv[s * 384 + c], x1 = xv[s * 384 + 128 + c], x2 = xv[s * 384 + 256 + c];
        a_s0 += w1 * xsv * es;
        float dve = x0 * ev0 + x1 * ev1 + x2 * ev2;
        a_s1 += w4 * dve * 0.57735026919f;
        float a2 = w2 * xsv;
        av0 += a2 * ev0;
        av1 += w3 * x0 * es;
        av2 += w5 * (x1 * ev2 - x2 * ev1) * 0.70710678119f;
        av3 += a2 * ev1;
        av4 += w3 * x1 * es;
        av5 += w5 * (x2 * ev0 - x0 * ev2) * 0.70710678119f;
        av6 += a2 * ev2;
        av7 += w3 * x2 * es;
        av8 += w5 * (x0 * ev1 - x1 * ev0) * 0.70710678119f;
    }
    msg_s[(long)n * 256 + c] = a_s0;
    msg_s[(long)n * 256 + 128 + c] = a_s1;
    float* mv = msg_v + (long)n * 1152 + c;
    mv[0] = av0; mv[128] = av1; mv[256] = av2;
    mv[384] = av3; mv[512] = av4; mv[640] = av5;
    mv[768] = av6; mv[896] = av7; mv[1024] = av8;
}

// ---------------- fallback: atomic per-edge (old path) ----------------
__global__ __launch_bounds__(256) void k_edge(const unsigned short* __restrict__ h2,
                                              const unsigned short* __restrict__ w3T,
                                              const float* __restrict__ eattr,
                                              const int* __restrict__ snd, const int* __restrict__ rcv,
                                              const float* __restrict__ xs, const float* __restrict__ xv,
                                              float* __restrict__ msg_s, float* __restrict__ msg_v) {
    __shared__ unsigned short h2s[32][72];
    __shared__ unsigned short tpw[32][644];
    __shared__ float es_l[32];
    __shared__ float ev_l[32][3];
    __shared__ int sn_l[32], rc_l[32];
    const int t = threadIdx.x;
    const int e0 = blockIdx.x * 32;
    {
        int r = t >> 3, kk = (t & 7) * 8;
        s8v v = *reinterpret_cast<const s8v*>(h2 + (long)(e0 + r) * 64 + kk);
        *reinterpret_cast<s8v*>(&h2s[r][kk]) = v;
    }
    if (t < 32) {
        es_l[t] = eattr[(e0 + t) * 4 + 0];
        ev_l[t][0] = eattr[(e0 + t) * 4 + 1];
        ev_l[t][1] = eattr[(e0 + t) * 4 + 2];
        ev_l[t][2] = eattr[(e0 + t) * 4 + 3];
        sn_l[t] = snd[e0 + t];
        rc_l[t] = rcv[e0 + t];
    }
    __syncthreads();
    const int wv = t >> 6, lane = t & 63, lr = lane & 15, lkg = lane >> 4;
#pragma unroll
    for (int p = 0; p < 20; p++) {
        int ct = wv + 4 * (p % 10);
        int rt = p / 10;
        f32x4 acc = (f32x4){0.f, 0.f, 0.f, 0.f};
#pragma unroll
        for (int ks = 0; ks < 2; ks++) {
            s8v a = *reinterpret_cast<const s8v*>(&h2s[rt * 16 + lr][ks * 32 + lkg * 8]);
            s8v b = *reinterpret_cast<const s8v*>(w3T + (long)(ct * 16 + lr) * 64 + ks * 32 + lkg * 8);
            acc = __builtin_amdgcn_mfma_f32_16x16x32_bf16(a, b, acc, 0, 0, 0);
        }
#pragma unroll
        for (int r = 0; r < 4; r++)
            tpw[rt * 16 + lkg * 4 + r][ct * 16 + lr] = f2b(acc[r] * 0.125f);
    }
    __syncthreads();
    const int c = t & 127, eb = t >> 7;
#pragma unroll 4
    for (int it = 0; it < 16; it++) {
        int e = eb + 2 * it;
        int s = sn_l[e], rc = rc_l[e];
        float es = es_l[e], ev0 = ev_l[e][0], ev1 = ev_l[e][1], ev2 = ev_l[e][2];
        float w1 = b2f(tpw[e][c]);
        float w2 = b2f(tpw[e][128 + c]);
        float w3 = b2f(tpw[e][256 + c]);
        float w4 = b2f(tpw[e][384 + c]);
        float w5 = b2f(tpw[e][512 + c]);
        float xsv = xs[s * 128 + c];
        float x0 = xv[s * 384 + c], x1 = xv[s * 384 + 128 + c], x2 = xv[s * 384 + 256 + c];
        float m0a = w1 * xsv * es;
        float dve = x0 * ev0 + x1 * ev1 + x2 * ev2;
        float m0b = w4 * dve * 0.57735026919f;
        float a2 = w2 * xsv;
        float cr0 = x1 * ev2 - x2 * ev1;
        float cr1 = x2 * ev0 - x0 * ev2;
        float cr2 = x0 * ev1 - x1 * ev0;
        float* ms = msg_s + (long)rc * 256 + c;
        unsafeAtomicAdd(ms, m0a);
        unsafeAtomicAdd(ms + 128, m0b);
        float* mv = msg_v + (long)rc * 1152 + c;
        unsafeAtomicAdd(mv + 0, a2 * ev0);
        unsafeAtomicAdd(mv + 128, w3 * x0 * es);
        unsafeAtomicAdd(mv + 256, w5 * cr0 * 0.70710678119f);
        unsafeAtomicAdd(mv + 384, a2 * ev1);
        unsafeAtomicAdd(mv + 512, w3 * x1 * es);
        unsafeAtomicAdd(mv + 640, w5 * cr1 * 0.70710678119f);
        unsafeAtomicAdd(mv + 768, a2 * ev2);
        unsafeAtomicAdd(mv + 896, w3 * x2 * es);
        unsafeAtomicAdd(mv + 1024, w5 * cr2 * 0.70710678119f);
    }
}

extern "C" void kernel_launch(void* const* d_in, const int* in_sizes, int n_in,
                              void* d_out, int out_size, void* d_ws, size_t ws_size,
                              hipStream_t stream) {
    const float* node_attrs = (const float*)d_in[0];
    const float* nfs        = (const float*)d_in[1];
    const float* nfv        = (const float*)d_in[2];
    const float* edge_attrs = (const float*)d_in[3];
    const float* edge_feats = (const float*)d_in[4];
    const float* W_sc_s     = (const float*)d_in[5];
    const float* W_sc_v     = (const float*)d_in[6];
    const float* W_lin_s    = (const float*)d_in[7];
    const float* W_lin_v    = (const float*)d_in[8];
    const float* mlp_w0     = (const float*)d_in[9];
    const float* mlp_w1     = (const float*)d_in[10];
    const float* mlp_w2     = (const float*)d_in[11];
    const float* mlp_w3     = (const float*)d_in[12];
    const float* W_out_s    = (const float*)d_in[13];
    const float* W_out_v    = (const float*)d_in[14];
    const int* senders      = (const int*)d_in[15];
    const int* receivers    = (const int*)d_in[16];
    float* dout = (float*)d_out;

    char* W = (char*)d_ws;
    float* xs_ws   = (float*)(W + 0);          // 5,120,000
    float* xv_ws   = (float*)(W + 5120000);    // 15,360,000
    float* msgs_ws = (float*)(W + 20480000);   // 10,240,000
    float* msgv_ws = (float*)(W + 30720000);   // 46,080,000
    unsigned short* h2_ws   = (unsigned short*)(W + 76800000);  // 20,480,000
    unsigned short* wsc_sT  = (unsigned short*)(W + 97280000);
    unsigned short* wsc_vT  = (unsigned short*)(W + 97607680);
    unsigned short* wlin_sT = (unsigned short*)(W + 97935360);
    unsigned short* wlin_vT = (unsigned short*)(W + 97968128);
    unsigned short* wout_sT = (unsigned short*)(W + 98000896);
    unsigned short* wout_vT = (unsigned short*)(W + 98066432);
    unsigned short* w3T     = (unsigned short*)(W + 98164736);  // ends 98,246,656
    int* cnt_ws  = (int*)(W + 98246656);   // 40,960 (10240 ints)
    int* base_ws = (int*)(W + 98287616);   // 40,960 (10001 used)
    int* cur_ws  = (int*)(W + 98328576);   // 40,960
    int* order_ws = (int*)(W + 98369536);  // 640,000 -> 99,009,536
    unsigned short* tpw_ws = (unsigned short*)(W + 99009536);  // 204,800,000 -> 303,809,536
    const size_t WS_FAST = 303809536;

    const float inv1280 = 0.02795084972f;
    const float inv128  = 0.08838834765f;
    const float scO_s   = 1.f / 256.f;
    const float scO_v   = 1.f / (19.5959179423f * 16.f);

    k_prep<<<dim3(640, 7, 1), 256, 0, stream>>>(W_sc_s, W_sc_v, W_lin_s, W_lin_v, W_out_s, W_out_v, mlp_w3,
                                                wsc_sT, wsc_vT, wlin_sT, wlin_vT, wout_sT, wout_vT, w3T);
    k_mlp012<<<dim3(2500), 256, 0, stream>>>(edge_feats, mlp_w0, mlp_w1, mlp_w2, h2_ws);

    // sc = tp @ W_sc * inv -> d_out second half
    {
        GemmZ g0{1, nfs,     128, 1, node_attrs, wsc_sT, dout + 5120000,           512, 1, 1280, inv1280, N_NODES};
        GemmZ g1{1, nfv + 0, 384, 3, node_attrs, wsc_vT, dout + 5120000 + 128 + 0, 512, 3, 1280, inv1280, N_NODES};
        GemmZ g2{1, nfv + 1, 384, 3, node_attrs, wsc_vT, dout + 5120000 + 128 + 1, 512, 3, 1280, inv1280, N_NODES};
        GemmZ g3{1, nfv + 2, 384, 3, node_attrs, wsc_vT, dout + 5120000 + 128 + 2, 512, 3, 1280, inv1280, N_NODES};
        k_gemm<<<dim3(157, 1, 4), 256, 0, stream>>>(g0, g1, g2, g3);
    }
    // x_s / x_v -> ws
    {
        GemmZ g0{0, nfs,     128, 1, nullptr, wlin_sT, xs_ws,       128, 1, 128, inv128, N_NODES};
        GemmZ g1{0, nfv + 0, 384, 3, nullptr, wlin_vT, xv_ws + 0,   384, 1, 128, inv128, N_NODES};
        GemmZ g2{0, nfv + 1, 384, 3, nullptr, wlin_vT, xv_ws + 128, 384, 1, 128, inv128, N_NODES};
        GemmZ g3{0, nfv + 2, 384, 3, nullptr, wlin_vT, xv_ws + 256, 384, 1, 128, inv128, N_NODES};
        k_gemm<<<dim3(157, 1, 4), 256, 0, stream>>>(g0, g1, g2, g3);
    }

    if (ws_size >= WS_FAST) {
        // CSR path: tpw GEMM + sort-by-receiver + atomic-free accumulate
        k_tpw<<<dim3(2500), 256, 0, stream>>>(h2_ws, w3T, tpw_ws);
        hipMemsetAsync(cnt_ws, 0, 40960, stream);
        k_hist<<<dim3(625), 256, 0, stream>>>(receivers, cnt_ws);
        k_scan<<<dim3(1), 256, 0, stream>>>(cnt_ws, base_ws, cur_ws);
        k_scatter<<<dim3(625), 256, 0, stream>>>(receivers, cur_ws, order_ws);
        k_accum<<<dim3(N_NODES / 2), 256, 0, stream>>>(tpw_ws, edge_attrs, senders, order_ws, base_ws,
                                                       xs_ws, xv_ws, msgs_ws, msgv_ws);
    } else {
        hipMemsetAsync(msgs_ws, 0, 56320000, stream);
        k_edge<<<dim3(5000), 256, 0, stream>>>(h2_ws, w3T, edge_attrs, senders, receivers,
                                               xs_ws, xv_ws, msgs_ws, msgv_ws);
    }

    // out = msg @ W_out -> d_out first half
    {
        GemmZ g0{0, msgs_ws,       256,  1, nullptr, wout_sT, dout,           512, 1, 256, scO_s, N_NODES};
        GemmZ g1{0, msgv_ws + 0,   1152, 1, nullptr, wout_vT, dout + 128 + 0, 512, 3, 384, scO_v, N_NODES};
        GemmZ g2{0, msgv_ws + 384, 1152, 1, nullptr, wout_vT, dout + 128 + 1, 512, 3, 384, scO_v, N_NODES};
        GemmZ g3{0, msgv_ws + 768, 1152, 1, nullptr, wout_vT, dout + 128 + 2, 512, 3, 384, scO_v, N_NODES};
        k_gemm<<<dim3(157, 1, 4), 256, 0, stream>>>(g0, g1, g2, g3);
    }
}

// Round 3
// 636.153 us; speedup vs baseline: 1.8088x; 1.7994x over previous
//
#include <hip/hip_runtime.h>

#define N_NODES 10000
#define N_EDGES 160000

typedef float f32x4 __attribute__((ext_vector_type(4)));
typedef short s8v __attribute__((ext_vector_type(8)));

__device__ __forceinline__ unsigned short f2b(float f) {
    unsigned u = __builtin_bit_cast(unsigned, f);
    u += 0x7FFFu + ((u >> 16) & 1u);
    return (unsigned short)(u >> 16);
}
__device__ __forceinline__ float b2f(unsigned short s) {
    unsigned u = ((unsigned)s) << 16;
    return __builtin_bit_cast(float, u);
}

// ---------------- prep: transpose + bf16-convert weight matrices ----------------
__global__ void k_prep(const float* s0, const float* s1, const float* s2, const float* s3,
                       const float* s4, const float* s5, const float* s6,
                       unsigned short* d0, unsigned short* d1, unsigned short* d2, unsigned short* d3,
                       unsigned short* d4, unsigned short* d5, unsigned short* d6) {
    const float* src; unsigned short* dst; int K, Nc;
    switch (blockIdx.y) {
        case 0: src = s0; dst = d0; K = 1280; Nc = 128; break;
        case 1: src = s1; dst = d1; K = 1280; Nc = 128; break;
        case 2: src = s2; dst = d2; K = 128;  Nc = 128; break;
        case 3: src = s3; dst = d3; K = 128;  Nc = 128; break;
        case 4: src = s4; dst = d4; K = 256;  Nc = 128; break;
        case 5: src = s5; dst = d5; K = 384;  Nc = 128; break;
        default: src = s6; dst = d6; K = 64;  Nc = 640; break;
    }
    int idx = blockIdx.x * 256 + threadIdx.x;
    if (idx < K * Nc) {
        int k = idx / Nc, c = idx - k * Nc;
        dst[c * K + k] = f2b(src[idx]);
    }
}

// ---------------- generic MFMA GEMM ----------------
struct GemmZ {
    int amode;
    const float* Ap;
    int ars, aks;
    const float* attr;
    const unsigned short* Bt;
    float* Cp;
    int crs, ccs;
    int K;
    float scale;
    int M;
};

__global__ __launch_bounds__(256) void k_gemm(GemmZ g0, GemmZ g1, GemmZ g2, GemmZ g3) {
    GemmZ g;
    switch (blockIdx.z) { case 0: g = g0; break; case 1: g = g1; break; case 2: g = g2; break; default: g = g3; }
    __shared__ unsigned short As[64][40];
    const int t = threadIdx.x;
    const int wv = t >> 6, lane = t & 63;
    const int lr = lane & 15, lkg = lane >> 4;
    const int row0 = blockIdx.x * 64;
    const int br = t >> 2;
    const int bk0 = (t & 3) * 8;
    const int arow = row0 + br;

    f32x4 acc[8];
#pragma unroll
    for (int i = 0; i < 8; i++) acc[i] = (f32x4){0.f, 0.f, 0.f, 0.f};

    for (int k0 = 0; k0 < g.K; k0 += 32) {
        s8v av;
        if (arow < g.M) {
            if (g.amode == 0) {
#pragma unroll
                for (int j = 0; j < 8; j++)
                    av[j] = (short)f2b(g.Ap[(long)arow * g.ars + (long)(k0 + bk0 + j) * g.aks]);
            } else {
#pragma unroll
                for (int j = 0; j < 8; j++) {
                    int k = k0 + bk0 + j;
                    int c = k / 10, a = k - c * 10;
                    av[j] = (short)f2b(g.Ap[(long)arow * g.ars + c * g.aks] * g.attr[arow * 10 + a]);
                }
            }
        } else {
#pragma unroll
            for (int j = 0; j < 8; j++) av[j] = 0;
        }
        __syncthreads();
        *reinterpret_cast<s8v*>(&As[br][bk0]) = av;
        __syncthreads();
        s8v af = *reinterpret_cast<const s8v*>(&As[wv * 16 + lr][lkg * 8]);
#pragma unroll
        for (int ct = 0; ct < 8; ct++) {
            const unsigned short* bp = g.Bt + (long)(ct * 16 + lr) * g.K + k0 + lkg * 8;
            s8v bf = *reinterpret_cast<const s8v*>(bp);
            acc[ct] = __builtin_amdgcn_mfma_f32_16x16x32_bf16(af, bf, acc[ct], 0, 0, 0);
        }
    }
#pragma unroll
    for (int ct = 0; ct < 8; ct++) {
#pragma unroll
        for (int r = 0; r < 4; r++) {
            int row = row0 + wv * 16 + lkg * 4 + r;
            if (row < g.M) {
                int col = ct * 16 + lr;
                g.Cp[(long)row * g.crs + col * g.ccs] = acc[ct][r] * g.scale;
            }
        }
    }
}

// ---------------- MLP layers 0..2 ----------------
__global__ __launch_bounds__(256) void k_mlp012(const float* __restrict__ ef, const float* __restrict__ w0,
                                                const float* __restrict__ w1, const float* __restrict__ w2,
                                                unsigned short* __restrict__ h2out) {
    __shared__ float efs[64][8];
    __shared__ float ha[64][64];
    __shared__ float hb[64][64];
    __shared__ float wl[64][64];
    __shared__ float w0l[8][64];
    const int t = threadIdx.x;
    const long e0 = (long)blockIdx.x * 64;
#pragma unroll
    for (int j = 0; j < 2; j++) { int idx = t + j * 256; ((float*)efs)[idx] = ef[e0 * 8 + idx]; }
#pragma unroll
    for (int j = 0; j < 2; j++) { int idx = t + j * 256; ((float*)w0l)[idx] = w0[idx]; }
#pragma unroll
    for (int j = 0; j < 16; j++) { int idx = t + j * 256; ((float*)wl)[idx] = w1[idx]; }
    __syncthreads();
    const int o = t & 63, ebase = t >> 6;
#pragma unroll
    for (int j = 0; j < 16; j++) {
        int e = ebase * 16 + j;
        float acc = 0.f;
#pragma unroll
        for (int k = 0; k < 8; k++) acc += efs[e][k] * w0l[k][o];
        acc *= 0.35355339059f;
        ha[e][o] = acc / (1.f + __expf(-acc));
    }
    __syncthreads();
#pragma unroll
    for (int j = 0; j < 16; j++) {
        int e = ebase * 16 + j;
        float acc = 0.f;
        for (int k = 0; k < 64; k++) acc += ha[e][k] * wl[k][o];
        acc *= 0.125f;
        hb[e][o] = acc / (1.f + __expf(-acc));
    }
    __syncthreads();
#pragma unroll
    for (int j = 0; j < 16; j++) { int idx = t + j * 256; ((float*)wl)[idx] = w2[idx]; }
    __syncthreads();
#pragma unroll
    for (int j = 0; j < 16; j++) {
        int e = ebase * 16 + j;
        float acc = 0.f;
        for (int k = 0; k < 64; k++) acc += hb[e][k] * wl[k][o];
        acc *= 0.125f;
        float h = acc / (1.f + __expf(-acc));
        h2out[(e0 + e) * 64 + o] = f2b(h);
    }
}

// ---------------- CSR build ----------------
__global__ void k_hist(const int* __restrict__ rcv, int* __restrict__ cnt) {
    int e = blockIdx.x * 256 + threadIdx.x;
    if (e < N_EDGES) atomicAdd(&cnt[rcv[e]], 1);
}

__global__ __launch_bounds__(256) void k_scan(const int* __restrict__ cnt, int* __restrict__ base, int* __restrict__ cur) {
    __shared__ int s[256];
    const int t = threadIdx.x;
    const int c0 = t * 40;
    int sum = 0;
    for (int i = 0; i < 40; i++) sum += cnt[c0 + i];
    s[t] = sum;
    __syncthreads();
    for (int off = 1; off < 256; off <<= 1) {
        int v = (t >= off) ? s[t - off] : 0;
        __syncthreads();
        s[t] += v;
        __syncthreads();
    }
    int run = t ? s[t - 1] : 0;
    for (int i = 0; i < 40; i++) {
        int idx = c0 + i;
        if (idx <= N_NODES) { base[idx] = run; cur[idx] = run; }
        run += cnt[idx];
    }
}

__global__ void k_scatter(const int* __restrict__ rcv, int* __restrict__ cur, int* __restrict__ order) {
    int e = blockIdx.x * 256 + threadIdx.x;
    if (e < N_EDGES) {
        int p = atomicAdd(&cur[rcv[e]], 1);
        order[p] = e;
    }
}

// ---------------- fused per-edge, sorted-by-receiver, run-reduced atomics ----------------
__global__ __launch_bounds__(256) void k_edge2(const unsigned short* __restrict__ h2,
                                               const unsigned short* __restrict__ w3T,
                                               const float* __restrict__ eattr,
                                               const int* __restrict__ snd, const int* __restrict__ rcv,
                                               const int* __restrict__ order,
                                               const float* __restrict__ xs, const float* __restrict__ xv,
                                               float* __restrict__ msg_s, float* __restrict__ msg_v) {
    __shared__ unsigned short h2s[32][72];
    __shared__ unsigned short tpw[32][644];
    __shared__ float es_l[32];
    __shared__ float ev_l[32][3];
    __shared__ int sn_l[32], rc_l[32];
    const int t = threadIdx.x;
    const int j0 = blockIdx.x * 32;
    {
        int r = t >> 3, kk = (t & 7) * 8;
        int e = order[j0 + r];
        s8v v = *reinterpret_cast<const s8v*>(h2 + (long)e * 64 + kk);
        *reinterpret_cast<s8v*>(&h2s[r][kk]) = v;
    }
    if (t < 32) {
        int e = order[j0 + t];
        es_l[t] = eattr[e * 4 + 0];
        ev_l[t][0] = eattr[e * 4 + 1];
        ev_l[t][1] = eattr[e * 4 + 2];
        ev_l[t][2] = eattr[e * 4 + 3];
        sn_l[t] = snd[e];
        rc_l[t] = rcv[e];
    }
    __syncthreads();
    const int wv = t >> 6, lane = t & 63, lr = lane & 15, lkg = lane >> 4;
#pragma unroll
    for (int p = 0; p < 20; p++) {
        int ct = wv + 4 * (p % 10);
        int rt = p / 10;
        f32x4 acc = (f32x4){0.f, 0.f, 0.f, 0.f};
#pragma unroll
        for (int ks = 0; ks < 2; ks++) {
            s8v a = *reinterpret_cast<const s8v*>(&h2s[rt * 16 + lr][ks * 32 + lkg * 8]);
            s8v b = *reinterpret_cast<const s8v*>(w3T + (long)(ct * 16 + lr) * 64 + ks * 32 + lkg * 8);
            acc = __builtin_amdgcn_mfma_f32_16x16x32_bf16(a, b, acc, 0, 0, 0);
        }
#pragma unroll
        for (int r = 0; r < 4; r++)
            tpw[rt * 16 + lkg * 4 + r][ct * 16 + lr] = f2b(acc[r] * 0.125f);
    }
    __syncthreads();
    const int c = t & 127, seg = t >> 7;
    float a_s0 = 0.f, a_s1 = 0.f;
    float av0 = 0.f, av1 = 0.f, av2 = 0.f, av3 = 0.f, av4 = 0.f, av5 = 0.f, av6 = 0.f, av7 = 0.f, av8 = 0.f;
    int cur_rc = -1;
#define FLUSH_RUN() do { \
        float* ms = msg_s + (long)cur_rc * 256 + c; \
        unsafeAtomicAdd(ms, a_s0); \
        unsafeAtomicAdd(ms + 128, a_s1); \
        float* mv = msg_v + (long)cur_rc * 1152 + c; \
        unsafeAtomicAdd(mv + 0, av0); \
        unsafeAtomicAdd(mv + 128, av1); \
        unsafeAtomicAdd(mv + 256, av2); \
        unsafeAtomicAdd(mv + 384, av3); \
        unsafeAtomicAdd(mv + 512, av4); \
        unsafeAtomicAdd(mv + 640, av5); \
        unsafeAtomicAdd(mv + 768, av6); \
        unsafeAtomicAdd(mv + 896, av7); \
        unsafeAtomicAdd(mv + 1024, av8); \
    } while (0)
    for (int i = 0; i < 16; i++) {
        int idx = seg * 16 + i;
        int rc = rc_l[idx];
        if (rc != cur_rc) {
            if (cur_rc >= 0) FLUSH_RUN();
            cur_rc = rc;
            a_s0 = a_s1 = 0.f;
            av0 = av1 = av2 = av3 = av4 = av5 = av6 = av7 = av8 = 0.f;
        }
        int s = sn_l[idx];
        float es = es_l[idx], ev0 = ev_l[idx][0], ev1 = ev_l[idx][1], ev2 = ev_l[idx][2];
        float w1 = b2f(tpw[idx][c]);
        float w2 = b2f(tpw[idx][128 + c]);
        float w3 = b2f(tpw[idx][256 + c]);
        float w4 = b2f(tpw[idx][384 + c]);
        float w5 = b2f(tpw[idx][512 + c]);
        float xsv = xs[s * 128 + c];
        float x0 = xv[s * 384 + c], x1 = xv[s * 384 + 128 + c], x2 = xv[s * 384 + 256 + c];
        a_s0 += w1 * xsv * es;
        float dve = x0 * ev0 + x1 * ev1 + x2 * ev2;
        a_s1 += w4 * dve * 0.57735026919f;
        float a2 = w2 * xsv;
        av0 += a2 * ev0;
        av1 += w3 * x0 * es;
        av2 += w5 * (x1 * ev2 - x2 * ev1) * 0.70710678119f;
        av3 += a2 * ev1;
        av4 += w3 * x1 * es;
        av5 += w5 * (x2 * ev0 - x0 * ev2) * 0.70710678119f;
        av6 += a2 * ev2;
        av7 += w3 * x2 * es;
        av8 += w5 * (x0 * ev1 - x1 * ev0) * 0.70710678119f;
    }
    FLUSH_RUN();
#undef FLUSH_RUN
}

// ---------------- fallback: atomic per-edge (original path) ----------------
__global__ __launch_bounds__(256) void k_edge(const unsigned short* __restrict__ h2,
                                              const unsigned short* __restrict__ w3T,
                                              const float* __restrict__ eattr,
                                              const int* __restrict__ snd, const int* __restrict__ rcv,
                                              const float* __restrict__ xs, const float* __restrict__ xv,
                                              float* __restrict__ msg_s, float* __restrict__ msg_v) {
    __shared__ unsigned short h2s[32][72];
    __shared__ unsigned short tpw[32][644];
    __shared__ float es_l[32];
    __shared__ float ev_l[32][3];
    __shared__ int sn_l[32], rc_l[32];
    const int t = threadIdx.x;
    const int e0 = blockIdx.x * 32;
    {
        int r = t >> 3, kk = (t & 7) * 8;
        s8v v = *reinterpret_cast<const s8v*>(h2 + (long)(e0 + r) * 64 + kk);
        *reinterpret_cast<s8v*>(&h2s[r][kk]) = v;
    }
    if (t < 32) {
        es_l[t] = eattr[(e0 + t) * 4 + 0];
        ev_l[t][0] = eattr[(e0 + t) * 4 + 1];
        ev_l[t][1] = eattr[(e0 + t) * 4 + 2];
        ev_l[t][2] = eattr[(e0 + t) * 4 + 3];
        sn_l[t] = snd[e0 + t];
        rc_l[t] = rcv[e0 + t];
    }
    __syncthreads();
    const int wv = t >> 6, lane = t & 63, lr = lane & 15, lkg = lane >> 4;
#pragma unroll
    for (int p = 0; p < 20; p++) {
        int ct = wv + 4 * (p % 10);
        int rt = p / 10;
        f32x4 acc = (f32x4){0.f, 0.f, 0.f, 0.f};
#pragma unroll
        for (int ks = 0; ks < 2; ks++) {
            s8v a = *reinterpret_cast<const s8v*>(&h2s[rt * 16 + lr][ks * 32 + lkg * 8]);
            s8v b = *reinterpret_cast<const s8v*>(w3T + (long)(ct * 16 + lr) * 64 + ks * 32 + lkg * 8);
            acc = __builtin_amdgcn_mfma_f32_16x16x32_bf16(a, b, acc, 0, 0, 0);
        }
#pragma unroll
        for (int r = 0; r < 4; r++)
            tpw[rt * 16 + lkg * 4 + r][ct * 16 + lr] = f2b(acc[r] * 0.125f);
    }
    __syncthreads();
    const int c = t & 127, eb = t >> 7;
#pragma unroll 4
    for (int it = 0; it < 16; it++) {
        int e = eb + 2 * it;
        int s = sn_l[e], rc = rc_l[e];
        float es = es_l[e], ev0 = ev_l[e][0], ev1 = ev_l[e][1], ev2 = ev_l[e][2];
        float w1 = b2f(tpw[e][c]);
        float w2 = b2f(tpw[e][128 + c]);
        float w3 = b2f(tpw[e][256 + c]);
        float w4 = b2f(tpw[e][384 + c]);
        float w5 = b2f(tpw[e][512 + c]);
        float xsv = xs[s * 128 + c];
        float x0 = xv[s * 384 + c], x1 = xv[s * 384 + 128 + c], x2 = xv[s * 384 + 256 + c];
        float m0a = w1 * xsv * es;
        float dve = x0 * ev0 + x1 * ev1 + x2 * ev2;
        float m0b = w4 * dve * 0.57735026919f;
        float a2 = w2 * xsv;
        float cr0 = x1 * ev2 - x2 * ev1;
        float cr1 = x2 * ev0 - x0 * ev2;
        float cr2 = x0 * ev1 - x1 * ev0;
        float* ms = msg_s + (long)rc * 256 + c;
        unsafeAtomicAdd(ms, m0a);
        unsafeAtomicAdd(ms + 128, m0b);
        float* mv = msg_v + (long)rc * 1152 + c;
        unsafeAtomicAdd(mv + 0, a2 * ev0);
        unsafeAtomicAdd(mv + 128, w3 * x0 * es);
        unsafeAtomicAdd(mv + 256, w5 * cr0 * 0.70710678119f);
        unsafeAtomicAdd(mv + 384, a2 * ev1);
        unsafeAtomicAdd(mv + 512, w3 * x1 * es);
        unsafeAtomicAdd(mv + 640, w5 * cr1 * 0.70710678119f);
        unsafeAtomicAdd(mv + 768, a2 * ev2);
        unsafeAtomicAdd(mv + 896, w3 * x2 * es);
        unsafeAtomicAdd(mv + 1024, w5 * cr2 * 0.70710678119f);
    }
}

extern "C" void kernel_launch(void* const* d_in, const int* in_sizes, int n_in,
                              void* d_out, int out_size, void* d_ws, size_t ws_size,
                              hipStream_t stream) {
    const float* node_attrs = (const float*)d_in[0];
    const float* nfs        = (const float*)d_in[1];
    const float* nfv        = (const float*)d_in[2];
    const float* edge_attrs = (const float*)d_in[3];
    const float* edge_feats = (const float*)d_in[4];
    const float* W_sc_s     = (const float*)d_in[5];
    const float* W_sc_v     = (const float*)d_in[6];
    const float* W_lin_s    = (const float*)d_in[7];
    const float* W_lin_v    = (const float*)d_in[8];
    const float* mlp_w0     = (const float*)d_in[9];
    const float* mlp_w1     = (const float*)d_in[10];
    const float* mlp_w2     = (const float*)d_in[11];
    const float* mlp_w3     = (const float*)d_in[12];
    const float* W_out_s    = (const float*)d_in[13];
    const float* W_out_v    = (const float*)d_in[14];
    const int* senders      = (const int*)d_in[15];
    const int* receivers    = (const int*)d_in[16];
    float* dout = (float*)d_out;

    char* W = (char*)d_ws;
    float* xs_ws   = (float*)(W + 0);          // 5,120,000
    float* xv_ws   = (float*)(W + 5120000);    // 15,360,000
    float* msgs_ws = (float*)(W + 20480000);   // 10,240,000
    float* msgv_ws = (float*)(W + 30720000);   // 46,080,000
    unsigned short* h2_ws   = (unsigned short*)(W + 76800000);  // 20,480,000
    unsigned short* wsc_sT  = (unsigned short*)(W + 97280000);
    unsigned short* wsc_vT  = (unsigned short*)(W + 97607680);
    unsigned short* wlin_sT = (unsigned short*)(W + 97935360);
    unsigned short* wlin_vT = (unsigned short*)(W + 97968128);
    unsigned short* wout_sT = (unsigned short*)(W + 98000896);
    unsigned short* wout_vT = (unsigned short*)(W + 98066432);
    unsigned short* w3T     = (unsigned short*)(W + 98164736);  // ends 98,246,656
    int* cnt_ws   = (int*)(W + 98246656);   // 40,960
    int* base_ws  = (int*)(W + 98287616);   // 40,960
    int* cur_ws   = (int*)(W + 98328576);   // 40,960
    int* order_ws = (int*)(W + 98369536);   // 640,000 -> ends 99,009,536
    const size_t WS_CSR = 99009536;

    const float inv1280 = 0.02795084972f;
    const float inv128  = 0.08838834765f;
    const float scO_s   = 1.f / 256.f;
    const float scO_v   = 1.f / (19.5959179423f * 16.f);

    k_prep<<<dim3(640, 7, 1), 256, 0, stream>>>(W_sc_s, W_sc_v, W_lin_s, W_lin_v, W_out_s, W_out_v, mlp_w3,
                                                wsc_sT, wsc_vT, wlin_sT, wlin_vT, wout_sT, wout_vT, w3T);
    k_mlp012<<<dim3(2500), 256, 0, stream>>>(edge_feats, mlp_w0, mlp_w1, mlp_w2, h2_ws);

    // sc = tp @ W_sc * inv -> d_out second half
    {
        GemmZ g0{1, nfs,     128, 1, node_attrs, wsc_sT, dout + 5120000,           512, 1, 1280, inv1280, N_NODES};
        GemmZ g1{1, nfv + 0, 384, 3, node_attrs, wsc_vT, dout + 5120000 + 128 + 0, 512, 3, 1280, inv1280, N_NODES};
        GemmZ g2{1, nfv + 1, 384, 3, node_attrs, wsc_vT, dout + 5120000 + 128 + 1, 512, 3, 1280, inv1280, N_NODES};
        GemmZ g3{1, nfv + 2, 384, 3, node_attrs, wsc_vT, dout + 5120000 + 128 + 2, 512, 3, 1280, inv1280, N_NODES};
        k_gemm<<<dim3(157, 1, 4), 256, 0, stream>>>(g0, g1, g2, g3);
    }
    // x_s / x_v -> ws
    {
        GemmZ g0{0, nfs,     128, 1, nullptr, wlin_sT, xs_ws,       128, 1, 128, inv128, N_NODES};
        GemmZ g1{0, nfv + 0, 384, 3, nullptr, wlin_vT, xv_ws + 0,   384, 1, 128, inv128, N_NODES};
        GemmZ g2{0, nfv + 1, 384, 3, nullptr, wlin_vT, xv_ws + 128, 384, 1, 128, inv128, N_NODES};
        GemmZ g3{0, nfv + 2, 384, 3, nullptr, wlin_vT, xv_ws + 256, 384, 1, 128, inv128, N_NODES};
        k_gemm<<<dim3(157, 1, 4), 256, 0, stream>>>(g0, g1, g2, g3);
    }

    hipMemsetAsync(msgs_ws, 0, 56320000, stream);  // msg_s + msg_v
    if (ws_size >= WS_CSR) {
        hipMemsetAsync(cnt_ws, 0, 40960, stream);
        k_hist<<<dim3(625), 256, 0, stream>>>(receivers, cnt_ws);
        k_scan<<<dim3(1), 256, 0, stream>>>(cnt_ws, base_ws, cur_ws);
        k_scatter<<<dim3(625), 256, 0, stream>>>(receivers, cur_ws, order_ws);
        k_edge2<<<dim3(5000), 256, 0, stream>>>(h2_ws, w3T, edge_attrs, senders, receivers, order_ws,
                                                xs_ws, xv_ws, msgs_ws, msgv_ws);
    } else {
        k_edge<<<dim3(5000), 256, 0, stream>>>(h2_ws, w3T, edge_attrs, senders, receivers,
                                               xs_ws, xv_ws, msgs_ws, msgv_ws);
    }

    // out = msg @ W_out -> d_out first half
    {
        GemmZ g0{0, msgs_ws,       256,  1, nullptr, wout_sT, dout,           512, 1, 256, scO_s, N_NODES};
        GemmZ g1{0, msgv_ws + 0,   1152, 1, nullptr, wout_vT, dout + 128 + 0, 512, 3, 384, scO_v, N_NODES};
        GemmZ g2{0, msgv_ws + 384, 1152, 1, nullptr, wout_vT, dout + 128 + 1, 512, 3, 384, scO_v, N_NODES};
        GemmZ g3{0, msgv_ws + 768, 1152, 1, nullptr, wout_vT, dout + 128 + 2, 512, 3, 384, scO_v, N_NODES};
        k_gemm<<<dim3(157, 1, 4), 256, 0, stream>>>(g0, g1, g2, g3);
    }
}

// Round 4
// 529.656 us; speedup vs baseline: 2.1724x; 1.2011x over previous
//
#include <hip/hip_runtime.h>

#define N_NODES 10000
#define N_EDGES 160000

typedef float f32x4 __attribute__((ext_vector_type(4)));
typedef short s8v __attribute__((ext_vector_type(8)));

__device__ __forceinline__ unsigned short f2b(float f) {
    unsigned u = __builtin_bit_cast(unsigned, f);
    u += 0x7FFFu + ((u >> 16) & 1u);
    return (unsigned short)(u >> 16);
}
__device__ __forceinline__ float b2f(unsigned short s) {
    unsigned u = ((unsigned)s) << 16;
    return __builtin_bit_cast(float, u);
}

// ---------------- prep: weight matrices -> bf16, layouts for MFMA ----------------
// cases 0,1 (sc weights): dst[a*16384 + o*128 + ci] = src[(ci*10+a)*128 + o]   [10][128][128]
// cases 2..6: dst[c*K + k] = src[k*Nc + c]  (B^T layout)
__global__ void k_prep(const float* s0, const float* s1, const float* s2, const float* s3,
                       const float* s4, const float* s5, const float* s6,
                       unsigned short* d0, unsigned short* d1, unsigned short* d2, unsigned short* d3,
                       unsigned short* d4, unsigned short* d5, unsigned short* d6) {
    int idx = blockIdx.x * 256 + threadIdx.x;
    if (blockIdx.y < 2) {
        const float* src = blockIdx.y ? s1 : s0;
        unsigned short* dst = blockIdx.y ? d1 : d0;
        // idx over 1280*128
        int k = idx >> 7, o = idx & 127;
        int ci = k / 10, a = k - ci * 10;
        dst[a * 16384 + o * 128 + ci] = f2b(src[idx]);
        return;
    }
    const float* src; unsigned short* dst; int K, Nc;
    switch (blockIdx.y) {
        case 2: src = s2; dst = d2; K = 128;  Nc = 128; break;
        case 3: src = s3; dst = d3; K = 128;  Nc = 128; break;
        case 4: src = s4; dst = d4; K = 256;  Nc = 128; break;
        case 5: src = s5; dst = d5; K = 384;  Nc = 128; break;
        default: src = s6; dst = d6; K = 64;  Nc = 640; break;
    }
    if (idx < K * Nc) {
        int k = idx / Nc, c = idx - k * Nc;
        dst[c * K + k] = f2b(src[idx]);
    }
}

// ---------------- sc: out[n, o] = inv1280 * sum_a attr[n,a] * (A_z @ W_a)[n, o] ----------------
// z = blockIdx.y: 0 -> A = node_feats_s (contig); 1..3 -> A = node_feats_v[:, :, z-1] (stride 3)
__global__ __launch_bounds__(256) void k_sc(const float* __restrict__ nfs,
                                            const float* __restrict__ nfv,
                                            const float* __restrict__ attr,
                                            const unsigned short* __restrict__ Ws2,
                                            const unsigned short* __restrict__ Wv2,
                                            float* __restrict__ out, float scale) {
    __shared__ unsigned short As[64][136];
    __shared__ unsigned short Bs[128][140];
    __shared__ float attr_l[64][10];
    const int t = threadIdx.x;
    const int z = blockIdx.y;
    const int row0 = blockIdx.x * 64;
    const int wv = t >> 6, lane = t & 63, lr = lane & 15, lkg = lane >> 4;

    // stage A tile (64 x 128) as bf16
    {
        int r = t >> 2, k0 = (t & 3) * 32;
        int row = row0 + r;
        if (z == 0) {
            if (row < N_NODES) {
#pragma unroll
                for (int j = 0; j < 8; j++) {
                    f32x4 v = *reinterpret_cast<const f32x4*>(nfs + (long)row * 128 + k0 + j * 4);
                    As[r][k0 + j * 4 + 0] = f2b(v[0]);
                    As[r][k0 + j * 4 + 1] = f2b(v[1]);
                    As[r][k0 + j * 4 + 2] = f2b(v[2]);
                    As[r][k0 + j * 4 + 3] = f2b(v[3]);
                }
            } else {
#pragma unroll
                for (int j = 0; j < 32; j++) As[r][k0 + j] = 0;
            }
        } else {
            int i = z - 1;
            if (row < N_NODES) {
#pragma unroll
                for (int j = 0; j < 32; j++)
                    As[r][k0 + j] = f2b(nfv[(long)row * 384 + (k0 + j) * 3 + i]);
            } else {
#pragma unroll
                for (int j = 0; j < 32; j++) As[r][k0 + j] = 0;
            }
        }
    }
    // stage attr tile (64 x 10)
    for (int idx = t; idx < 640; idx += 256) {
        int r = idx / 10, a = idx - r * 10;
        int row = row0 + r;
        attr_l[r][a] = (row < N_NODES) ? attr[row * 10 + a] : 0.f;
    }
    __syncthreads();

    // A fragments in registers (reused across all a)
    s8v af[4];
#pragma unroll
    for (int kk = 0; kk < 4; kk++)
        af[kk] = *reinterpret_cast<const s8v*>(&As[wv * 16 + lr][kk * 32 + lkg * 8]);

    f32x4 accS[8];
#pragma unroll
    for (int i = 0; i < 8; i++) accS[i] = (f32x4){0.f, 0.f, 0.f, 0.f};

    const unsigned short* Wbase = (z == 0) ? Ws2 : Wv2;
    for (int a = 0; a < 10; a++) {
        // stage W_a (128 x 128 bf16), [o][c]
        {
            const unsigned short* src = Wbase + a * 16384;
            int r = t >> 1, c0 = (t & 1) * 64;
#pragma unroll
            for (int j = 0; j < 8; j++) {
                s8v v = *reinterpret_cast<const s8v*>(src + r * 128 + c0 + j * 8);
                *reinterpret_cast<s8v*>(&Bs[r][c0 + j * 8]) = v;
            }
        }
        __syncthreads();
        f32x4 acc[8];
#pragma unroll
        for (int i = 0; i < 8; i++) acc[i] = (f32x4){0.f, 0.f, 0.f, 0.f};
#pragma unroll
        for (int kk = 0; kk < 4; kk++) {
#pragma unroll
            for (int ct = 0; ct < 8; ct++) {
                s8v bf = *reinterpret_cast<const s8v*>(&Bs[ct * 16 + lr][kk * 32 + lkg * 8]);
                acc[ct] = __builtin_amdgcn_mfma_f32_16x16x32_bf16(af[kk], bf, acc[ct], 0, 0, 0);
            }
        }
#pragma unroll
        for (int r = 0; r < 4; r++) {
            float aw = attr_l[wv * 16 + lkg * 4 + r][a];
#pragma unroll
            for (int ct = 0; ct < 8; ct++)
                accS[ct][r] += aw * acc[ct][r];
        }
        __syncthreads();
    }
    // write
#pragma unroll
    for (int ct = 0; ct < 8; ct++) {
#pragma unroll
        for (int r = 0; r < 4; r++) {
            int row = row0 + wv * 16 + lkg * 4 + r;
            if (row < N_NODES) {
                int col = ct * 16 + lr;
                if (z == 0) out[(long)row * 512 + col] = accS[ct][r] * scale;
                else        out[(long)row * 512 + 128 + col * 3 + (z - 1)] = accS[ct][r] * scale;
            }
        }
    }
}

// ---------------- generic MFMA GEMM (x and out GEMMs) ----------------
struct GemmZ {
    int amode;
    const float* Ap;
    int ars, aks;
    const float* attr;
    const unsigned short* Bt;
    float* Cp;
    int crs, ccs;
    int K;
    float scale;
    int M;
};

__global__ __launch_bounds__(256) void k_gemm(GemmZ g0, GemmZ g1, GemmZ g2, GemmZ g3) {
    GemmZ g;
    switch (blockIdx.z) { case 0: g = g0; break; case 1: g = g1; break; case 2: g = g2; break; default: g = g3; }
    __shared__ unsigned short As[64][40];
    const int t = threadIdx.x;
    const int wv = t >> 6, lane = t & 63;
    const int lr = lane & 15, lkg = lane >> 4;
    const int row0 = blockIdx.x * 64;
    const int br = t >> 2;
    const int bk0 = (t & 3) * 8;
    const int arow = row0 + br;

    f32x4 acc[8];
#pragma unroll
    for (int i = 0; i < 8; i++) acc[i] = (f32x4){0.f, 0.f, 0.f, 0.f};

    for (int k0 = 0; k0 < g.K; k0 += 32) {
        s8v av;
        if (arow < g.M) {
#pragma unroll
            for (int j = 0; j < 8; j++)
                av[j] = (short)f2b(g.Ap[(long)arow * g.ars + (long)(k0 + bk0 + j) * g.aks]);
        } else {
#pragma unroll
            for (int j = 0; j < 8; j++) av[j] = 0;
        }
        __syncthreads();
        *reinterpret_cast<s8v*>(&As[br][bk0]) = av;
        __syncthreads();
        s8v af = *reinterpret_cast<const s8v*>(&As[wv * 16 + lr][lkg * 8]);
#pragma unroll
        for (int ct = 0; ct < 8; ct++) {
            const unsigned short* bp = g.Bt + (long)(ct * 16 + lr) * g.K + k0 + lkg * 8;
            s8v bf = *reinterpret_cast<const s8v*>(bp);
            acc[ct] = __builtin_amdgcn_mfma_f32_16x16x32_bf16(af, bf, acc[ct], 0, 0, 0);
        }
    }
#pragma unroll
    for (int ct = 0; ct < 8; ct++) {
#pragma unroll
        for (int r = 0; r < 4; r++) {
            int row = row0 + wv * 16 + lkg * 4 + r;
            if (row < g.M) {
                int col = ct * 16 + lr;
                g.Cp[(long)row * g.crs + col * g.ccs] = acc[ct][r] * g.scale;
            }
        }
    }
}

// ---------------- MLP layers 0..2 ----------------
__global__ __launch_bounds__(256) void k_mlp012(const float* __restrict__ ef, const float* __restrict__ w0,
                                                const float* __restrict__ w1, const float* __restrict__ w2,
                                                unsigned short* __restrict__ h2out) {
    __shared__ float efs[64][8];
    __shared__ float ha[64][64];
    __shared__ float hb[64][64];
    __shared__ float wl[64][64];
    __shared__ float w0l[8][64];
    const int t = threadIdx.x;
    const long e0 = (long)blockIdx.x * 64;
#pragma unroll
    for (int j = 0; j < 2; j++) { int idx = t + j * 256; ((float*)efs)[idx] = ef[e0 * 8 + idx]; }
#pragma unroll
    for (int j = 0; j < 2; j++) { int idx = t + j * 256; ((float*)w0l)[idx] = w0[idx]; }
#pragma unroll
    for (int j = 0; j < 16; j++) { int idx = t + j * 256; ((float*)wl)[idx] = w1[idx]; }
    __syncthreads();
    const int o = t & 63, ebase = t >> 6;
#pragma unroll
    for (int j = 0; j < 16; j++) {
        int e = ebase * 16 + j;
        float acc = 0.f;
#pragma unroll
        for (int k = 0; k < 8; k++) acc += efs[e][k] * w0l[k][o];
        acc *= 0.35355339059f;
        ha[e][o] = acc / (1.f + __expf(-acc));
    }
    __syncthreads();
#pragma unroll
    for (int j = 0; j < 16; j++) {
        int e = ebase * 16 + j;
        float acc = 0.f;
        for (int k = 0; k < 64; k++) acc += ha[e][k] * wl[k][o];
        acc *= 0.125f;
        hb[e][o] = acc / (1.f + __expf(-acc));
    }
    __syncthreads();
#pragma unroll
    for (int j = 0; j < 16; j++) { int idx = t + j * 256; ((float*)wl)[idx] = w2[idx]; }
    __syncthreads();
#pragma unroll
    for (int j = 0; j < 16; j++) {
        int e = ebase * 16 + j;
        float acc = 0.f;
        for (int k = 0; k < 64; k++) acc += hb[e][k] * wl[k][o];
        acc *= 0.125f;
        float h = acc / (1.f + __expf(-acc));
        h2out[(e0 + e) * 64 + o] = f2b(h);
    }
}

// ---------------- CSR build ----------------
__global__ void k_hist(const int* __restrict__ rcv, int* __restrict__ cnt) {
    int e = blockIdx.x * 256 + threadIdx.x;
    if (e < N_EDGES) atomicAdd(&cnt[rcv[e]], 1);
}

__global__ __launch_bounds__(256) void k_scan(const int* __restrict__ cnt, int* __restrict__ base, int* __restrict__ cur) {
    __shared__ int s[256];
    const int t = threadIdx.x;
    const int c0 = t * 40;
    int sum = 0;
    for (int i = 0; i < 40; i++) sum += cnt[c0 + i];
    s[t] = sum;
    __syncthreads();
    for (int off = 1; off < 256; off <<= 1) {
        int v = (t >= off) ? s[t - off] : 0;
        __syncthreads();
        s[t] += v;
        __syncthreads();
    }
    int run = t ? s[t - 1] : 0;
    for (int i = 0; i < 40; i++) {
        int idx = c0 + i;
        if (idx <= N_NODES) { base[idx] = run; cur[idx] = run; }
        run += cnt[idx];
    }
}

__global__ void k_scatter(const int* __restrict__ rcv, int* __restrict__ cur, int* __restrict__ order) {
    int e = blockIdx.x * 256 + threadIdx.x;
    if (e < N_EDGES) {
        int p = atomicAdd(&cur[rcv[e]], 1);
        order[p] = e;
    }
}

// ---------------- fused per-edge, sorted-by-receiver, run-reduced atomics ----------------
__global__ __launch_bounds__(256) void k_edge2(const unsigned short* __restrict__ h2,
                                               const unsigned short* __restrict__ w3T,
                                               const float* __restrict__ eattr,
                                               const int* __restrict__ snd, const int* __restrict__ rcv,
                                               const int* __restrict__ order,
                                               const float* __restrict__ xs, const float* __restrict__ xv,
                                               float* __restrict__ msg_s, float* __restrict__ msg_v) {
    __shared__ unsigned short h2s[32][72];
    __shared__ unsigned short tpw[32][644];
    __shared__ float es_l[32];
    __shared__ float ev_l[32][3];
    __shared__ int sn_l[32], rc_l[32];
    const int t = threadIdx.x;
    const int j0 = blockIdx.x * 32;
    {
        int r = t >> 3, kk = (t & 7) * 8;
        int e = order[j0 + r];
        s8v v = *reinterpret_cast<const s8v*>(h2 + (long)e * 64 + kk);
        *reinterpret_cast<s8v*>(&h2s[r][kk]) = v;
    }
    if (t < 32) {
        int e = order[j0 + t];
        es_l[t] = eattr[e * 4 + 0];
        ev_l[t][0] = eattr[e * 4 + 1];
        ev_l[t][1] = eattr[e * 4 + 2];
        ev_l[t][2] = eattr[e * 4 + 3];
        sn_l[t] = snd[e];
        rc_l[t] = rcv[e];
    }
    __syncthreads();
    const int wv = t >> 6, lane = t & 63, lr = lane & 15, lkg = lane >> 4;
#pragma unroll
    for (int p = 0; p < 20; p++) {
        int ct = wv + 4 * (p % 10);
        int rt = p / 10;
        f32x4 acc = (f32x4){0.f, 0.f, 0.f, 0.f};
#pragma unroll
        for (int ks = 0; ks < 2; ks++) {
            s8v a = *reinterpret_cast<const s8v*>(&h2s[rt * 16 + lr][ks * 32 + lkg * 8]);
            s8v b = *reinterpret_cast<const s8v*>(w3T + (long)(ct * 16 + lr) * 64 + ks * 32 + lkg * 8);
            acc = __builtin_amdgcn_mfma_f32_16x16x32_bf16(a, b, acc, 0, 0, 0);
        }
#pragma unroll
        for (int r = 0; r < 4; r++)
            tpw[rt * 16 + lkg * 4 + r][ct * 16 + lr] = f2b(acc[r] * 0.125f);
    }
    __syncthreads();
    const int c = t & 127, seg = t >> 7;
    float a_s0 = 0.f, a_s1 = 0.f;
    float av0 = 0.f, av1 = 0.f, av2 = 0.f, av3 = 0.f, av4 = 0.f, av5 = 0.f, av6 = 0.f, av7 = 0.f, av8 = 0.f;
    int cur_rc = -1;
#define FLUSH_RUN() do { \
        float* ms = msg_s + (long)cur_rc * 256 + c; \
        unsafeAtomicAdd(ms, a_s0); \
        unsafeAtomicAdd(ms + 128, a_s1); \
        float* mv = msg_v + (long)cur_rc * 1152 + c; \
        unsafeAtomicAdd(mv + 0, av0); \
        unsafeAtomicAdd(mv + 128, av1); \
        unsafeAtomicAdd(mv + 256, av2); \
        unsafeAtomicAdd(mv + 384, av3); \
        unsafeAtomicAdd(mv + 512, av4); \
        unsafeAtomicAdd(mv + 640, av5); \
        unsafeAtomicAdd(mv + 768, av6); \
        unsafeAtomicAdd(mv + 896, av7); \
        unsafeAtomicAdd(mv + 1024, av8); \
    } while (0)
    for (int i = 0; i < 16; i++) {
        int idx = seg * 16 + i;
        int rc = rc_l[idx];
        if (rc != cur_rc) {
            if (cur_rc >= 0) FLUSH_RUN();
            cur_rc = rc;
            a_s0 = a_s1 = 0.f;
            av0 = av1 = av2 = av3 = av4 = av5 = av6 = av7 = av8 = 0.f;
        }
        int s = sn_l[idx];
        float es = es_l[idx], ev0 = ev_l[idx][0], ev1 = ev_l[idx][1], ev2 = ev_l[idx][2];
        float w1 = b2f(tpw[idx][c]);
        float w2 = b2f(tpw[idx][128 + c]);
        float w3 = b2f(tpw[idx][256 + c]);
        float w4 = b2f(tpw[idx][384 + c]);
        float w5 = b2f(tpw[idx][512 + c]);
        float xsv = xs[s * 128 + c];
        float x0 = xv[s * 384 + c], x1 = xv[s * 384 + 128 + c], x2 = xv[s * 384 + 256 + c];
        a_s0 += w1 * xsv * es;
        float dve = x0 * ev0 + x1 * ev1 + x2 * ev2;
        a_s1 += w4 * dve * 0.57735026919f;
        float a2 = w2 * xsv;
        av0 += a2 * ev0;
        av1 += w3 * x0 * es;
        av2 += w5 * (x1 * ev2 - x2 * ev1) * 0.70710678119f;
        av3 += a2 * ev1;
        av4 += w3 * x1 * es;
        av5 += w5 * (x2 * ev0 - x0 * ev2) * 0.70710678119f;
        av6 += a2 * ev2;
        av7 += w3 * x2 * es;
        av8 += w5 * (x0 * ev1 - x1 * ev0) * 0.70710678119f;
    }
    FLUSH_RUN();
#undef FLUSH_RUN
}

extern "C" void kernel_launch(void* const* d_in, const int* in_sizes, int n_in,
                              void* d_out, int out_size, void* d_ws, size_t ws_size,
                              hipStream_t stream) {
    const float* node_attrs = (const float*)d_in[0];
    const float* nfs        = (const float*)d_in[1];
    const float* nfv        = (const float*)d_in[2];
    const float* edge_attrs = (const float*)d_in[3];
    const float* edge_feats = (const float*)d_in[4];
    const float* W_sc_s     = (const float*)d_in[5];
    const float* W_sc_v     = (const float*)d_in[6];
    const float* W_lin_s    = (const float*)d_in[7];
    const float* W_lin_v    = (const float*)d_in[8];
    const float* mlp_w0     = (const float*)d_in[9];
    const float* mlp_w1     = (const float*)d_in[10];
    const float* mlp_w2     = (const float*)d_in[11];
    const float* mlp_w3     = (const float*)d_in[12];
    const float* W_out_s    = (const float*)d_in[13];
    const float* W_out_v    = (const float*)d_in[14];
    const int* senders      = (const int*)d_in[15];
    const int* receivers    = (const int*)d_in[16];
    float* dout = (float*)d_out;

    char* W = (char*)d_ws;
    float* xs_ws   = (float*)(W + 0);          // 5,120,000
    float* xv_ws   = (float*)(W + 5120000);    // 15,360,000
    float* msgs_ws = (float*)(W + 20480000);   // 10,240,000
    float* msgv_ws = (float*)(W + 30720000);   // 46,080,000
    unsigned short* h2_ws   = (unsigned short*)(W + 76800000);  // 20,480,000
    unsigned short* wsc_s2  = (unsigned short*)(W + 97280000);  // [10][128][128] bf16
    unsigned short* wsc_v2  = (unsigned short*)(W + 97607680);  // [10][128][128]
    unsigned short* wlin_sT = (unsigned short*)(W + 97935360);
    unsigned short* wlin_vT = (unsigned short*)(W + 97968128);
    unsigned short* wout_sT = (unsigned short*)(W + 98000896);
    unsigned short* wout_vT = (unsigned short*)(W + 98066432);
    unsigned short* w3T     = (unsigned short*)(W + 98164736);  // ends 98,246,656
    int* cnt_ws   = (int*)(W + 98246656);
    int* base_ws  = (int*)(W + 98287616);
    int* cur_ws   = (int*)(W + 98328576);
    int* order_ws = (int*)(W + 98369536);   // ends 99,009,536
    const size_t WS_CSR = 99009536;

    const float inv1280 = 0.02795084972f;
    const float inv128  = 0.08838834765f;
    const float scO_s   = 1.f / 256.f;
    const float scO_v   = 1.f / (19.5959179423f * 16.f);

    k_prep<<<dim3(640, 7, 1), 256, 0, stream>>>(W_sc_s, W_sc_v, W_lin_s, W_lin_v, W_out_s, W_out_v, mlp_w3,
                                                wsc_s2, wsc_v2, wlin_sT, wlin_vT, wout_sT, wout_vT, w3T);
    k_mlp012<<<dim3(2500), 256, 0, stream>>>(edge_feats, mlp_w0, mlp_w1, mlp_w2, h2_ws);

    // sc -> d_out second half (factorized tensor-product GEMM)
    k_sc<<<dim3(157, 4), 256, 0, stream>>>(nfs, nfv, node_attrs, wsc_s2, wsc_v2, dout + 5120000, inv1280);

    // x_s / x_v -> ws
    {
        GemmZ g0{0, nfs,     128, 1, nullptr, wlin_sT, xs_ws,       128, 1, 128, inv128, N_NODES};
        GemmZ g1{0, nfv + 0, 384, 3, nullptr, wlin_vT, xv_ws + 0,   384, 1, 128, inv128, N_NODES};
        GemmZ g2{0, nfv + 1, 384, 3, nullptr, wlin_vT, xv_ws + 128, 384, 1, 128, inv128, N_NODES};
        GemmZ g3{0, nfv + 2, 384, 3, nullptr, wlin_vT, xv_ws + 256, 384, 1, 128, inv128, N_NODES};
        k_gemm<<<dim3(157, 1, 4), 256, 0, stream>>>(g0, g1, g2, g3);
    }

    hipMemsetAsync(msgs_ws, 0, 56320000, stream);  // msg_s + msg_v
    if (ws_size >= WS_CSR) {
        hipMemsetAsync(cnt_ws, 0, 40960, stream);
        k_hist<<<dim3(625), 256, 0, stream>>>(receivers, cnt_ws);
        k_scan<<<dim3(1), 256, 0, stream>>>(cnt_ws, base_ws, cur_ws);
        k_scatter<<<dim3(625), 256, 0, stream>>>(receivers, cur_ws, order_ws);
    }
    k_edge2<<<dim3(5000), 256, 0, stream>>>(h2_ws, w3T, edge_attrs, senders, receivers, order_ws,
                                            xs_ws, xv_ws, msgs_ws, msgv_ws);

    // out = msg @ W_out -> d_out first half
    {
        GemmZ g0{0, msgs_ws,       256,  1, nullptr, wout_sT, dout,           512, 1, 256, scO_s, N_NODES};
        GemmZ g1{0, msgv_ws + 0,   1152, 1, nullptr, wout_vT, dout + 128 + 0, 512, 3, 384, scO_v, N_NODES};
        GemmZ g2{0, msgv_ws + 384, 1152, 1, nullptr, wout_vT, dout + 128 + 1, 512, 3, 384, scO_v, N_NODES};
        GemmZ g3{0, msgv_ws + 768, 1152, 1, nullptr, wout_vT, dout + 128 + 2, 512, 3, 384, scO_v, N_NODES};
        k_gemm<<<dim3(157, 1, 4), 256, 0, stream>>>(g0, g1, g2, g3);
    }
}

// Round 5
// 430.424 us; speedup vs baseline: 2.6733x; 1.2305x over previous
//
#include <hip/hip_runtime.h>

#define N_NODES 10000
#define N_EDGES 160000

typedef float f32x4 __attribute__((ext_vector_type(4)));
typedef short s8v __attribute__((ext_vector_type(8)));
typedef unsigned short u4s __attribute__((ext_vector_type(4)));

__device__ __forceinline__ unsigned short f2b(float f) {
    unsigned u = __builtin_bit_cast(unsigned, f);
    u += 0x7FFFu + ((u >> 16) & 1u);
    return (unsigned short)(u >> 16);
}
__device__ __forceinline__ float b2f(unsigned short s) {
    unsigned u = ((unsigned)s) << 16;
    return __builtin_bit_cast(float, u);
}

// ---------------- prep: weight matrices -> bf16, layouts for MFMA ----------------
// cases 0,1 (sc weights): dst[a*16384 + o*128 + ci] = src[(ci*10+a)*128 + o]   [10][128][128]
// cases 2..8: dst[c*K + k] = src[k*Nc + c]  (B^T layout)
__global__ void k_prep(const float* s0, const float* s1, const float* s2, const float* s3,
                       const float* s4, const float* s5, const float* s6,
                       const float* s7, const float* s8,
                       unsigned short* d0, unsigned short* d1, unsigned short* d2, unsigned short* d3,
                       unsigned short* d4, unsigned short* d5, unsigned short* d6,
                       unsigned short* d7, unsigned short* d8) {
    int idx = blockIdx.x * 256 + threadIdx.x;
    if (blockIdx.y < 2) {
        const float* src = blockIdx.y ? s1 : s0;
        unsigned short* dst = blockIdx.y ? d1 : d0;
        int k = idx >> 7, o = idx & 127;
        int ci = k / 10, a = k - ci * 10;
        dst[a * 16384 + o * 128 + ci] = f2b(src[idx]);
        return;
    }
    const float* src; unsigned short* dst; int K, Nc;
    switch (blockIdx.y) {
        case 2: src = s2; dst = d2; K = 128;  Nc = 128; break;
        case 3: src = s3; dst = d3; K = 128;  Nc = 128; break;
        case 4: src = s4; dst = d4; K = 256;  Nc = 128; break;
        case 5: src = s5; dst = d5; K = 384;  Nc = 128; break;
        case 6: src = s6; dst = d6; K = 64;   Nc = 640; break;
        case 7: src = s7; dst = d7; K = 64;   Nc = 64;  break;
        default: src = s8; dst = d8; K = 64;  Nc = 64;  break;
    }
    if (idx < K * Nc) {
        int k = idx / Nc, c = idx - k * Nc;
        dst[c * K + k] = f2b(src[idx]);
    }
}

// ---------------- sc: out[n, o] = inv1280 * sum_a attr[n,a] * (A_z @ W_a)[n, o] ----------------
__global__ __launch_bounds__(256) void k_sc(const float* __restrict__ nfs,
                                            const float* __restrict__ nfv,
                                            const float* __restrict__ attr,
                                            const unsigned short* __restrict__ Ws2,
                                            const unsigned short* __restrict__ Wv2,
                                            float* __restrict__ out, float scale) {
    __shared__ unsigned short As[64][136];
    __shared__ unsigned short Bs[128][140];
    __shared__ float attr_l[64][10];
    const int t = threadIdx.x;
    const int z = blockIdx.y;
    const int row0 = blockIdx.x * 64;
    const int wv = t >> 6, lane = t & 63, lr = lane & 15, lkg = lane >> 4;

    {
        int r = t >> 2, k0 = (t & 3) * 32;
        int row = row0 + r;
        if (z == 0) {
            if (row < N_NODES) {
#pragma unroll
                for (int j = 0; j < 8; j++) {
                    f32x4 v = *reinterpret_cast<const f32x4*>(nfs + (long)row * 128 + k0 + j * 4);
                    As[r][k0 + j * 4 + 0] = f2b(v[0]);
                    As[r][k0 + j * 4 + 1] = f2b(v[1]);
                    As[r][k0 + j * 4 + 2] = f2b(v[2]);
                    As[r][k0 + j * 4 + 3] = f2b(v[3]);
                }
            } else {
#pragma unroll
                for (int j = 0; j < 32; j++) As[r][k0 + j] = 0;
            }
        } else {
            int i = z - 1;
            if (row < N_NODES) {
#pragma unroll
                for (int j = 0; j < 32; j++)
                    As[r][k0 + j] = f2b(nfv[(long)row * 384 + (k0 + j) * 3 + i]);
            } else {
#pragma unroll
                for (int j = 0; j < 32; j++) As[r][k0 + j] = 0;
            }
        }
    }
    for (int idx = t; idx < 640; idx += 256) {
        int r = idx / 10, a = idx - r * 10;
        int row = row0 + r;
        attr_l[r][a] = (row < N_NODES) ? attr[row * 10 + a] : 0.f;
    }
    __syncthreads();

    s8v af[4];
#pragma unroll
    for (int kk = 0; kk < 4; kk++)
        af[kk] = *reinterpret_cast<const s8v*>(&As[wv * 16 + lr][kk * 32 + lkg * 8]);

    f32x4 accS[8];
#pragma unroll
    for (int i = 0; i < 8; i++) accS[i] = (f32x4){0.f, 0.f, 0.f, 0.f};

    const unsigned short* Wbase = (z == 0) ? Ws2 : Wv2;
    for (int a = 0; a < 10; a++) {
        {
            const unsigned short* src = Wbase + a * 16384;
            int r = t >> 1, c0 = (t & 1) * 64;
#pragma unroll
            for (int j = 0; j < 8; j++) {
                s8v v = *reinterpret_cast<const s8v*>(src + r * 128 + c0 + j * 8);
                *reinterpret_cast<s8v*>(&Bs[r][c0 + j * 8]) = v;
            }
        }
        __syncthreads();
        f32x4 acc[8];
#pragma unroll
        for (int i = 0; i < 8; i++) acc[i] = (f32x4){0.f, 0.f, 0.f, 0.f};
#pragma unroll
        for (int kk = 0; kk < 4; kk++) {
#pragma unroll
            for (int ct = 0; ct < 8; ct++) {
                s8v bf = *reinterpret_cast<const s8v*>(&Bs[ct * 16 + lr][kk * 32 + lkg * 8]);
                acc[ct] = __builtin_amdgcn_mfma_f32_16x16x32_bf16(af[kk], bf, acc[ct], 0, 0, 0);
            }
        }
#pragma unroll
        for (int r = 0; r < 4; r++) {
            float aw = attr_l[wv * 16 + lkg * 4 + r][a];
#pragma unroll
            for (int ct = 0; ct < 8; ct++)
                accS[ct][r] += aw * acc[ct][r];
        }
        __syncthreads();
    }
#pragma unroll
    for (int ct = 0; ct < 8; ct++) {
#pragma unroll
        for (int r = 0; r < 4; r++) {
            int row = row0 + wv * 16 + lkg * 4 + r;
            if (row < N_NODES) {
                int col = ct * 16 + lr;
                if (z == 0) out[(long)row * 512 + col] = accS[ct][r] * scale;
                else        out[(long)row * 512 + 128 + col * 3 + (z - 1)] = accS[ct][r] * scale;
            }
        }
    }
}

// ---------------- generic MFMA GEMM (x and out GEMMs) ----------------
struct GemmZ {
    const float* Ap;
    int ars, aks;
    const unsigned short* Bt;
    float* Cp;                 // f32 out, or (bf16 out if obf16: cast to ushort*)
    int crs, ccs;
    int K;
    float scale;
    int M;
    int obf16;
};

__global__ __launch_bounds__(256) void k_gemm(GemmZ g0, GemmZ g1, GemmZ g2, GemmZ g3) {
    GemmZ g;
    switch (blockIdx.z) { case 0: g = g0; break; case 1: g = g1; break; case 2: g = g2; break; default: g = g3; }
    __shared__ unsigned short As[64][40];
    const int t = threadIdx.x;
    const int wv = t >> 6, lane = t & 63;
    const int lr = lane & 15, lkg = lane >> 4;
    const int row0 = blockIdx.x * 64;
    const int br = t >> 2;
    const int bk0 = (t & 3) * 8;
    const int arow = row0 + br;

    f32x4 acc[8];
#pragma unroll
    for (int i = 0; i < 8; i++) acc[i] = (f32x4){0.f, 0.f, 0.f, 0.f};

    for (int k0 = 0; k0 < g.K; k0 += 32) {
        s8v av;
        if (arow < g.M) {
#pragma unroll
            for (int j = 0; j < 8; j++)
                av[j] = (short)f2b(g.Ap[(long)arow * g.ars + (long)(k0 + bk0 + j) * g.aks]);
        } else {
#pragma unroll
            for (int j = 0; j < 8; j++) av[j] = 0;
        }
        __syncthreads();
        *reinterpret_cast<s8v*>(&As[br][bk0]) = av;
        __syncthreads();
        s8v af = *reinterpret_cast<const s8v*>(&As[wv * 16 + lr][lkg * 8]);
#pragma unroll
        for (int ct = 0; ct < 8; ct++) {
            const unsigned short* bp = g.Bt + (long)(ct * 16 + lr) * g.K + k0 + lkg * 8;
            s8v bf = *reinterpret_cast<const s8v*>(bp);
            acc[ct] = __builtin_amdgcn_mfma_f32_16x16x32_bf16(af, bf, acc[ct], 0, 0, 0);
        }
    }
#pragma unroll
    for (int ct = 0; ct < 8; ct++) {
#pragma unroll
        for (int r = 0; r < 4; r++) {
            int row = row0 + wv * 16 + lkg * 4 + r;
            if (row < g.M) {
                int col = ct * 16 + lr;
                if (g.obf16)
                    ((unsigned short*)g.Cp)[(long)row * g.crs + col * g.ccs] = f2b(acc[ct][r] * g.scale);
                else
                    g.Cp[(long)row * g.crs + col * g.ccs] = acc[ct][r] * g.scale;
            }
        }
    }
}

// ---------------- MLP: layer0 VALU, layers 1-2 MFMA ----------------
__global__ __launch_bounds__(256) void k_mlp012(const float* __restrict__ ef, const float* __restrict__ w0,
                                                const unsigned short* __restrict__ w1T,
                                                const unsigned short* __restrict__ w2T,
                                                unsigned short* __restrict__ h2out) {
    __shared__ float efs[64][8];
    __shared__ unsigned short hA[64][72];
    __shared__ unsigned short hB[64][72];
    const int t = threadIdx.x;
    const long e0 = (long)blockIdx.x * 64;
#pragma unroll
    for (int j = 0; j < 2; j++) { int idx = t + j * 256; ((float*)efs)[idx] = ef[e0 * 8 + idx]; }
    const int o = t & 63, ebase = t >> 6;
    float w0r[8];
#pragma unroll
    for (int k = 0; k < 8; k++) w0r[k] = w0[k * 64 + o];
    __syncthreads();
#pragma unroll
    for (int j = 0; j < 16; j++) {
        int e = ebase * 16 + j;
        float acc = 0.f;
#pragma unroll
        for (int k = 0; k < 8; k++) acc += efs[e][k] * w0r[k];
        acc *= 0.35355339059f;  // 1/sqrt(8)
        hA[e][o] = f2b(acc / (1.f + __expf(-acc)));
    }
    __syncthreads();
    const int wv = t >> 6, lane = t & 63, lr = lane & 15, lkg = lane >> 4;
    // layer1: rows = wv*16..+16, cols = 64
    {
        f32x4 acc1[4];
#pragma unroll
        for (int ct = 0; ct < 4; ct++) acc1[ct] = (f32x4){0.f, 0.f, 0.f, 0.f};
#pragma unroll
        for (int kk = 0; kk < 2; kk++) {
            s8v a = *reinterpret_cast<const s8v*>(&hA[wv * 16 + lr][kk * 32 + lkg * 8]);
#pragma unroll
            for (int ct = 0; ct < 4; ct++) {
                s8v b = *reinterpret_cast<const s8v*>(w1T + (ct * 16 + lr) * 64 + kk * 32 + lkg * 8);
                acc1[ct] = __builtin_amdgcn_mfma_f32_16x16x32_bf16(a, b, acc1[ct], 0, 0, 0);
            }
        }
#pragma unroll
        for (int ct = 0; ct < 4; ct++)
#pragma unroll
            for (int r = 0; r < 4; r++) {
                float v = acc1[ct][r] * 0.125f;  // 1/sqrt(64)
                hB[wv * 16 + lkg * 4 + r][ct * 16 + lr] = f2b(v / (1.f + __expf(-v)));
            }
    }
    __syncthreads();
    // layer2 -> global
    {
        f32x4 acc2[4];
#pragma unroll
        for (int ct = 0; ct < 4; ct++) acc2[ct] = (f32x4){0.f, 0.f, 0.f, 0.f};
#pragma unroll
        for (int kk = 0; kk < 2; kk++) {
            s8v a = *reinterpret_cast<const s8v*>(&hB[wv * 16 + lr][kk * 32 + lkg * 8]);
#pragma unroll
            for (int ct = 0; ct < 4; ct++) {
                s8v b = *reinterpret_cast<const s8v*>(w2T + (ct * 16 + lr) * 64 + kk * 32 + lkg * 8);
                acc2[ct] = __builtin_amdgcn_mfma_f32_16x16x32_bf16(a, b, acc2[ct], 0, 0, 0);
            }
        }
#pragma unroll
        for (int ct = 0; ct < 4; ct++)
#pragma unroll
            for (int r = 0; r < 4; r++) {
                float v = acc2[ct][r] * 0.125f;
                int row = wv * 16 + lkg * 4 + r;
                h2out[(e0 + row) * 64 + ct * 16 + lr] = f2b(v / (1.f + __expf(-v)));
            }
    }
}

// ---------------- CSR build ----------------
__global__ void k_hist(const int* __restrict__ rcv, int* __restrict__ cnt) {
    int e = blockIdx.x * 256 + threadIdx.x;
    if (e < N_EDGES) atomicAdd(&cnt[rcv[e]], 1);
}

__global__ __launch_bounds__(256) void k_scan(const int* __restrict__ cnt, int* __restrict__ base, int* __restrict__ cur) {
    __shared__ int s[256];
    const int t = threadIdx.x;
    const int c0 = t * 40;
    int sum = 0;
    for (int i = 0; i < 40; i++) sum += cnt[c0 + i];
    s[t] = sum;
    __syncthreads();
    for (int off = 1; off < 256; off <<= 1) {
        int v = (t >= off) ? s[t - off] : 0;
        __syncthreads();
        s[t] += v;
        __syncthreads();
    }
    int run = t ? s[t - 1] : 0;
    for (int i = 0; i < 40; i++) {
        int idx = c0 + i;
        if (idx <= N_NODES) { base[idx] = run; cur[idx] = run; }
        run += cnt[idx];
    }
}

__global__ void k_scatter(const int* __restrict__ rcv, int* __restrict__ cur, int* __restrict__ order) {
    int e = blockIdx.x * 256 + threadIdx.x;
    if (e < N_EDGES) {
        int p = atomicAdd(&cur[rcv[e]], 1);
        order[p] = e;
    }
}

// ---------------- fused per-edge, sorted-by-receiver, run-reduced atomics ----------------
__global__ __launch_bounds__(256) void k_edge2(const unsigned short* __restrict__ h2,
                                               const unsigned short* __restrict__ w3T,
                                               const float* __restrict__ eattr,
                                               const int* __restrict__ snd, const int* __restrict__ rcv,
                                               const int* __restrict__ order,
                                               const unsigned short* __restrict__ xpack,
                                               float* __restrict__ msg_s, float* __restrict__ msg_v) {
    __shared__ unsigned short h2s[32][72];
    __shared__ unsigned short tpw[32][644];
    __shared__ float es_l[32];
    __shared__ float ev_l[32][3];
    __shared__ int sn_l[32], rc_l[32];
    const int t = threadIdx.x;
    const int j0 = blockIdx.x * 32;
    {
        int r = t >> 3, kk = (t & 7) * 8;
        int e = order[j0 + r];
        s8v v = *reinterpret_cast<const s8v*>(h2 + (long)e * 64 + kk);
        *reinterpret_cast<s8v*>(&h2s[r][kk]) = v;
    }
    if (t < 32) {
        int e = order[j0 + t];
        es_l[t] = eattr[e * 4 + 0];
        ev_l[t][0] = eattr[e * 4 + 1];
        ev_l[t][1] = eattr[e * 4 + 2];
        ev_l[t][2] = eattr[e * 4 + 3];
        sn_l[t] = snd[e];
        rc_l[t] = rcv[e];
    }
    __syncthreads();
    const int wv = t >> 6, lane = t & 63, lr = lane & 15, lkg = lane >> 4;
#pragma unroll
    for (int p = 0; p < 20; p++) {
        int ct = wv + 4 * (p % 10);
        int rt = p / 10;
        f32x4 acc = (f32x4){0.f, 0.f, 0.f, 0.f};
#pragma unroll
        for (int ks = 0; ks < 2; ks++) {
            s8v a = *reinterpret_cast<const s8v*>(&h2s[rt * 16 + lr][ks * 32 + lkg * 8]);
            s8v b = *reinterpret_cast<const s8v*>(w3T + (long)(ct * 16 + lr) * 64 + ks * 32 + lkg * 8);
            acc = __builtin_amdgcn_mfma_f32_16x16x32_bf16(a, b, acc, 0, 0, 0);
        }
#pragma unroll
        for (int r = 0; r < 4; r++)
            tpw[rt * 16 + lkg * 4 + r][ct * 16 + lr] = f2b(acc[r] * 0.125f);
    }
    __syncthreads();
    const int c = t & 127, seg = t >> 7;
    float a_s0 = 0.f, a_s1 = 0.f;
    float av0 = 0.f, av1 = 0.f, av2 = 0.f, av3 = 0.f, av4 = 0.f, av5 = 0.f, av6 = 0.f, av7 = 0.f, av8 = 0.f;
    int cur_rc = -1;
#define FLUSH_RUN() do { \
        float* ms = msg_s + (long)cur_rc * 256 + c; \
        unsafeAtomicAdd(ms, a_s0); \
        unsafeAtomicAdd(ms + 128, a_s1); \
        float* mv = msg_v + (long)cur_rc * 1152 + c; \
        unsafeAtomicAdd(mv + 0, av0); \
        unsafeAtomicAdd(mv + 128, av1); \
        unsafeAtomicAdd(mv + 256, av2); \
        unsafeAtomicAdd(mv + 384, av3); \
        unsafeAtomicAdd(mv + 512, av4); \
        unsafeAtomicAdd(mv + 640, av5); \
        unsafeAtomicAdd(mv + 768, av6); \
        unsafeAtomicAdd(mv + 896, av7); \
        unsafeAtomicAdd(mv + 1024, av8); \
    } while (0)
    for (int i = 0; i < 16; i++) {
        int idx = seg * 16 + i;
        int rc = rc_l[idx];
        if (rc != cur_rc) {
            if (cur_rc >= 0) FLUSH_RUN();
            cur_rc = rc;
            a_s0 = a_s1 = 0.f;
            av0 = av1 = av2 = av3 = av4 = av5 = av6 = av7 = av8 = 0.f;
        }
        int s = sn_l[idx];
        float es = es_l[idx], ev0 = ev_l[idx][0], ev1 = ev_l[idx][1], ev2 = ev_l[idx][2];
        float w1 = b2f(tpw[idx][c]);
        float w2 = b2f(tpw[idx][128 + c]);
        float w3 = b2f(tpw[idx][256 + c]);
        float w4 = b2f(tpw[idx][384 + c]);
        float w5 = b2f(tpw[idx][512 + c]);
        u4s xp = *reinterpret_cast<const u4s*>(xpack + (long)s * 512 + c * 4);
        float xsv = b2f(xp[0]);
        float x0 = b2f(xp[1]), x1 = b2f(xp[2]), x2 = b2f(xp[3]);
        a_s0 += w1 * xsv * es;
        float dve = x0 * ev0 + x1 * ev1 + x2 * ev2;
        a_s1 += w4 * dve * 0.57735026919f;
        float a2 = w2 * xsv;
        av0 += a2 * ev0;
        av1 += w3 * x0 * es;
        av2 += w5 * (x1 * ev2 - x2 * ev1) * 0.70710678119f;
        av3 += a2 * ev1;
        av4 += w3 * x1 * es;
        av5 += w5 * (x2 * ev0 - x0 * ev2) * 0.70710678119f;
        av6 += a2 * ev2;
        av7 += w3 * x2 * es;
        av8 += w5 * (x0 * ev1 - x1 * ev0) * 0.70710678119f;
    }
    FLUSH_RUN();
#undef FLUSH_RUN
}

extern "C" void kernel_launch(void* const* d_in, const int* in_sizes, int n_in,
                              void* d_out, int out_size, void* d_ws, size_t ws_size,
                              hipStream_t stream) {
    const float* node_attrs = (const float*)d_in[0];
    const float* nfs        = (const float*)d_in[1];
    const float* nfv        = (const float*)d_in[2];
    const float* edge_attrs = (const float*)d_in[3];
    const float* edge_feats = (const float*)d_in[4];
    const float* W_sc_s     = (const float*)d_in[5];
    const float* W_sc_v     = (const float*)d_in[6];
    const float* W_lin_s    = (const float*)d_in[7];
    const float* W_lin_v    = (const float*)d_in[8];
    const float* mlp_w0     = (const float*)d_in[9];
    const float* mlp_w1     = (const float*)d_in[10];
    const float* mlp_w2     = (const float*)d_in[11];
    const float* mlp_w3     = (const float*)d_in[12];
    const float* W_out_s    = (const float*)d_in[13];
    const float* W_out_v    = (const float*)d_in[14];
    const int* senders      = (const int*)d_in[15];
    const int* receivers    = (const int*)d_in[16];
    float* dout = (float*)d_out;

    char* W = (char*)d_ws;
    unsigned short* xpack_ws = (unsigned short*)(W + 0);        // N*128*4 bf16 = 10,240,000
    float* msgs_ws = (float*)(W + 10240000);   // 10,240,000
    float* msgv_ws = (float*)(W + 20480000);   // 46,080,000 -> ends 66,560,000
    unsigned short* h2_ws   = (unsigned short*)(W + 66560000);  // 20,480,000 -> ends 87,040,000
    unsigned short* wsc_s2  = (unsigned short*)(W + 87040000);  // 327,680
    unsigned short* wsc_v2  = (unsigned short*)(W + 87367680);  // 327,680
    unsigned short* wlin_sT = (unsigned short*)(W + 87695360);  // 32,768
    unsigned short* wlin_vT = (unsigned short*)(W + 87728128);  // 32,768
    unsigned short* wout_sT = (unsigned short*)(W + 87760896);  // 65,536
    unsigned short* wout_vT = (unsigned short*)(W + 87826432);  // 98,304
    unsigned short* w3T     = (unsigned short*)(W + 87924736);  // 81,920 -> ends 88,006,656
    unsigned short* w1T     = (unsigned short*)(W + 88006656);  // 8,192
    unsigned short* w2T     = (unsigned short*)(W + 88014848);  // 8,192 -> ends 88,023,040
    int* cnt_ws   = (int*)(W + 88023040);
    int* base_ws  = (int*)(W + 88064000);
    int* cur_ws   = (int*)(W + 88104960);
    int* order_ws = (int*)(W + 88145920);   // 640,000 -> ends 88,785,920

    const float inv1280 = 0.02795084972f;
    const float inv128  = 0.08838834765f;
    const float scO_s   = 1.f / 256.f;
    const float scO_v   = 1.f / (19.5959179423f * 16.f);

    k_prep<<<dim3(640, 9, 1), 256, 0, stream>>>(W_sc_s, W_sc_v, W_lin_s, W_lin_v, W_out_s, W_out_v, mlp_w3,
                                                mlp_w1, mlp_w2,
                                                wsc_s2, wsc_v2, wlin_sT, wlin_vT, wout_sT, wout_vT, w3T,
                                                w1T, w2T);
    k_mlp012<<<dim3(2500), 256, 0, stream>>>(edge_feats, mlp_w0, w1T, w2T, h2_ws);

    // sc -> d_out second half (factorized tensor-product GEMM)
    k_sc<<<dim3(157, 4), 256, 0, stream>>>(nfs, nfv, node_attrs, wsc_s2, wsc_v2, dout + 5120000, inv1280);

    // x_s / x_v -> xpack (bf16, interleaved [n][c][4])
    {
        GemmZ g0{nfs,     128, 1, wlin_sT, (float*)(xpack_ws + 0), 512, 4, 128, inv128, N_NODES, 1};
        GemmZ g1{nfv + 0, 384, 3, wlin_vT, (float*)(xpack_ws + 1), 512, 4, 128, inv128, N_NODES, 1};
        GemmZ g2{nfv + 1, 384, 3, wlin_vT, (float*)(xpack_ws + 2), 512, 4, 128, inv128, N_NODES, 1};
        GemmZ g3{nfv + 2, 384, 3, wlin_vT, (float*)(xpack_ws + 3), 512, 4, 128, inv128, N_NODES, 1};
        k_gemm<<<dim3(157, 1, 4), 256, 0, stream>>>(g0, g1, g2, g3);
    }

    hipMemsetAsync(msgs_ws, 0, 56320000, stream);  // msg_s + msg_v
    hipMemsetAsync(cnt_ws, 0, 40960, stream);
    k_hist<<<dim3(625), 256, 0, stream>>>(receivers, cnt_ws);
    k_scan<<<dim3(1), 256, 0, stream>>>(cnt_ws, base_ws, cur_ws);
    k_scatter<<<dim3(625), 256, 0, stream>>>(receivers, cur_ws, order_ws);
    k_edge2<<<dim3(5000), 256, 0, stream>>>(h2_ws, w3T, edge_attrs, senders, receivers, order_ws,
                                            xpack_ws, msgs_ws, msgv_ws);

    // out = msg @ W_out -> d_out first half
    {
        GemmZ g0{msgs_ws,       256,  1, wout_sT, dout,           512, 1, 256, scO_s, N_NODES, 0};
        GemmZ g1{msgv_ws + 0,   1152, 1, wout_vT, dout + 128 + 0, 512, 3, 384, scO_v, N_NODES, 0};
        GemmZ g2{msgv_ws + 384, 1152, 1, wout_vT, dout + 128 + 1, 512, 3, 384, scO_v, N_NODES, 0};
        GemmZ g3{msgv_ws + 768, 1152, 1, wout_vT, dout + 128 + 2, 512, 3, 384, scO_v, N_NODES, 0};
        k_gemm<<<dim3(157, 1, 4), 256, 0, stream>>>(g0, g1, g2, g3);
    }
}

// Round 6
// 398.358 us; speedup vs baseline: 2.8885x; 1.0805x over previous
//
#include <hip/hip_runtime.h>

#define N_NODES 10000
#define N_EDGES 160000

typedef float f32x4 __attribute__((ext_vector_type(4)));
typedef short s8v __attribute__((ext_vector_type(8)));
typedef unsigned short u4s __attribute__((ext_vector_type(4)));

__device__ __forceinline__ unsigned short f2b(float f) {
    unsigned u = __builtin_bit_cast(unsigned, f);
    u += 0x7FFFu + ((u >> 16) & 1u);
    return (unsigned short)(u >> 16);
}
__device__ __forceinline__ float b2f(unsigned short s) {
    unsigned u = ((unsigned)s) << 16;
    return __builtin_bit_cast(float, u);
}

// ---------------- prep: weight matrices -> bf16, layouts for MFMA ----------------
__global__ void k_prep(const float* s0, const float* s1, const float* s2, const float* s3,
                       const float* s4, const float* s5, const float* s6,
                       const float* s7, const float* s8,
                       unsigned short* d0, unsigned short* d1, unsigned short* d2, unsigned short* d3,
                       unsigned short* d4, unsigned short* d5, unsigned short* d6,
                       unsigned short* d7, unsigned short* d8) {
    int idx = blockIdx.x * 256 + threadIdx.x;
    if (blockIdx.y < 2) {
        const float* src = blockIdx.y ? s1 : s0;
        unsigned short* dst = blockIdx.y ? d1 : d0;
        int k = idx >> 7, o = idx & 127;
        int ci = k / 10, a = k - ci * 10;
        dst[a * 16384 + o * 128 + ci] = f2b(src[idx]);
        return;
    }
    const float* src; unsigned short* dst; int K, Nc;
    switch (blockIdx.y) {
        case 2: src = s2; dst = d2; K = 128;  Nc = 128; break;
        case 3: src = s3; dst = d3; K = 128;  Nc = 128; break;
        case 4: src = s4; dst = d4; K = 256;  Nc = 128; break;
        case 5: src = s5; dst = d5; K = 384;  Nc = 128; break;
        case 6: src = s6; dst = d6; K = 64;   Nc = 640; break;
        case 7: src = s7; dst = d7; K = 64;   Nc = 64;  break;
        default: src = s8; dst = d8; K = 64;  Nc = 64;  break;
    }
    if (idx < K * Nc) {
        int k = idx / Nc, c = idx - k * Nc;
        dst[c * K + k] = f2b(src[idx]);
    }
}

// ---------------- sc: out[n, o] = inv1280 * sum_a attr[n,a] * (A_z @ W_a)[n, o] ----------------
__global__ __launch_bounds__(256) void k_sc(const float* __restrict__ nfs,
                                            const float* __restrict__ nfv,
                                            const float* __restrict__ attr,
                                            const unsigned short* __restrict__ Ws2,
                                            const unsigned short* __restrict__ Wv2,
                                            float* __restrict__ out, float scale) {
    __shared__ unsigned short As[64][136];
    __shared__ unsigned short Bs[128][140];
    __shared__ float attr_l[64][10];
    const int t = threadIdx.x;
    const int z = blockIdx.y;
    const int row0 = blockIdx.x * 64;
    const int wv = t >> 6, lane = t & 63, lr = lane & 15, lkg = lane >> 4;

    {
        int r = t >> 2, k0 = (t & 3) * 32;
        int row = row0 + r;
        if (z == 0) {
            if (row < N_NODES) {
#pragma unroll
                for (int j = 0; j < 8; j++) {
                    f32x4 v = *reinterpret_cast<const f32x4*>(nfs + (long)row * 128 + k0 + j * 4);
                    As[r][k0 + j * 4 + 0] = f2b(v[0]);
                    As[r][k0 + j * 4 + 1] = f2b(v[1]);
                    As[r][k0 + j * 4 + 2] = f2b(v[2]);
                    As[r][k0 + j * 4 + 3] = f2b(v[3]);
                }
            } else {
#pragma unroll
                for (int j = 0; j < 32; j++) As[r][k0 + j] = 0;
            }
        } else {
            int i = z - 1;
            if (row < N_NODES) {
#pragma unroll
                for (int j = 0; j < 32; j++)
                    As[r][k0 + j] = f2b(nfv[(long)row * 384 + (k0 + j) * 3 + i]);
            } else {
#pragma unroll
                for (int j = 0; j < 32; j++) As[r][k0 + j] = 0;
            }
        }
    }
    for (int idx = t; idx < 640; idx += 256) {
        int r = idx / 10, a = idx - r * 10;
        int row = row0 + r;
        attr_l[r][a] = (row < N_NODES) ? attr[row * 10 + a] : 0.f;
    }
    __syncthreads();

    s8v af[4];
#pragma unroll
    for (int kk = 0; kk < 4; kk++)
        af[kk] = *reinterpret_cast<const s8v*>(&As[wv * 16 + lr][kk * 32 + lkg * 8]);

    f32x4 accS[8];
#pragma unroll
    for (int i = 0; i < 8; i++) accS[i] = (f32x4){0.f, 0.f, 0.f, 0.f};

    const unsigned short* Wbase = (z == 0) ? Ws2 : Wv2;
    for (int a = 0; a < 10; a++) {
        {
            const unsigned short* src = Wbase + a * 16384;
            int r = t >> 1, c0 = (t & 1) * 64;
#pragma unroll
            for (int j = 0; j < 8; j++) {
                s8v v = *reinterpret_cast<const s8v*>(src + r * 128 + c0 + j * 8);
                *reinterpret_cast<s8v*>(&Bs[r][c0 + j * 8]) = v;
            }
        }
        __syncthreads();
        f32x4 acc[8];
#pragma unroll
        for (int i = 0; i < 8; i++) acc[i] = (f32x4){0.f, 0.f, 0.f, 0.f};
#pragma unroll
        for (int kk = 0; kk < 4; kk++) {
#pragma unroll
            for (int ct = 0; ct < 8; ct++) {
                s8v bf = *reinterpret_cast<const s8v*>(&Bs[ct * 16 + lr][kk * 32 + lkg * 8]);
                acc[ct] = __builtin_amdgcn_mfma_f32_16x16x32_bf16(af[kk], bf, acc[ct], 0, 0, 0);
            }
        }
#pragma unroll
        for (int r = 0; r < 4; r++) {
            float aw = attr_l[wv * 16 + lkg * 4 + r][a];
#pragma unroll
            for (int ct = 0; ct < 8; ct++)
                accS[ct][r] += aw * acc[ct][r];
        }
        __syncthreads();
    }
#pragma unroll
    for (int ct = 0; ct < 8; ct++) {
#pragma unroll
        for (int r = 0; r < 4; r++) {
            int row = row0 + wv * 16 + lkg * 4 + r;
            if (row < N_NODES) {
                int col = ct * 16 + lr;
                if (z == 0) out[(long)row * 512 + col] = accS[ct][r] * scale;
                else        out[(long)row * 512 + 128 + col * 3 + (z - 1)] = accS[ct][r] * scale;
            }
        }
    }
}

// ---------------- generic MFMA GEMM (x and out GEMMs) ----------------
struct GemmZ {
    const float* Ap;
    int ars, aks;
    const unsigned short* Bt;
    float* Cp;
    int crs, ccs;
    int K;
    float scale;
    int M;
    int obf16;
};

__global__ __launch_bounds__(256) void k_gemm(GemmZ g0, GemmZ g1, GemmZ g2, GemmZ g3) {
    GemmZ g;
    switch (blockIdx.z) { case 0: g = g0; break; case 1: g = g1; break; case 2: g = g2; break; default: g = g3; }
    __shared__ unsigned short As[64][40];
    const int t = threadIdx.x;
    const int wv = t >> 6, lane = t & 63;
    const int lr = lane & 15, lkg = lane >> 4;
    const int row0 = blockIdx.x * 64;
    const int br = t >> 2;
    const int bk0 = (t & 3) * 8;
    const int arow = row0 + br;

    f32x4 acc[8];
#pragma unroll
    for (int i = 0; i < 8; i++) acc[i] = (f32x4){0.f, 0.f, 0.f, 0.f};

    for (int k0 = 0; k0 < g.K; k0 += 32) {
        s8v av;
        if (arow < g.M) {
#pragma unroll
            for (int j = 0; j < 8; j++)
                av[j] = (short)f2b(g.Ap[(long)arow * g.ars + (long)(k0 + bk0 + j) * g.aks]);
        } else {
#pragma unroll
            for (int j = 0; j < 8; j++) av[j] = 0;
        }
        __syncthreads();
        *reinterpret_cast<s8v*>(&As[br][bk0]) = av;
        __syncthreads();
        s8v af = *reinterpret_cast<const s8v*>(&As[wv * 16 + lr][lkg * 8]);
#pragma unroll
        for (int ct = 0; ct < 8; ct++) {
            const unsigned short* bp = g.Bt + (long)(ct * 16 + lr) * g.K + k0 + lkg * 8;
            s8v bf = *reinterpret_cast<const s8v*>(bp);
            acc[ct] = __builtin_amdgcn_mfma_f32_16x16x32_bf16(af, bf, acc[ct], 0, 0, 0);
        }
    }
#pragma unroll
    for (int ct = 0; ct < 8; ct++) {
#pragma unroll
        for (int r = 0; r < 4; r++) {
            int row = row0 + wv * 16 + lkg * 4 + r;
            if (row < g.M) {
                int col = ct * 16 + lr;
                if (g.obf16)
                    ((unsigned short*)g.Cp)[(long)row * g.crs + col * g.ccs] = f2b(acc[ct][r] * g.scale);
                else
                    g.Cp[(long)row * g.crs + col * g.ccs] = acc[ct][r] * g.scale;
            }
        }
    }
}

// ---------------- MLP: layer0 VALU, layers 1-2 MFMA ----------------
__global__ __launch_bounds__(256) void k_mlp012(const float* __restrict__ ef, const float* __restrict__ w0,
                                                const unsigned short* __restrict__ w1T,
                                                const unsigned short* __restrict__ w2T,
                                                unsigned short* __restrict__ h2out) {
    __shared__ float efs[64][8];
    __shared__ unsigned short hA[64][72];
    __shared__ unsigned short hB[64][72];
    const int t = threadIdx.x;
    const long e0 = (long)blockIdx.x * 64;
#pragma unroll
    for (int j = 0; j < 2; j++) { int idx = t + j * 256; ((float*)efs)[idx] = ef[e0 * 8 + idx]; }
    const int o = t & 63, ebase = t >> 6;
    float w0r[8];
#pragma unroll
    for (int k = 0; k < 8; k++) w0r[k] = w0[k * 64 + o];
    __syncthreads();
#pragma unroll
    for (int j = 0; j < 16; j++) {
        int e = ebase * 16 + j;
        float acc = 0.f;
#pragma unroll
        for (int k = 0; k < 8; k++) acc += efs[e][k] * w0r[k];
        acc *= 0.35355339059f;
        hA[e][o] = f2b(acc / (1.f + __expf(-acc)));
    }
    __syncthreads();
    const int wv = t >> 6, lane = t & 63, lr = lane & 15, lkg = lane >> 4;
    {
        f32x4 acc1[4];
#pragma unroll
        for (int ct = 0; ct < 4; ct++) acc1[ct] = (f32x4){0.f, 0.f, 0.f, 0.f};
#pragma unroll
        for (int kk = 0; kk < 2; kk++) {
            s8v a = *reinterpret_cast<const s8v*>(&hA[wv * 16 + lr][kk * 32 + lkg * 8]);
#pragma unroll
            for (int ct = 0; ct < 4; ct++) {
                s8v b = *reinterpret_cast<const s8v*>(w1T + (ct * 16 + lr) * 64 + kk * 32 + lkg * 8);
                acc1[ct] = __builtin_amdgcn_mfma_f32_16x16x32_bf16(a, b, acc1[ct], 0, 0, 0);
            }
        }
#pragma unroll
        for (int ct = 0; ct < 4; ct++)
#pragma unroll
            for (int r = 0; r < 4; r++) {
                float v = acc1[ct][r] * 0.125f;
                hB[wv * 16 + lkg * 4 + r][ct * 16 + lr] = f2b(v / (1.f + __expf(-v)));
            }
    }
    __syncthreads();
    {
        f32x4 acc2[4];
#pragma unroll
        for (int ct = 0; ct < 4; ct++) acc2[ct] = (f32x4){0.f, 0.f, 0.f, 0.f};
#pragma unroll
        for (int kk = 0; kk < 2; kk++) {
            s8v a = *reinterpret_cast<const s8v*>(&hB[wv * 16 + lr][kk * 32 + lkg * 8]);
#pragma unroll
            for (int ct = 0; ct < 4; ct++) {
                s8v b = *reinterpret_cast<const s8v*>(w2T + (ct * 16 + lr) * 64 + kk * 32 + lkg * 8);
                acc2[ct] = __builtin_amdgcn_mfma_f32_16x16x32_bf16(a, b, acc2[ct], 0, 0, 0);
            }
        }
#pragma unroll
        for (int ct = 0; ct < 4; ct++)
#pragma unroll
            for (int r = 0; r < 4; r++) {
                float v = acc2[ct][r] * 0.125f;
                int row = wv * 16 + lkg * 4 + r;
                h2out[(e0 + row) * 64 + ct * 16 + lr] = f2b(v / (1.f + __expf(-v)));
            }
    }
}

// ---------------- CSR build ----------------
__global__ void k_hist(const int* __restrict__ rcv, int* __restrict__ cnt) {
    int e = blockIdx.x * 256 + threadIdx.x;
    if (e < N_EDGES) atomicAdd(&cnt[rcv[e]], 1);
}

__global__ __launch_bounds__(256) void k_scan(const int* __restrict__ cnt, int* __restrict__ base, int* __restrict__ cur) {
    __shared__ int s[256];
    const int t = threadIdx.x;
    const int c0 = t * 40;
    int sum = 0;
    for (int i = 0; i < 40; i++) sum += cnt[c0 + i];
    s[t] = sum;
    __syncthreads();
    for (int off = 1; off < 256; off <<= 1) {
        int v = (t >= off) ? s[t - off] : 0;
        __syncthreads();
        s[t] += v;
        __syncthreads();
    }
    int run = t ? s[t - 1] : 0;
    for (int i = 0; i < 40; i++) {
        int idx = c0 + i;
        if (idx <= N_NODES) { base[idx] = run; cur[idx] = run; }
        run += cnt[idx];
    }
}

__global__ void k_scatter(const int* __restrict__ rcv, int* __restrict__ cur, int* __restrict__ order) {
    int e = blockIdx.x * 256 + threadIdx.x;
    if (e < N_EDGES) {
        int p = atomicAdd(&cur[rcv[e]], 1);
        order[p] = e;
    }
}

// ---------------- fused per-edge, sorted-by-receiver, prefetched accumulate ----------------
__global__ __launch_bounds__(256, 3) void k_edge2(const unsigned short* __restrict__ h2,
                                                  const unsigned short* __restrict__ w3T,
                                                  const float* __restrict__ eattr,
                                                  const int* __restrict__ snd, const int* __restrict__ rcv,
                                                  const int* __restrict__ order,
                                                  const unsigned short* __restrict__ xpack,
                                                  float* __restrict__ msg_s, float* __restrict__ msg_v) {
    __shared__ unsigned short h2s[32][72];
    __shared__ unsigned short tpw[32][644];
    __shared__ float es_l[32];
    __shared__ float ev_l[32][3];
    __shared__ int sn_l[32], rc_l[32];
    const int t = threadIdx.x;
    const int j0 = blockIdx.x * 32;
    {
        int r = t >> 3, kk = (t & 7) * 8;
        int e = order[j0 + r];
        s8v v = *reinterpret_cast<const s8v*>(h2 + (long)e * 64 + kk);
        *reinterpret_cast<s8v*>(&h2s[r][kk]) = v;
    }
    if (t < 32) {
        int e = order[j0 + t];
        es_l[t] = eattr[e * 4 + 0];
        ev_l[t][0] = eattr[e * 4 + 1];
        ev_l[t][1] = eattr[e * 4 + 2];
        ev_l[t][2] = eattr[e * 4 + 3];
        sn_l[t] = snd[e];
        rc_l[t] = rcv[e];
    }
    __syncthreads();
    const int wv = t >> 6, lane = t & 63, lr = lane & 15, lkg = lane >> 4;
#pragma unroll
    for (int p = 0; p < 20; p++) {
        int ct = wv + 4 * (p % 10);
        int rt = p / 10;
        f32x4 acc = (f32x4){0.f, 0.f, 0.f, 0.f};
#pragma unroll
        for (int ks = 0; ks < 2; ks++) {
            s8v a = *reinterpret_cast<const s8v*>(&h2s[rt * 16 + lr][ks * 32 + lkg * 8]);
            s8v b = *reinterpret_cast<const s8v*>(w3T + (long)(ct * 16 + lr) * 64 + ks * 32 + lkg * 8);
            acc = __builtin_amdgcn_mfma_f32_16x16x32_bf16(a, b, acc, 0, 0, 0);
        }
#pragma unroll
        for (int r = 0; r < 4; r++)
            tpw[rt * 16 + lkg * 4 + r][ct * 16 + lr] = f2b(acc[r] * 0.125f);
    }
    __syncthreads();
    const int c = t & 127, seg = t >> 7;

    // prefetch all 16 sender-gathers into registers (static indices -> VGPRs)
    u4s xpr[16];
#pragma unroll
    for (int i = 0; i < 16; i++)
        xpr[i] = *reinterpret_cast<const u4s*>(xpack + (long)sn_l[seg * 16 + i] * 512 + c * 4);

    float a_s0 = 0.f, a_s1 = 0.f;
    float av0 = 0.f, av1 = 0.f, av2 = 0.f, av3 = 0.f, av4 = 0.f, av5 = 0.f, av6 = 0.f, av7 = 0.f, av8 = 0.f;
    int cur_rc = -1;
#define FLUSH_RUN() do { \
        float* ms = msg_s + (long)cur_rc * 256 + c; \
        unsafeAtomicAdd(ms, a_s0); \
        unsafeAtomicAdd(ms + 128, a_s1); \
        float* mv = msg_v + (long)cur_rc * 1152 + c; \
        unsafeAtomicAdd(mv + 0, av0); \
        unsafeAtomicAdd(mv + 128, av1); \
        unsafeAtomicAdd(mv + 256, av2); \
        unsafeAtomicAdd(mv + 384, av3); \
        unsafeAtomicAdd(mv + 512, av4); \
        unsafeAtomicAdd(mv + 640, av5); \
        unsafeAtomicAdd(mv + 768, av6); \
        unsafeAtomicAdd(mv + 896, av7); \
        unsafeAtomicAdd(mv + 1024, av8); \
    } while (0)
#pragma unroll
    for (int i = 0; i < 16; i++) {
        int idx = seg * 16 + i;
        int rc = rc_l[idx];
        if (rc != cur_rc) {
            if (cur_rc >= 0) FLUSH_RUN();
            cur_rc = rc;
            a_s0 = a_s1 = 0.f;
            av0 = av1 = av2 = av3 = av4 = av5 = av6 = av7 = av8 = 0.f;
        }
        float es = es_l[idx], ev0 = ev_l[idx][0], ev1 = ev_l[idx][1], ev2 = ev_l[idx][2];
        float w1 = b2f(tpw[idx][c]);
        float w2 = b2f(tpw[idx][128 + c]);
        float w3 = b2f(tpw[idx][256 + c]);
        float w4 = b2f(tpw[idx][384 + c]);
        float w5 = b2f(tpw[idx][512 + c]);
        float xsv = b2f(xpr[i][0]);
        float x0 = b2f(xpr[i][1]), x1 = b2f(xpr[i][2]), x2 = b2f(xpr[i][3]);
        a_s0 += w1 * xsv * es;
        float dve = x0 * ev0 + x1 * ev1 + x2 * ev2;
        a_s1 += w4 * dve * 0.57735026919f;
        float a2 = w2 * xsv;
        av0 += a2 * ev0;
        av1 += w3 * x0 * es;
        av2 += w5 * (x1 * ev2 - x2 * ev1) * 0.70710678119f;
        av3 += a2 * ev1;
        av4 += w3 * x1 * es;
        av5 += w5 * (x2 * ev0 - x0 * ev2) * 0.70710678119f;
        av6 += a2 * ev2;
        av7 += w3 * x2 * es;
        av8 += w5 * (x0 * ev1 - x1 * ev0) * 0.70710678119f;
    }
    FLUSH_RUN();
#undef FLUSH_RUN
}

extern "C" void kernel_launch(void* const* d_in, const int* in_sizes, int n_in,
                              void* d_out, int out_size, void* d_ws, size_t ws_size,
                              hipStream_t stream) {
    const float* node_attrs = (const float*)d_in[0];
    const float* nfs        = (const float*)d_in[1];
    const float* nfv        = (const float*)d_in[2];
    const float* edge_attrs = (const float*)d_in[3];
    const float* edge_feats = (const float*)d_in[4];
    const float* W_sc_s     = (const float*)d_in[5];
    const float* W_sc_v     = (const float*)d_in[6];
    const float* W_lin_s    = (const float*)d_in[7];
    const float* W_lin_v    = (const float*)d_in[8];
    const float* mlp_w0     = (const float*)d_in[9];
    const float* mlp_w1     = (const float*)d_in[10];
    const float* mlp_w2     = (const float*)d_in[11];
    const float* mlp_w3     = (const float*)d_in[12];
    const float* W_out_s    = (const float*)d_in[13];
    const float* W_out_v    = (const float*)d_in[14];
    const int* senders      = (const int*)d_in[15];
    const int* receivers    = (const int*)d_in[16];
    float* dout = (float*)d_out;

    char* W = (char*)d_ws;
    unsigned short* xpack_ws = (unsigned short*)(W + 0);        // 10,240,000
    float* msgs_ws = (float*)(W + 10240000);   // 10,240,000
    float* msgv_ws = (float*)(W + 20480000);   // 46,080,000 -> ends 66,560,000
    unsigned short* h2_ws   = (unsigned short*)(W + 66560000);  // 20,480,000 -> ends 87,040,000
    unsigned short* wsc_s2  = (unsigned short*)(W + 87040000);
    unsigned short* wsc_v2  = (unsigned short*)(W + 87367680);
    unsigned short* wlin_sT = (unsigned short*)(W + 87695360);
    unsigned short* wlin_vT = (unsigned short*)(W + 87728128);
    unsigned short* wout_sT = (unsigned short*)(W + 87760896);
    unsigned short* wout_vT = (unsigned short*)(W + 87826432);
    unsigned short* w3T     = (unsigned short*)(W + 87924736);
    unsigned short* w1T     = (unsigned short*)(W + 88006656);
    unsigned short* w2T     = (unsigned short*)(W + 88014848);
    int* cnt_ws   = (int*)(W + 88023040);
    int* base_ws  = (int*)(W + 88064000);
    int* cur_ws   = (int*)(W + 88104960);
    int* order_ws = (int*)(W + 88145920);   // ends 88,785,920

    const float inv1280 = 0.02795084972f;
    const float inv128  = 0.08838834765f;
    const float scO_s   = 1.f / 256.f;
    const float scO_v   = 1.f / (19.5959179423f * 16.f);

    k_prep<<<dim3(640, 9, 1), 256, 0, stream>>>(W_sc_s, W_sc_v, W_lin_s, W_lin_v, W_out_s, W_out_v, mlp_w3,
                                                mlp_w1, mlp_w2,
                                                wsc_s2, wsc_v2, wlin_sT, wlin_vT, wout_sT, wout_vT, w3T,
                                                w1T, w2T);
    k_mlp012<<<dim3(2500), 256, 0, stream>>>(edge_feats, mlp_w0, w1T, w2T, h2_ws);

    // sc -> d_out second half (factorized tensor-product GEMM)
    k_sc<<<dim3(157, 4), 256, 0, stream>>>(nfs, nfv, node_attrs, wsc_s2, wsc_v2, dout + 5120000, inv1280);

    // x_s / x_v -> xpack (bf16, interleaved [n][c][4])
    {
        GemmZ g0{nfs,     128, 1, wlin_sT, (float*)(xpack_ws + 0), 512, 4, 128, inv128, N_NODES, 1};
        GemmZ g1{nfv + 0, 384, 3, wlin_vT, (float*)(xpack_ws + 1), 512, 4, 128, inv128, N_NODES, 1};
        GemmZ g2{nfv + 1, 384, 3, wlin_vT, (float*)(xpack_ws + 2), 512, 4, 128, inv128, N_NODES, 1};
        GemmZ g3{nfv + 2, 384, 3, wlin_vT, (float*)(xpack_ws + 3), 512, 4, 128, inv128, N_NODES, 1};
        k_gemm<<<dim3(157, 1, 4), 256, 0, stream>>>(g0, g1, g2, g3);
    }

    hipMemsetAsync(msgs_ws, 0, 56320000, stream);  // msg_s + msg_v
    hipMemsetAsync(cnt_ws, 0, 40960, stream);
    k_hist<<<dim3(625), 256, 0, stream>>>(receivers, cnt_ws);
    k_scan<<<dim3(1), 256, 0, stream>>>(cnt_ws, base_ws, cur_ws);
    k_scatter<<<dim3(625), 256, 0, stream>>>(receivers, cur_ws, order_ws);
    k_edge2<<<dim3(5000), 256, 0, stream>>>(h2_ws, w3T, edge_attrs, senders, receivers, order_ws,
                                            xpack_ws, msgs_ws, msgv_ws);

    // out = msg @ W_out -> d_out first half
    {
        GemmZ g0{msgs_ws,       256,  1, wout_sT, dout,           512, 1, 256, scO_s, N_NODES, 0};
        GemmZ g1{msgv_ws + 0,   1152, 1, wout_vT, dout + 128 + 0, 512, 3, 384, scO_v, N_NODES, 0};
        GemmZ g2{msgv_ws + 384, 1152, 1, wout_vT, dout + 128 + 1, 512, 3, 384, scO_v, N_NODES, 0};
        GemmZ g3{msgv_ws + 768, 1152, 1, wout_vT, dout + 128 + 2, 512, 3, 384, scO_v, N_NODES, 0};
        k_gemm<<<dim3(157, 1, 4), 256, 0, stream>>>(g0, g1, g2, g3);
    }
}

// Round 7
// 393.231 us; speedup vs baseline: 2.9261x; 1.0130x over previous
//
#include <hip/hip_runtime.h>

#define N_NODES 10000
#define N_EDGES 160000

typedef float f32x4 __attribute__((ext_vector_type(4)));
typedef short s8v __attribute__((ext_vector_type(8)));
typedef unsigned short u4s __attribute__((ext_vector_type(4)));

__device__ __forceinline__ unsigned short f2b(float f) {
    unsigned u = __builtin_bit_cast(unsigned, f);
    u += 0x7FFFu + ((u >> 16) & 1u);
    return (unsigned short)(u >> 16);
}
__device__ __forceinline__ float b2f(unsigned short s) {
    unsigned u = ((unsigned)s) << 16;
    return __builtin_bit_cast(float, u);
}

// ---------------- prep: weight matrices -> bf16, layouts for MFMA ----------------
__global__ void k_prep(const float* s0, const float* s1, const float* s2, const float* s3,
                       const float* s4, const float* s5, const float* s6,
                       const float* s7, const float* s8,
                       unsigned short* d0, unsigned short* d1, unsigned short* d2, unsigned short* d3,
                       unsigned short* d4, unsigned short* d5, unsigned short* d6,
                       unsigned short* d7, unsigned short* d8) {
    int idx = blockIdx.x * 256 + threadIdx.x;
    if (blockIdx.y < 2) {
        const float* src = blockIdx.y ? s1 : s0;
        unsigned short* dst = blockIdx.y ? d1 : d0;
        int k = idx >> 7, o = idx & 127;
        int ci = k / 10, a = k - ci * 10;
        dst[a * 16384 + o * 128 + ci] = f2b(src[idx]);
        return;
    }
    const float* src; unsigned short* dst; int K, Nc;
    switch (blockIdx.y) {
        case 2: src = s2; dst = d2; K = 128;  Nc = 128; break;
        case 3: src = s3; dst = d3; K = 128;  Nc = 128; break;
        case 4: src = s4; dst = d4; K = 256;  Nc = 128; break;
        case 5: src = s5; dst = d5; K = 384;  Nc = 128; break;
        case 6: src = s6; dst = d6; K = 64;   Nc = 640; break;
        case 7: src = s7; dst = d7; K = 64;   Nc = 64;  break;
        default: src = s8; dst = d8; K = 64;  Nc = 64;  break;
    }
    if (idx < K * Nc) {
        int k = idx / Nc, c = idx - k * Nc;
        dst[c * K + k] = f2b(src[idx]);
    }
}

// ---------------- sc: out[n, o] = inv1280 * sum_a attr[n,a] * (A_z @ W_a)[n, o] ----------------
__global__ __launch_bounds__(256) void k_sc(const float* __restrict__ nfs,
                                            const float* __restrict__ nfv,
                                            const float* __restrict__ attr,
                                            const unsigned short* __restrict__ Ws2,
                                            const unsigned short* __restrict__ Wv2,
                                            float* __restrict__ out, float scale) {
    __shared__ unsigned short As[64][136];
    __shared__ unsigned short Bs[128][140];
    __shared__ float attr_l[64][10];
    const int t = threadIdx.x;
    const int z = blockIdx.y;
    const int row0 = blockIdx.x * 64;
    const int wv = t >> 6, lane = t & 63, lr = lane & 15, lkg = lane >> 4;

    {
        int r = t >> 2, k0 = (t & 3) * 32;
        int row = row0 + r;
        if (z == 0) {
            if (row < N_NODES) {
#pragma unroll
                for (int j = 0; j < 8; j++) {
                    f32x4 v = *reinterpret_cast<const f32x4*>(nfs + (long)row * 128 + k0 + j * 4);
                    As[r][k0 + j * 4 + 0] = f2b(v[0]);
                    As[r][k0 + j * 4 + 1] = f2b(v[1]);
                    As[r][k0 + j * 4 + 2] = f2b(v[2]);
                    As[r][k0 + j * 4 + 3] = f2b(v[3]);
                }
            } else {
#pragma unroll
                for (int j = 0; j < 32; j++) As[r][k0 + j] = 0;
            }
        } else {
            int i = z - 1;
            if (row < N_NODES) {
#pragma unroll
                for (int j = 0; j < 32; j++)
                    As[r][k0 + j] = f2b(nfv[(long)row * 384 + (k0 + j) * 3 + i]);
            } else {
#pragma unroll
                for (int j = 0; j < 32; j++) As[r][k0 + j] = 0;
            }
        }
    }
    for (int idx = t; idx < 640; idx += 256) {
        int r = idx / 10, a = idx - r * 10;
        int row = row0 + r;
        attr_l[r][a] = (row < N_NODES) ? attr[row * 10 + a] : 0.f;
    }
    __syncthreads();

    s8v af[4];
#pragma unroll
    for (int kk = 0; kk < 4; kk++)
        af[kk] = *reinterpret_cast<const s8v*>(&As[wv * 16 + lr][kk * 32 + lkg * 8]);

    f32x4 accS[8];
#pragma unroll
    for (int i = 0; i < 8; i++) accS[i] = (f32x4){0.f, 0.f, 0.f, 0.f};

    const unsigned short* Wbase = (z == 0) ? Ws2 : Wv2;
    for (int a = 0; a < 10; a++) {
        {
            const unsigned short* src = Wbase + a * 16384;
            int r = t >> 1, c0 = (t & 1) * 64;
#pragma unroll
            for (int j = 0; j < 8; j++) {
                s8v v = *reinterpret_cast<const s8v*>(src + r * 128 + c0 + j * 8);
                *reinterpret_cast<s8v*>(&Bs[r][c0 + j * 8]) = v;
            }
        }
        __syncthreads();
        f32x4 acc[8];
#pragma unroll
        for (int i = 0; i < 8; i++) acc[i] = (f32x4){0.f, 0.f, 0.f, 0.f};
#pragma unroll
        for (int kk = 0; kk < 4; kk++) {
#pragma unroll
            for (int ct = 0; ct < 8; ct++) {
                s8v bf = *reinterpret_cast<const s8v*>(&Bs[ct * 16 + lr][kk * 32 + lkg * 8]);
                acc[ct] = __builtin_amdgcn_mfma_f32_16x16x32_bf16(af[kk], bf, acc[ct], 0, 0, 0);
            }
        }
#pragma unroll
        for (int r = 0; r < 4; r++) {
            float aw = attr_l[wv * 16 + lkg * 4 + r][a];
#pragma unroll
            for (int ct = 0; ct < 8; ct++)
                accS[ct][r] += aw * acc[ct][r];
        }
        __syncthreads();
    }
#pragma unroll
    for (int ct = 0; ct < 8; ct++) {
#pragma unroll
        for (int r = 0; r < 4; r++) {
            int row = row0 + wv * 16 + lkg * 4 + r;
            if (row < N_NODES) {
                int col = ct * 16 + lr;
                if (z == 0) out[(long)row * 512 + col] = accS[ct][r] * scale;
                else        out[(long)row * 512 + 128 + col * 3 + (z - 1)] = accS[ct][r] * scale;
            }
        }
    }
}

// ---------------- generic MFMA GEMM (x and out GEMMs) ----------------
struct GemmZ {
    const float* Ap;
    int ars, aks;
    const unsigned short* Bt;
    float* Cp;
    int crs, ccs;
    int K;
    float scale;
    int M;
    int obf16;
};

__global__ __launch_bounds__(256) void k_gemm(GemmZ g0, GemmZ g1, GemmZ g2, GemmZ g3) {
    GemmZ g;
    switch (blockIdx.z) { case 0: g = g0; break; case 1: g = g1; break; case 2: g = g2; break; default: g = g3; }
    __shared__ unsigned short As[64][40];
    const int t = threadIdx.x;
    const int wv = t >> 6, lane = t & 63;
    const int lr = lane & 15, lkg = lane >> 4;
    const int row0 = blockIdx.x * 64;
    const int br = t >> 2;
    const int bk0 = (t & 3) * 8;
    const int arow = row0 + br;

    f32x4 acc[8];
#pragma unroll
    for (int i = 0; i < 8; i++) acc[i] = (f32x4){0.f, 0.f, 0.f, 0.f};

    for (int k0 = 0; k0 < g.K; k0 += 32) {
        s8v av;
        if (arow < g.M) {
            if (g.aks == 1) {
                const float* ap = g.Ap + (long)arow * g.ars + k0 + bk0;
                f32x4 v0 = *reinterpret_cast<const f32x4*>(ap);
                f32x4 v1 = *reinterpret_cast<const f32x4*>(ap + 4);
                av[0] = (short)f2b(v0[0]); av[1] = (short)f2b(v0[1]);
                av[2] = (short)f2b(v0[2]); av[3] = (short)f2b(v0[3]);
                av[4] = (short)f2b(v1[0]); av[5] = (short)f2b(v1[1]);
                av[6] = (short)f2b(v1[2]); av[7] = (short)f2b(v1[3]);
            } else {
#pragma unroll
                for (int j = 0; j < 8; j++)
                    av[j] = (short)f2b(g.Ap[(long)arow * g.ars + (long)(k0 + bk0 + j) * g.aks]);
            }
        } else {
#pragma unroll
            for (int j = 0; j < 8; j++) av[j] = 0;
        }
        __syncthreads();
        *reinterpret_cast<s8v*>(&As[br][bk0]) = av;
        __syncthreads();
        s8v af = *reinterpret_cast<const s8v*>(&As[wv * 16 + lr][lkg * 8]);
#pragma unroll
        for (int ct = 0; ct < 8; ct++) {
            const unsigned short* bp = g.Bt + (long)(ct * 16 + lr) * g.K + k0 + lkg * 8;
            s8v bf = *reinterpret_cast<const s8v*>(bp);
            acc[ct] = __builtin_amdgcn_mfma_f32_16x16x32_bf16(af, bf, acc[ct], 0, 0, 0);
        }
    }
#pragma unroll
    for (int ct = 0; ct < 8; ct++) {
#pragma unroll
        for (int r = 0; r < 4; r++) {
            int row = row0 + wv * 16 + lkg * 4 + r;
            if (row < g.M) {
                int col = ct * 16 + lr;
                if (g.obf16)
                    ((unsigned short*)g.Cp)[(long)row * g.crs + col * g.ccs] = f2b(acc[ct][r] * g.scale);
                else
                    g.Cp[(long)row * g.crs + col * g.ccs] = acc[ct][r] * g.scale;
            }
        }
    }
}

// ---------------- MLP: layer0 VALU, layers 1-2 MFMA ----------------
__global__ __launch_bounds__(256) void k_mlp012(const float* __restrict__ ef, const float* __restrict__ w0,
                                                const unsigned short* __restrict__ w1T,
                                                const unsigned short* __restrict__ w2T,
                                                unsigned short* __restrict__ h2out) {
    __shared__ float efs[64][8];
    __shared__ unsigned short hA[64][72];
    __shared__ unsigned short hB[64][72];
    const int t = threadIdx.x;
    const long e0 = (long)blockIdx.x * 64;
#pragma unroll
    for (int j = 0; j < 2; j++) { int idx = t + j * 256; ((float*)efs)[idx] = ef[e0 * 8 + idx]; }
    const int o = t & 63, ebase = t >> 6;
    float w0r[8];
#pragma unroll
    for (int k = 0; k < 8; k++) w0r[k] = w0[k * 64 + o];
    __syncthreads();
#pragma unroll
    for (int j = 0; j < 16; j++) {
        int e = ebase * 16 + j;
        float acc = 0.f;
#pragma unroll
        for (int k = 0; k < 8; k++) acc += efs[e][k] * w0r[k];
        acc *= 0.35355339059f;
        hA[e][o] = f2b(acc / (1.f + __expf(-acc)));
    }
    __syncthreads();
    const int wv = t >> 6, lane = t & 63, lr = lane & 15, lkg = lane >> 4;
    {
        f32x4 acc1[4];
#pragma unroll
        for (int ct = 0; ct < 4; ct++) acc1[ct] = (f32x4){0.f, 0.f, 0.f, 0.f};
#pragma unroll
        for (int kk = 0; kk < 2; kk++) {
            s8v a = *reinterpret_cast<const s8v*>(&hA[wv * 16 + lr][kk * 32 + lkg * 8]);
#pragma unroll
            for (int ct = 0; ct < 4; ct++) {
                s8v b = *reinterpret_cast<const s8v*>(w1T + (ct * 16 + lr) * 64 + kk * 32 + lkg * 8);
                acc1[ct] = __builtin_amdgcn_mfma_f32_16x16x32_bf16(a, b, acc1[ct], 0, 0, 0);
            }
        }
#pragma unroll
        for (int ct = 0; ct < 4; ct++)
#pragma unroll
            for (int r = 0; r < 4; r++) {
                float v = acc1[ct][r] * 0.125f;
                hB[wv * 16 + lkg * 4 + r][ct * 16 + lr] = f2b(v / (1.f + __expf(-v)));
            }
    }
    __syncthreads();
    {
        f32x4 acc2[4];
#pragma unroll
        for (int ct = 0; ct < 4; ct++) acc2[ct] = (f32x4){0.f, 0.f, 0.f, 0.f};
#pragma unroll
        for (int kk = 0; kk < 2; kk++) {
            s8v a = *reinterpret_cast<const s8v*>(&hB[wv * 16 + lr][kk * 32 + lkg * 8]);
#pragma unroll
            for (int ct = 0; ct < 4; ct++) {
                s8v b = *reinterpret_cast<const s8v*>(w2T + (ct * 16 + lr) * 64 + kk * 32 + lkg * 8);
                acc2[ct] = __builtin_amdgcn_mfma_f32_16x16x32_bf16(a, b, acc2[ct], 0, 0, 0);
            }
        }
#pragma unroll
        for (int ct = 0; ct < 4; ct++)
#pragma unroll
            for (int r = 0; r < 4; r++) {
                float v = acc2[ct][r] * 0.125f;
                int row = wv * 16 + lkg * 4 + r;
                h2out[(e0 + row) * 64 + ct * 16 + lr] = f2b(v / (1.f + __expf(-v)));
            }
    }
}

// ---------------- CSR build ----------------
__global__ void k_hist(const int* __restrict__ rcv, int* __restrict__ cnt) {
    int e = blockIdx.x * 256 + threadIdx.x;
    if (e < N_EDGES) atomicAdd(&cnt[rcv[e]], 1);
}

__global__ __launch_bounds__(256) void k_scan(const int* __restrict__ cnt, int* __restrict__ base, int* __restrict__ cur) {
    __shared__ int s[256];
    const int t = threadIdx.x;
    const int c0 = t * 40;
    int sum = 0;
    for (int i = 0; i < 40; i++) sum += cnt[c0 + i];
    s[t] = sum;
    __syncthreads();
    for (int off = 1; off < 256; off <<= 1) {
        int v = (t >= off) ? s[t - off] : 0;
        __syncthreads();
        s[t] += v;
        __syncthreads();
    }
    int run = t ? s[t - 1] : 0;
    for (int i = 0; i < 40; i++) {
        int idx = c0 + i;
        if (idx <= N_NODES) { base[idx] = run; cur[idx] = run; }
        run += cnt[idx];
    }
}

__global__ void k_scatter(const int* __restrict__ rcv, int* __restrict__ cur, int* __restrict__ order) {
    int e = blockIdx.x * 256 + threadIdx.x;
    if (e < N_EDGES) {
        int p = atomicAdd(&cur[rcv[e]], 1);
        order[p] = e;
    }
}

// ---------------- fused per-edge, 16 edges/block for occupancy ----------------
__global__ __launch_bounds__(256, 3) void k_edge2(const unsigned short* __restrict__ h2,
                                                  const unsigned short* __restrict__ w3T,
                                                  const float* __restrict__ eattr,
                                                  const int* __restrict__ snd, const int* __restrict__ rcv,
                                                  const int* __restrict__ order,
                                                  const unsigned short* __restrict__ xpack,
                                                  float* __restrict__ msg_s, float* __restrict__ msg_v) {
    __shared__ unsigned short h2s[16][72];
    __shared__ unsigned short tpw[16][644];
    __shared__ float es_l[16];
    __shared__ float ev_l[16][3];
    __shared__ int sn_l[16], rc_l[16];
    const int t = threadIdx.x;
    const int j0 = blockIdx.x * 16;
    if (t < 128) {
        int r = t >> 3, kk = (t & 7) * 8;
        int e = order[j0 + r];
        s8v v = *reinterpret_cast<const s8v*>(h2 + (long)e * 64 + kk);
        *reinterpret_cast<s8v*>(&h2s[r][kk]) = v;
    }
    if (t < 16) {
        int e = order[j0 + t];
        es_l[t] = eattr[e * 4 + 0];
        ev_l[t][0] = eattr[e * 4 + 1];
        ev_l[t][1] = eattr[e * 4 + 2];
        ev_l[t][2] = eattr[e * 4 + 3];
        sn_l[t] = snd[e];
        rc_l[t] = rcv[e];
    }
    __syncthreads();
    const int wv = t >> 6, lane = t & 63, lr = lane & 15, lkg = lane >> 4;
#pragma unroll
    for (int p = 0; p < 10; p++) {
        int ct = wv + 4 * p;
        f32x4 acc = (f32x4){0.f, 0.f, 0.f, 0.f};
#pragma unroll
        for (int ks = 0; ks < 2; ks++) {
            s8v a = *reinterpret_cast<const s8v*>(&h2s[lr][ks * 32 + lkg * 8]);
            s8v b = *reinterpret_cast<const s8v*>(w3T + (long)(ct * 16 + lr) * 64 + ks * 32 + lkg * 8);
            acc = __builtin_amdgcn_mfma_f32_16x16x32_bf16(a, b, acc, 0, 0, 0);
        }
#pragma unroll
        for (int r = 0; r < 4; r++)
            tpw[lkg * 4 + r][ct * 16 + lr] = f2b(acc[r] * 0.125f);
    }
    __syncthreads();
    const int c = t & 127, seg = t >> 7;

    // prefetch the 8 sender-gathers into registers
    u4s xpr[8];
#pragma unroll
    for (int i = 0; i < 8; i++)
        xpr[i] = *reinterpret_cast<const u4s*>(xpack + (long)sn_l[seg * 8 + i] * 512 + c * 4);

    float a_s0 = 0.f, a_s1 = 0.f;
    float av0 = 0.f, av1 = 0.f, av2 = 0.f, av3 = 0.f, av4 = 0.f, av5 = 0.f, av6 = 0.f, av7 = 0.f, av8 = 0.f;
    int cur_rc = -1;
#define FLUSH_RUN() do { \
        float* ms = msg_s + (long)cur_rc * 256 + c; \
        unsafeAtomicAdd(ms, a_s0); \
        unsafeAtomicAdd(ms + 128, a_s1); \
        float* mv = msg_v + (long)cur_rc * 1152 + c; \
        unsafeAtomicAdd(mv + 0, av0); \
        unsafeAtomicAdd(mv + 128, av1); \
        unsafeAtomicAdd(mv + 256, av2); \
        unsafeAtomicAdd(mv + 384, av3); \
        unsafeAtomicAdd(mv + 512, av4); \
        unsafeAtomicAdd(mv + 640, av5); \
        unsafeAtomicAdd(mv + 768, av6); \
        unsafeAtomicAdd(mv + 896, av7); \
        unsafeAtomicAdd(mv + 1024, av8); \
    } while (0)
#pragma unroll
    for (int i = 0; i < 8; i++) {
        int idx = seg * 8 + i;
        int rc = rc_l[idx];
        if (rc != cur_rc) {
            if (cur_rc >= 0) FLUSH_RUN();
            cur_rc = rc;
            a_s0 = a_s1 = 0.f;
            av0 = av1 = av2 = av3 = av4 = av5 = av6 = av7 = av8 = 0.f;
        }
        float es = es_l[idx], ev0 = ev_l[idx][0], ev1 = ev_l[idx][1], ev2 = ev_l[idx][2];
        float w1 = b2f(tpw[idx][c]);
        float w2 = b2f(tpw[idx][128 + c]);
        float w3 = b2f(tpw[idx][256 + c]);
        float w4 = b2f(tpw[idx][384 + c]);
        float w5 = b2f(tpw[idx][512 + c]);
        float xsv = b2f(xpr[i][0]);
        float x0 = b2f(xpr[i][1]), x1 = b2f(xpr[i][2]), x2 = b2f(xpr[i][3]);
        a_s0 += w1 * xsv * es;
        float dve = x0 * ev0 + x1 * ev1 + x2 * ev2;
        a_s1 += w4 * dve * 0.57735026919f;
        float a2 = w2 * xsv;
        av0 += a2 * ev0;
        av1 += w3 * x0 * es;
        av2 += w5 * (x1 * ev2 - x2 * ev1) * 0.70710678119f;
        av3 += a2 * ev1;
        av4 += w3 * x1 * es;
        av5 += w5 * (x2 * ev0 - x0 * ev2) * 0.70710678119f;
        av6 += a2 * ev2;
        av7 += w3 * x2 * es;
        av8 += w5 * (x0 * ev1 - x1 * ev0) * 0.70710678119f;
    }
    FLUSH_RUN();
#undef FLUSH_RUN
}

extern "C" void kernel_launch(void* const* d_in, const int* in_sizes, int n_in,
                              void* d_out, int out_size, void* d_ws, size_t ws_size,
                              hipStream_t stream) {
    const float* node_attrs = (const float*)d_in[0];
    const float* nfs        = (const float*)d_in[1];
    const float* nfv        = (const float*)d_in[2];
    const float* edge_attrs = (const float*)d_in[3];
    const float* edge_feats = (const float*)d_in[4];
    const float* W_sc_s     = (const float*)d_in[5];
    const float* W_sc_v     = (const float*)d_in[6];
    const float* W_lin_s    = (const float*)d_in[7];
    const float* W_lin_v    = (const float*)d_in[8];
    const float* mlp_w0     = (const float*)d_in[9];
    const float* mlp_w1     = (const float*)d_in[10];
    const float* mlp_w2     = (const float*)d_in[11];
    const float* mlp_w3     = (const float*)d_in[12];
    const float* W_out_s    = (const float*)d_in[13];
    const float* W_out_v    = (const float*)d_in[14];
    const int* senders      = (const int*)d_in[15];
    const int* receivers    = (const int*)d_in[16];
    float* dout = (float*)d_out;

    char* W = (char*)d_ws;
    unsigned short* xpack_ws = (unsigned short*)(W + 0);        // 10,240,000
    float* msgs_ws = (float*)(W + 10240000);   // 10,240,000
    float* msgv_ws = (float*)(W + 20480000);   // 46,080,000 -> ends 66,560,000
    unsigned short* h2_ws   = (unsigned short*)(W + 66560000);  // 20,480,000 -> ends 87,040,000
    unsigned short* wsc_s2  = (unsigned short*)(W + 87040000);
    unsigned short* wsc_v2  = (unsigned short*)(W + 87367680);
    unsigned short* wlin_sT = (unsigned short*)(W + 87695360);
    unsigned short* wlin_vT = (unsigned short*)(W + 87728128);
    unsigned short* wout_sT = (unsigned short*)(W + 87760896);
    unsigned short* wout_vT = (unsigned short*)(W + 87826432);
    unsigned short* w3T     = (unsigned short*)(W + 87924736);
    unsigned short* w1T     = (unsigned short*)(W + 88006656);
    unsigned short* w2T     = (unsigned short*)(W + 88014848);
    int* cnt_ws   = (int*)(W + 88023040);
    int* base_ws  = (int*)(W + 88064000);
    int* cur_ws   = (int*)(W + 88104960);
    int* order_ws = (int*)(W + 88145920);   // ends 88,785,920

    const float inv1280 = 0.02795084972f;
    const float inv128  = 0.08838834765f;
    const float scO_s   = 1.f / 256.f;
    const float scO_v   = 1.f / (19.5959179423f * 16.f);

    k_prep<<<dim3(640, 9, 1), 256, 0, stream>>>(W_sc_s, W_sc_v, W_lin_s, W_lin_v, W_out_s, W_out_v, mlp_w3,
                                                mlp_w1, mlp_w2,
                                                wsc_s2, wsc_v2, wlin_sT, wlin_vT, wout_sT, wout_vT, w3T,
                                                w1T, w2T);
    k_mlp012<<<dim3(2500), 256, 0, stream>>>(edge_feats, mlp_w0, w1T, w2T, h2_ws);

    // sc -> d_out second half (factorized tensor-product GEMM)
    k_sc<<<dim3(157, 4), 256, 0, stream>>>(nfs, nfv, node_attrs, wsc_s2, wsc_v2, dout + 5120000, inv1280);

    // x_s / x_v -> xpack (bf16, interleaved [n][c][4])
    {
        GemmZ g0{nfs,     128, 1, wlin_sT, (float*)(xpack_ws + 0), 512, 4, 128, inv128, N_NODES, 1};
        GemmZ g1{nfv + 0, 384, 3, wlin_vT, (float*)(xpack_ws + 1), 512, 4, 128, inv128, N_NODES, 1};
        GemmZ g2{nfv + 1, 384, 3, wlin_vT, (float*)(xpack_ws + 2), 512, 4, 128, inv128, N_NODES, 1};
        GemmZ g3{nfv + 2, 384, 3, wlin_vT, (float*)(xpack_ws + 3), 512, 4, 128, inv128, N_NODES, 1};
        k_gemm<<<dim3(157, 1, 4), 256, 0, stream>>>(g0, g1, g2, g3);
    }

    hipMemsetAsync(msgs_ws, 0, 56320000, stream);  // msg_s + msg_v
    hipMemsetAsync(cnt_ws, 0, 40960, stream);
    k_hist<<<dim3(625), 256, 0, stream>>>(receivers, cnt_ws);
    k_scan<<<dim3(1), 256, 0, stream>>>(cnt_ws, base_ws, cur_ws);
    k_scatter<<<dim3(625), 256, 0, stream>>>(receivers, cur_ws, order_ws);
    k_edge2<<<dim3(10000), 256, 0, stream>>>(h2_ws, w3T, edge_attrs, senders, receivers, order_ws,
                                             xpack_ws, msgs_ws, msgv_ws);

    // out = msg @ W_out -> d_out first half
    {
        GemmZ g0{msgs_ws,       256,  1, wout_sT, dout,           512, 1, 256, scO_s, N_NODES, 0};
        GemmZ g1{msgv_ws + 0,   1152, 1, wout_vT, dout + 128 + 0, 512, 3, 384, scO_v, N_NODES, 0};
        GemmZ g2{msgv_ws + 384, 1152, 1, wout_vT, dout + 128 + 1, 512, 3, 384, scO_v, N_NODES, 0};
        GemmZ g3{msgv_ws + 768, 1152, 1, wout_vT, dout + 128 + 2, 512, 3, 384, scO_v, N_NODES, 0};
        k_gemm<<<dim3(157, 1, 4), 256, 0, stream>>>(g0, g1, g2, g3);
    }
}

// Round 8
// 377.307 us; speedup vs baseline: 3.0496x; 1.0422x over previous
//
#include <hip/hip_runtime.h>

#define N_NODES 10000
#define N_EDGES 160000

typedef float f32x4 __attribute__((ext_vector_type(4)));
typedef short s8v __attribute__((ext_vector_type(8)));
typedef unsigned short u4s __attribute__((ext_vector_type(4)));

__device__ __forceinline__ unsigned short f2b(float f) {
    unsigned u = __builtin_bit_cast(unsigned, f);
    u += 0x7FFFu + ((u >> 16) & 1u);
    return (unsigned short)(u >> 16);
}
__device__ __forceinline__ float b2f(unsigned short s) {
    unsigned u = ((unsigned)s) << 16;
    return __builtin_bit_cast(float, u);
}

// ---------------- prep: weight matrices -> bf16, layouts for MFMA ----------------
__global__ void k_prep(const float* s0, const float* s1, const float* s2, const float* s3,
                       const float* s4, const float* s5, const float* s6,
                       const float* s7, const float* s8,
                       unsigned short* d0, unsigned short* d1, unsigned short* d2, unsigned short* d3,
                       unsigned short* d4, unsigned short* d5, unsigned short* d6,
                       unsigned short* d7, unsigned short* d8) {
    int idx = blockIdx.x * 256 + threadIdx.x;
    if (blockIdx.y < 2) {
        const float* src = blockIdx.y ? s1 : s0;
        unsigned short* dst = blockIdx.y ? d1 : d0;
        int k = idx >> 7, o = idx & 127;
        int ci = k / 10, a = k - ci * 10;
        dst[a * 16384 + o * 128 + ci] = f2b(src[idx]);
        return;
    }
    const float* src; unsigned short* dst; int K, Nc;
    switch (blockIdx.y) {
        case 2: src = s2; dst = d2; K = 128;  Nc = 128; break;
        case 3: src = s3; dst = d3; K = 128;  Nc = 128; break;
        case 4: src = s4; dst = d4; K = 256;  Nc = 128; break;
        case 5: src = s5; dst = d5; K = 384;  Nc = 128; break;
        case 6: src = s6; dst = d6; K = 64;   Nc = 640; break;
        case 7: src = s7; dst = d7; K = 64;   Nc = 64;  break;
        default: src = s8; dst = d8; K = 64;  Nc = 64;  break;
    }
    if (idx < K * Nc) {
        int k = idx / Nc, c = idx - k * Nc;
        dst[c * K + k] = f2b(src[idx]);
    }
}

// ---------------- sc: out[n, o] = inv1280 * sum_a attr[n,a] * (A_z @ W_a)[n, o] ----------------
__global__ __launch_bounds__(256) void k_sc(const float* __restrict__ nfs,
                                            const float* __restrict__ nfv,
                                            const float* __restrict__ attr,
                                            const unsigned short* __restrict__ Ws2,
                                            const unsigned short* __restrict__ Wv2,
                                            float* __restrict__ out, float scale) {
    __shared__ unsigned short As[64][136];
    __shared__ unsigned short Bs[128][140];
    __shared__ float attr_l[64][10];
    const int t = threadIdx.x;
    const int z = blockIdx.y;
    const int row0 = blockIdx.x * 64;
    const int wv = t >> 6, lane = t & 63, lr = lane & 15, lkg = lane >> 4;

    {
        int r = t >> 2, k0 = (t & 3) * 32;
        int row = row0 + r;
        if (z == 0) {
            if (row < N_NODES) {
#pragma unroll
                for (int j = 0; j < 8; j++) {
                    f32x4 v = *reinterpret_cast<const f32x4*>(nfs + (long)row * 128 + k0 + j * 4);
                    As[r][k0 + j * 4 + 0] = f2b(v[0]);
                    As[r][k0 + j * 4 + 1] = f2b(v[1]);
                    As[r][k0 + j * 4 + 2] = f2b(v[2]);
                    As[r][k0 + j * 4 + 3] = f2b(v[3]);
                }
            } else {
#pragma unroll
                for (int j = 0; j < 32; j++) As[r][k0 + j] = 0;
            }
        } else {
            int i = z - 1;
            if (row < N_NODES) {
#pragma unroll
                for (int j = 0; j < 32; j++)
                    As[r][k0 + j] = f2b(nfv[(long)row * 384 + (k0 + j) * 3 + i]);
            } else {
#pragma unroll
                for (int j = 0; j < 32; j++) As[r][k0 + j] = 0;
            }
        }
    }
    for (int idx = t; idx < 640; idx += 256) {
        int r = idx / 10, a = idx - r * 10;
        int row = row0 + r;
        attr_l[r][a] = (row < N_NODES) ? attr[row * 10 + a] : 0.f;
    }
    __syncthreads();

    s8v af[4];
#pragma unroll
    for (int kk = 0; kk < 4; kk++)
        af[kk] = *reinterpret_cast<const s8v*>(&As[wv * 16 + lr][kk * 32 + lkg * 8]);

    f32x4 accS[8];
#pragma unroll
    for (int i = 0; i < 8; i++) accS[i] = (f32x4){0.f, 0.f, 0.f, 0.f};

    const unsigned short* Wbase = (z == 0) ? Ws2 : Wv2;
    for (int a = 0; a < 10; a++) {
        {
            const unsigned short* src = Wbase + a * 16384;
            int r = t >> 1, c0 = (t & 1) * 64;
#pragma unroll
            for (int j = 0; j < 8; j++) {
                s8v v = *reinterpret_cast<const s8v*>(src + r * 128 + c0 + j * 8);
                *reinterpret_cast<s8v*>(&Bs[r][c0 + j * 8]) = v;
            }
        }
        __syncthreads();
        f32x4 acc[8];
#pragma unroll
        for (int i = 0; i < 8; i++) acc[i] = (f32x4){0.f, 0.f, 0.f, 0.f};
#pragma unroll
        for (int kk = 0; kk < 4; kk++) {
#pragma unroll
            for (int ct = 0; ct < 8; ct++) {
                s8v bf = *reinterpret_cast<const s8v*>(&Bs[ct * 16 + lr][kk * 32 + lkg * 8]);
                acc[ct] = __builtin_amdgcn_mfma_f32_16x16x32_bf16(af[kk], bf, acc[ct], 0, 0, 0);
            }
        }
#pragma unroll
        for (int r = 0; r < 4; r++) {
            float aw = attr_l[wv * 16 + lkg * 4 + r][a];
#pragma unroll
            for (int ct = 0; ct < 8; ct++)
                accS[ct][r] += aw * acc[ct][r];
        }
        __syncthreads();
    }
#pragma unroll
    for (int ct = 0; ct < 8; ct++) {
#pragma unroll
        for (int r = 0; r < 4; r++) {
            int row = row0 + wv * 16 + lkg * 4 + r;
            if (row < N_NODES) {
                int col = ct * 16 + lr;
                if (z == 0) out[(long)row * 512 + col] = accS[ct][r] * scale;
                else        out[(long)row * 512 + 128 + col * 3 + (z - 1)] = accS[ct][r] * scale;
            }
        }
    }
}

// ---------------- generic MFMA GEMM (x and out GEMMs) ----------------
struct GemmZ {
    const float* Ap;
    int ars, aks;
    const unsigned short* Bt;
    float* Cp;
    int crs, ccs;
    int K;
    float scale;
    int M;
    int obf16;
};

__global__ __launch_bounds__(256) void k_gemm(GemmZ g0, GemmZ g1, GemmZ g2, GemmZ g3) {
    GemmZ g;
    switch (blockIdx.z) { case 0: g = g0; break; case 1: g = g1; break; case 2: g = g2; break; default: g = g3; }
    __shared__ unsigned short As[64][40];
    const int t = threadIdx.x;
    const int wv = t >> 6, lane = t & 63;
    const int lr = lane & 15, lkg = lane >> 4;
    const int row0 = blockIdx.x * 64;
    const int br = t >> 2;
    const int bk0 = (t & 3) * 8;
    const int arow = row0 + br;

    f32x4 acc[8];
#pragma unroll
    for (int i = 0; i < 8; i++) acc[i] = (f32x4){0.f, 0.f, 0.f, 0.f};

    for (int k0 = 0; k0 < g.K; k0 += 32) {
        s8v av;
        if (arow < g.M) {
            if (g.aks == 1) {
                const float* ap = g.Ap + (long)arow * g.ars + k0 + bk0;
                f32x4 v0 = *reinterpret_cast<const f32x4*>(ap);
                f32x4 v1 = *reinterpret_cast<const f32x4*>(ap + 4);
                av[0] = (short)f2b(v0[0]); av[1] = (short)f2b(v0[1]);
                av[2] = (short)f2b(v0[2]); av[3] = (short)f2b(v0[3]);
                av[4] = (short)f2b(v1[0]); av[5] = (short)f2b(v1[1]);
                av[6] = (short)f2b(v1[2]); av[7] = (short)f2b(v1[3]);
            } else {
#pragma unroll
                for (int j = 0; j < 8; j++)
                    av[j] = (short)f2b(g.Ap[(long)arow * g.ars + (long)(k0 + bk0 + j) * g.aks]);
            }
        } else {
#pragma unroll
            for (int j = 0; j < 8; j++) av[j] = 0;
        }
        __syncthreads();
        *reinterpret_cast<s8v*>(&As[br][bk0]) = av;
        __syncthreads();
        s8v af = *reinterpret_cast<const s8v*>(&As[wv * 16 + lr][lkg * 8]);
#pragma unroll
        for (int ct = 0; ct < 8; ct++) {
            const unsigned short* bp = g.Bt + (long)(ct * 16 + lr) * g.K + k0 + lkg * 8;
            s8v bf = *reinterpret_cast<const s8v*>(bp);
            acc[ct] = __builtin_amdgcn_mfma_f32_16x16x32_bf16(af, bf, acc[ct], 0, 0, 0);
        }
    }
#pragma unroll
    for (int ct = 0; ct < 8; ct++) {
#pragma unroll
        for (int r = 0; r < 4; r++) {
            int row = row0 + wv * 16 + lkg * 4 + r;
            if (row < g.M) {
                int col = ct * 16 + lr;
                if (g.obf16)
                    ((unsigned short*)g.Cp)[(long)row * g.crs + col * g.ccs] = f2b(acc[ct][r] * g.scale);
                else
                    g.Cp[(long)row * g.crs + col * g.ccs] = acc[ct][r] * g.scale;
            }
        }
    }
}

// ---------------- MLP: layer0 VALU, layers 1-2 MFMA ----------------
__global__ __launch_bounds__(256) void k_mlp012(const float* __restrict__ ef, const float* __restrict__ w0,
                                                const unsigned short* __restrict__ w1T,
                                                const unsigned short* __restrict__ w2T,
                                                unsigned short* __restrict__ h2out) {
    __shared__ float efs[64][8];
    __shared__ unsigned short hA[64][72];
    __shared__ unsigned short hB[64][72];
    const int t = threadIdx.x;
    const long e0 = (long)blockIdx.x * 64;
#pragma unroll
    for (int j = 0; j < 2; j++) { int idx = t + j * 256; ((float*)efs)[idx] = ef[e0 * 8 + idx]; }
    const int o = t & 63, ebase = t >> 6;
    float w0r[8];
#pragma unroll
    for (int k = 0; k < 8; k++) w0r[k] = w0[k * 64 + o];
    __syncthreads();
#pragma unroll
    for (int j = 0; j < 16; j++) {
        int e = ebase * 16 + j;
        float acc = 0.f;
#pragma unroll
        for (int k = 0; k < 8; k++) acc += efs[e][k] * w0r[k];
        acc *= 0.35355339059f;
        hA[e][o] = f2b(acc / (1.f + __expf(-acc)));
    }
    __syncthreads();
    const int wv = t >> 6, lane = t & 63, lr = lane & 15, lkg = lane >> 4;
    {
        f32x4 acc1[4];
#pragma unroll
        for (int ct = 0; ct < 4; ct++) acc1[ct] = (f32x4){0.f, 0.f, 0.f, 0.f};
#pragma unroll
        for (int kk = 0; kk < 2; kk++) {
            s8v a = *reinterpret_cast<const s8v*>(&hA[wv * 16 + lr][kk * 32 + lkg * 8]);
#pragma unroll
            for (int ct = 0; ct < 4; ct++) {
                s8v b = *reinterpret_cast<const s8v*>(w1T + (ct * 16 + lr) * 64 + kk * 32 + lkg * 8);
                acc1[ct] = __builtin_amdgcn_mfma_f32_16x16x32_bf16(a, b, acc1[ct], 0, 0, 0);
            }
        }
#pragma unroll
        for (int ct = 0; ct < 4; ct++)
#pragma unroll
            for (int r = 0; r < 4; r++) {
                float v = acc1[ct][r] * 0.125f;
                hB[wv * 16 + lkg * 4 + r][ct * 16 + lr] = f2b(v / (1.f + __expf(-v)));
            }
    }
    __syncthreads();
    {
        f32x4 acc2[4];
#pragma unroll
        for (int ct = 0; ct < 4; ct++) acc2[ct] = (f32x4){0.f, 0.f, 0.f, 0.f};
#pragma unroll
        for (int kk = 0; kk < 2; kk++) {
            s8v a = *reinterpret_cast<const s8v*>(&hB[wv * 16 + lr][kk * 32 + lkg * 8]);
#pragma unroll
            for (int ct = 0; ct < 4; ct++) {
                s8v b = *reinterpret_cast<const s8v*>(w2T + (ct * 16 + lr) * 64 + kk * 32 + lkg * 8);
                acc2[ct] = __builtin_amdgcn_mfma_f32_16x16x32_bf16(a, b, acc2[ct], 0, 0, 0);
            }
        }
#pragma unroll
        for (int ct = 0; ct < 4; ct++)
#pragma unroll
            for (int r = 0; r < 4; r++) {
                float v = acc2[ct][r] * 0.125f;
                int row = wv * 16 + lkg * 4 + r;
                h2out[(e0 + row) * 64 + ct * 16 + lr] = f2b(v / (1.f + __expf(-v)));
            }
    }
}

// ---------------- CSR build ----------------
__global__ void k_hist(const int* __restrict__ rcv, int* __restrict__ cnt) {
    int e = blockIdx.x * 256 + threadIdx.x;
    if (e < N_EDGES) atomicAdd(&cnt[rcv[e]], 1);
}

__global__ __launch_bounds__(256) void k_scan(const int* __restrict__ cnt, int* __restrict__ base, int* __restrict__ cur) {
    __shared__ int s[256];
    const int t = threadIdx.x;
    const int c0 = t * 40;
    int sum = 0;
    for (int i = 0; i < 40; i++) sum += cnt[c0 + i];
    s[t] = sum;
    __syncthreads();
    for (int off = 1; off < 256; off <<= 1) {
        int v = (t >= off) ? s[t - off] : 0;
        __syncthreads();
        s[t] += v;
        __syncthreads();
    }
    int run = t ? s[t - 1] : 0;
    for (int i = 0; i < 40; i++) {
        int idx = c0 + i;
        if (idx <= N_NODES) { base[idx] = run; cur[idx] = run; }
        run += cnt[idx];
    }
}

__global__ void k_scatter(const int* __restrict__ rcv, int* __restrict__ cur, int* __restrict__ order) {
    int e = blockIdx.x * 256 + threadIdx.x;
    if (e < N_EDGES) {
        int p = atomicAdd(&cur[rcv[e]], 1);
        order[p] = e;
    }
}

// ---------------- fused per-edge, sorted, store-for-complete-runs ----------------
__global__ __launch_bounds__(256, 3) void k_edge2(const unsigned short* __restrict__ h2,
                                                  const unsigned short* __restrict__ w3T,
                                                  const float* __restrict__ eattr,
                                                  const int* __restrict__ snd, const int* __restrict__ rcv,
                                                  const int* __restrict__ order,
                                                  const int* __restrict__ base,
                                                  const unsigned short* __restrict__ xpack,
                                                  float* __restrict__ msg_s, float* __restrict__ msg_v) {
    __shared__ unsigned short h2s[32][72];
    __shared__ unsigned short tpw[32][644];
    __shared__ float es_l[32];
    __shared__ float ev_l[32][3];
    __shared__ int sn_l[32], rc_l[32];
    __shared__ float mrg[128][11];
    __shared__ int bflags[3];   // [0]=base[rc_l[0]], [1]=base[rc_l[16]], [2]=base[rc_l[31]+1]
    const int t = threadIdx.x;
    const int j0 = blockIdx.x * 32;
    {
        int r = t >> 3, kk = (t & 7) * 8;
        int e = order[j0 + r];
        s8v v = *reinterpret_cast<const s8v*>(h2 + (long)e * 64 + kk);
        *reinterpret_cast<s8v*>(&h2s[r][kk]) = v;
    }
    if (t < 32) {
        int e = order[j0 + t];
        es_l[t] = eattr[e * 4 + 0];
        ev_l[t][0] = eattr[e * 4 + 1];
        ev_l[t][1] = eattr[e * 4 + 2];
        ev_l[t][2] = eattr[e * 4 + 3];
        sn_l[t] = snd[e];
        int rc = rcv[e];
        rc_l[t] = rc;
        if (t == 0)  bflags[0] = base[rc];
        if (t == 16) bflags[1] = base[rc];
        if (t == 31) bflags[2] = base[rc + 1];
    }
    __syncthreads();
    const int wv = t >> 6, lane = t & 63, lr = lane & 15, lkg = lane >> 4;
#pragma unroll
    for (int p = 0; p < 20; p++) {
        int ct = wv + 4 * (p % 10);
        int rt = p / 10;
        f32x4 acc = (f32x4){0.f, 0.f, 0.f, 0.f};
#pragma unroll
        for (int ks = 0; ks < 2; ks++) {
            s8v a = *reinterpret_cast<const s8v*>(&h2s[rt * 16 + lr][ks * 32 + lkg * 8]);
            s8v b = *reinterpret_cast<const s8v*>(w3T + (long)(ct * 16 + lr) * 64 + ks * 32 + lkg * 8);
            acc = __builtin_amdgcn_mfma_f32_16x16x32_bf16(a, b, acc, 0, 0, 0);
        }
#pragma unroll
        for (int r = 0; r < 4; r++)
            tpw[rt * 16 + lkg * 4 + r][ct * 16 + lr] = f2b(acc[r] * 0.125f);
    }
    __syncthreads();
    const int c = t & 127, seg = t >> 7;

    u4s xpr[16];
#pragma unroll
    for (int i = 0; i < 16; i++)
        xpr[i] = *reinterpret_cast<const u4s*>(xpack + (long)sn_l[seg * 16 + i] * 512 + c * 4);

    float A[11], F[11];
#pragma unroll
    for (int q = 0; q < 11; q++) { A[q] = 0.f; F[q] = 0.f; }
    int cur_rc = rc_l[seg * 16];
    int Frc = -1;          // rc of held first-run (-1 = not yet transitioned)

#define STORE_RUN(RC, SRC) do { \
        float* ms = msg_s + (long)(RC) * 256 + c; \
        ms[0] = SRC[0]; ms[128] = SRC[1]; \
        float* mv = msg_v + (long)(RC) * 1152 + c; \
        mv[0] = SRC[2]; mv[128] = SRC[3]; mv[256] = SRC[4]; \
        mv[384] = SRC[5]; mv[512] = SRC[6]; mv[640] = SRC[7]; \
        mv[768] = SRC[8]; mv[896] = SRC[9]; mv[1024] = SRC[10]; \
    } while (0)
#define ATOM_RUN(RC, SRC) do { \
        float* ms = msg_s + (long)(RC) * 256 + c; \
        unsafeAtomicAdd(ms, SRC[0]); unsafeAtomicAdd(ms + 128, SRC[1]); \
        float* mv = msg_v + (long)(RC) * 1152 + c; \
        unsafeAtomicAdd(mv + 0, SRC[2]); unsafeAtomicAdd(mv + 128, SRC[3]); \
        unsafeAtomicAdd(mv + 256, SRC[4]); unsafeAtomicAdd(mv + 384, SRC[5]); \
        unsafeAtomicAdd(mv + 512, SRC[6]); unsafeAtomicAdd(mv + 640, SRC[7]); \
        unsafeAtomicAdd(mv + 768, SRC[8]); unsafeAtomicAdd(mv + 896, SRC[9]); \
        unsafeAtomicAdd(mv + 1024, SRC[10]); \
    } while (0)

#pragma unroll
    for (int i = 0; i < 16; i++) {
        int idx = seg * 16 + i;
        int rc = rc_l[idx];
        if (rc != cur_rc) {
            if (Frc < 0) {              // first transition: bank the first run
#pragma unroll
                for (int q = 0; q < 11; q++) { F[q] = A[q]; A[q] = 0.f; }
                Frc = cur_rc;
            } else {                    // middle run: complete within segment -> store
                STORE_RUN(cur_rc, A);
#pragma unroll
                for (int q = 0; q < 11; q++) A[q] = 0.f;
            }
            cur_rc = rc;
        }
        float es = es_l[idx], ev0 = ev_l[idx][0], ev1 = ev_l[idx][1], ev2 = ev_l[idx][2];
        float w1 = b2f(tpw[idx][c]);
        float w2 = b2f(tpw[idx][128 + c]);
        float w3 = b2f(tpw[idx][256 + c]);
        float w4 = b2f(tpw[idx][384 + c]);
        float w5 = b2f(tpw[idx][512 + c]);
        float xsv = b2f(xpr[i][0]);
        float x0 = b2f(xpr[i][1]), x1 = b2f(xpr[i][2]), x2 = b2f(xpr[i][3]);
        A[0] += w1 * xsv * es;
        float dve = x0 * ev0 + x1 * ev1 + x2 * ev2;
        A[1] += w4 * dve * 0.57735026919f;
        float a2 = w2 * xsv;
        A[2] += a2 * ev0;
        A[3] += w3 * x0 * es;
        A[4] += w5 * (x1 * ev2 - x2 * ev1) * 0.70710678119f;
        A[5] += a2 * ev1;
        A[6] += w3 * x1 * es;
        A[7] += w5 * (x2 * ev0 - x0 * ev2) * 0.70710678119f;
        A[8] += a2 * ev2;
        A[9] += w3 * x2 * es;
        A[10] += w5 * (x0 * ev1 - x1 * ev0) * 0.70710678119f;
    }
    // A now holds the segment's LAST run (rc == cur_rc); F holds first run if Frc>=0.
    const bool merge = (rc_l[15] == rc_l[16]);   // block-uniform
    if (seg == 0) {
        if (merge) {
            // pass last run to seg1
#pragma unroll
            for (int q = 0; q < 11; q++) mrg[c][q] = A[q];
            if (Frc >= 0) {  // flush banked first run
                if (bflags[0] == j0) STORE_RUN(Frc, F); else ATOM_RUN(Frc, F);
            }
        } else {
            // last run ends exactly at j0+16 -> complete on right
            if (Frc < 0) {   // single run spans whole segment
                if (bflags[0] == j0) STORE_RUN(cur_rc, A); else ATOM_RUN(cur_rc, A);
            } else {
                if (bflags[0] == j0) STORE_RUN(Frc, F); else ATOM_RUN(Frc, F);
                STORE_RUN(cur_rc, A);   // starts inside, ends at boundary -> complete
            }
        }
    } else {
        // seg1: first run (F or A if single) starts exactly at j0+16 unless merged
        if (!merge) {
            if (Frc < 0) {   // single run: left-complete; right depends on tile end
                if (bflags[2] == j0 + 32) STORE_RUN(cur_rc, A); else ATOM_RUN(cur_rc, A);
            } else {
                STORE_RUN(Frc, F);      // starts at seg boundary, ends inside -> complete
                if (bflags[2] == j0 + 32) STORE_RUN(cur_rc, A); else ATOM_RUN(cur_rc, A);
            }
        }
    }
    __syncthreads();
    if (seg == 1 && merge) {
        if (Frc < 0) {       // single run across whole seg1, merged with seg0's tail
#pragma unroll
            for (int q = 0; q < 11; q++) A[q] += mrg[c][q];
            bool st = (bflags[1] >= j0) && (bflags[2] == j0 + 32);
            if (st) STORE_RUN(cur_rc, A); else ATOM_RUN(cur_rc, A);
        } else {
#pragma unroll
            for (int q = 0; q < 11; q++) F[q] += mrg[c][q];
            if (bflags[1] >= j0) STORE_RUN(Frc, F); else ATOM_RUN(Frc, F);
            if (bflags[2] == j0 + 32) STORE_RUN(cur_rc, A); else ATOM_RUN(cur_rc, A);
        }
    }
#undef STORE_RUN
#undef ATOM_RUN
}

extern "C" void kernel_launch(void* const* d_in, const int* in_sizes, int n_in,
                              void* d_out, int out_size, void* d_ws, size_t ws_size,
                              hipStream_t stream) {
    const float* node_attrs = (const float*)d_in[0];
    const float* nfs        = (const float*)d_in[1];
    const float* nfv        = (const float*)d_in[2];
    const float* edge_attrs = (const float*)d_in[3];
    const float* edge_feats = (const float*)d_in[4];
    const float* W_sc_s     = (const float*)d_in[5];
    const float* W_sc_v     = (const float*)d_in[6];
    const float* W_lin_s    = (const float*)d_in[7];
    const float* W_lin_v    = (const float*)d_in[8];
    const float* mlp_w0     = (const float*)d_in[9];
    const float* mlp_w1     = (const float*)d_in[10];
    const float* mlp_w2     = (const float*)d_in[11];
    const float* mlp_w3     = (const float*)d_in[12];
    const float* W_out_s    = (const float*)d_in[13];
    const float* W_out_v    = (const float*)d_in[14];
    const int* senders      = (const int*)d_in[15];
    const int* receivers    = (const int*)d_in[16];
    float* dout = (float*)d_out;

    char* W = (char*)d_ws;
    unsigned short* xpack_ws = (unsigned short*)(W + 0);        // 10,240,000
    float* msgs_ws = (float*)(W + 10240000);   // 10,240,000
    float* msgv_ws = (float*)(W + 20480000);   // 46,080,000 -> ends 66,560,000
    unsigned short* h2_ws   = (unsigned short*)(W + 66560000);  // 20,480,000 -> ends 87,040,000
    unsigned short* wsc_s2  = (unsigned short*)(W + 87040000);
    unsigned short* wsc_v2  = (unsigned short*)(W + 87367680);
    unsigned short* wlin_sT = (unsigned short*)(W + 87695360);
    unsigned short* wlin_vT = (unsigned short*)(W + 87728128);
    unsigned short* wout_sT = (unsigned short*)(W + 87760896);
    unsigned short* wout_vT = (unsigned short*)(W + 87826432);
    unsigned short* w3T     = (unsigned short*)(W + 87924736);
    unsigned short* w1T     = (unsigned short*)(W + 88006656);
    unsigned short* w2T     = (unsigned short*)(W + 88014848);
    int* cnt_ws   = (int*)(W + 88023040);
    int* base_ws  = (int*)(W + 88064000);
    int* cur_ws   = (int*)(W + 88104960);
    int* order_ws = (int*)(W + 88145920);   // ends 88,785,920

    const float inv1280 = 0.02795084972f;
    const float inv128  = 0.08838834765f;
    const float scO_s   = 1.f / 256.f;
    const float scO_v   = 1.f / (19.5959179423f * 16.f);

    k_prep<<<dim3(640, 9, 1), 256, 0, stream>>>(W_sc_s, W_sc_v, W_lin_s, W_lin_v, W_out_s, W_out_v, mlp_w3,
                                                mlp_w1, mlp_w2,
                                                wsc_s2, wsc_v2, wlin_sT, wlin_vT, wout_sT, wout_vT, w3T,
                                                w1T, w2T);
    k_mlp012<<<dim3(2500), 256, 0, stream>>>(edge_feats, mlp_w0, w1T, w2T, h2_ws);

    // sc -> d_out second half (factorized tensor-product GEMM)
    k_sc<<<dim3(157, 4), 256, 0, stream>>>(nfs, nfv, node_attrs, wsc_s2, wsc_v2, dout + 5120000, inv1280);

    // x_s / x_v -> xpack (bf16, interleaved [n][c][4])
    {
        GemmZ g0{nfs,     128, 1, wlin_sT, (float*)(xpack_ws + 0), 512, 4, 128, inv128, N_NODES, 1};
        GemmZ g1{nfv + 0, 384, 3, wlin_vT, (float*)(xpack_ws + 1), 512, 4, 128, inv128, N_NODES, 1};
        GemmZ g2{nfv + 1, 384, 3, wlin_vT, (float*)(xpack_ws + 2), 512, 4, 128, inv128, N_NODES, 1};
        GemmZ g3{nfv + 2, 384, 3, wlin_vT, (float*)(xpack_ws + 3), 512, 4, 128, inv128, N_NODES, 1};
        k_gemm<<<dim3(157, 1, 4), 256, 0, stream>>>(g0, g1, g2, g3);
    }

    hipMemsetAsync(msgs_ws, 0, 56320000, stream);  // msg_s + msg_v
    hipMemsetAsync(cnt_ws, 0, 40960, stream);
    k_hist<<<dim3(625), 256, 0, stream>>>(receivers, cnt_ws);
    k_scan<<<dim3(1), 256, 0, stream>>>(cnt_ws, base_ws, cur_ws);
    k_scatter<<<dim3(625), 256, 0, stream>>>(receivers, cur_ws, order_ws);
    k_edge2<<<dim3(5000), 256, 0, stream>>>(h2_ws, w3T, edge_attrs, senders, receivers, order_ws,
                                            base_ws, xpack_ws, msgs_ws, msgv_ws);

    // out = msg @ W_out -> d_out first half
    {
        GemmZ g0{msgs_ws,       256,  1, wout_sT, dout,           512, 1, 256, scO_s, N_NODES, 0};
        GemmZ g1{msgv_ws + 0,   1152, 1, wout_vT, dout + 128 + 0, 512, 3, 384, scO_v, N_NODES, 0};
        GemmZ g2{msgv_ws + 384, 1152, 1, wout_vT, dout + 128 + 1, 512, 3, 384, scO_v, N_NODES, 0};
        GemmZ g3{msgv_ws + 768, 1152, 1, wout_vT, dout + 128 + 2, 512, 3, 384, scO_v, N_NODES, 0};
        k_gemm<<<dim3(157, 1, 4), 256, 0, stream>>>(g0, g1, g2, g3);
    }
}

// Round 9
// 356.878 us; speedup vs baseline: 3.2242x; 1.0572x over previous
//
#include <hip/hip_runtime.h>

#define N_NODES 10000
#define N_EDGES 160000

typedef float f32x4 __attribute__((ext_vector_type(4)));
typedef short s8v __attribute__((ext_vector_type(8)));
typedef short s4v __attribute__((ext_vector_type(4)));
typedef unsigned short u4s __attribute__((ext_vector_type(4)));

__device__ __forceinline__ unsigned short f2b(float f) {
    unsigned u = __builtin_bit_cast(unsigned, f);
    u += 0x7FFFu + ((u >> 16) & 1u);
    return (unsigned short)(u >> 16);
}
__device__ __forceinline__ float b2f(unsigned short s) {
    unsigned u = ((unsigned)s) << 16;
    return __builtin_bit_cast(float, u);
}

// ---------------- prep: weight matrices -> bf16, layouts for MFMA ----------------
__global__ void k_prep(const float* s0, const float* s1, const float* s2, const float* s3,
                       const float* s4, const float* s5, const float* s6,
                       const float* s7, const float* s8,
                       unsigned short* d0, unsigned short* d1, unsigned short* d2, unsigned short* d3,
                       unsigned short* d4, unsigned short* d5, unsigned short* d6,
                       unsigned short* d7, unsigned short* d8) {
    int idx = blockIdx.x * 256 + threadIdx.x;
    if (blockIdx.y < 2) {
        const float* src = blockIdx.y ? s1 : s0;
        unsigned short* dst = blockIdx.y ? d1 : d0;
        int k = idx >> 7, o = idx & 127;
        int ci = k / 10, a = k - ci * 10;
        dst[a * 16384 + o * 128 + ci] = f2b(src[idx]);
        return;
    }
    const float* src; unsigned short* dst; int K, Nc;
    switch (blockIdx.y) {
        case 2: src = s2; dst = d2; K = 128;  Nc = 128; break;
        case 3: src = s3; dst = d3; K = 128;  Nc = 128; break;
        case 4: src = s4; dst = d4; K = 256;  Nc = 128; break;
        case 5: src = s5; dst = d5; K = 384;  Nc = 128; break;
        case 6: src = s6; dst = d6; K = 64;   Nc = 640; break;
        case 7: src = s7; dst = d7; K = 64;   Nc = 64;  break;
        default: src = s8; dst = d8; K = 64;  Nc = 64;  break;
    }
    if (idx < K * Nc) {
        int k = idx / Nc, c = idx - k * Nc;
        dst[c * K + k] = f2b(src[idx]);
    }
}

// ---------------- sc: out[n, o] = inv1280 * sum_a attr[n,a] * (A_z @ W_a)[n, o] ----------------
__global__ __launch_bounds__(256) void k_sc(const float* __restrict__ nfs,
                                            const float* __restrict__ nfv,
                                            const float* __restrict__ attr,
                                            const unsigned short* __restrict__ Ws2,
                                            const unsigned short* __restrict__ Wv2,
                                            float* __restrict__ out, float scale) {
    __shared__ unsigned short As[64][136];
    __shared__ unsigned short Bs[128][140];
    __shared__ float attr_l[64][10];
    const int t = threadIdx.x;
    const int z = blockIdx.y;
    const int row0 = blockIdx.x * 64;
    const int wv = t >> 6, lane = t & 63, lr = lane & 15, lkg = lane >> 4;

    {
        int r = t >> 2, k0 = (t & 3) * 32;
        int row = row0 + r;
        if (z == 0) {
            if (row < N_NODES) {
#pragma unroll
                for (int j = 0; j < 8; j++) {
                    f32x4 v = *reinterpret_cast<const f32x4*>(nfs + (long)row * 128 + k0 + j * 4);
                    As[r][k0 + j * 4 + 0] = f2b(v[0]);
                    As[r][k0 + j * 4 + 1] = f2b(v[1]);
                    As[r][k0 + j * 4 + 2] = f2b(v[2]);
                    As[r][k0 + j * 4 + 3] = f2b(v[3]);
                }
            } else {
#pragma unroll
                for (int j = 0; j < 32; j++) As[r][k0 + j] = 0;
            }
        } else {
            int i = z - 1;
            if (row < N_NODES) {
#pragma unroll
                for (int j = 0; j < 32; j++)
                    As[r][k0 + j] = f2b(nfv[(long)row * 384 + (k0 + j) * 3 + i]);
            } else {
#pragma unroll
                for (int j = 0; j < 32; j++) As[r][k0 + j] = 0;
            }
        }
    }
    for (int idx = t; idx < 640; idx += 256) {
        int r = idx / 10, a = idx - r * 10;
        int row = row0 + r;
        attr_l[r][a] = (row < N_NODES) ? attr[row * 10 + a] : 0.f;
    }
    __syncthreads();

    s8v af[4];
#pragma unroll
    for (int kk = 0; kk < 4; kk++)
        af[kk] = *reinterpret_cast<const s8v*>(&As[wv * 16 + lr][kk * 32 + lkg * 8]);

    f32x4 accS[8];
#pragma unroll
    for (int i = 0; i < 8; i++) accS[i] = (f32x4){0.f, 0.f, 0.f, 0.f};

    const unsigned short* Wbase = (z == 0) ? Ws2 : Wv2;
    for (int a = 0; a < 10; a++) {
        {
            const unsigned short* src = Wbase + a * 16384;
            int r = t >> 1, c0 = (t & 1) * 64;
#pragma unroll
            for (int j = 0; j < 8; j++) {
                s8v v = *reinterpret_cast<const s8v*>(src + r * 128 + c0 + j * 8);
                *reinterpret_cast<s8v*>(&Bs[r][c0 + j * 8]) = v;
            }
        }
        __syncthreads();
        f32x4 acc[8];
#pragma unroll
        for (int i = 0; i < 8; i++) acc[i] = (f32x4){0.f, 0.f, 0.f, 0.f};
#pragma unroll
        for (int kk = 0; kk < 4; kk++) {
#pragma unroll
            for (int ct = 0; ct < 8; ct++) {
                s8v bf = *reinterpret_cast<const s8v*>(&Bs[ct * 16 + lr][kk * 32 + lkg * 8]);
                acc[ct] = __builtin_amdgcn_mfma_f32_16x16x32_bf16(af[kk], bf, acc[ct], 0, 0, 0);
            }
        }
#pragma unroll
        for (int r = 0; r < 4; r++) {
            float aw = attr_l[wv * 16 + lkg * 4 + r][a];
#pragma unroll
            for (int ct = 0; ct < 8; ct++)
                accS[ct][r] += aw * acc[ct][r];
        }
        __syncthreads();
    }
#pragma unroll
    for (int ct = 0; ct < 8; ct++) {
#pragma unroll
        for (int r = 0; r < 4; r++) {
            int row = row0 + wv * 16 + lkg * 4 + r;
            if (row < N_NODES) {
                int col = ct * 16 + lr;
                if (z == 0) out[(long)row * 512 + col] = accS[ct][r] * scale;
                else        out[(long)row * 512 + 128 + col * 3 + (z - 1)] = accS[ct][r] * scale;
            }
        }
    }
}

// ---------------- generic MFMA GEMM (x and out GEMMs) ----------------
struct GemmZ {
    const float* Ap;
    int ars, aks;
    const unsigned short* Bt;
    float* Cp;
    int crs, ccs;
    int K;
    float scale;
    int M;
    int obf16;
};

__global__ __launch_bounds__(256) void k_gemm(GemmZ g0, GemmZ g1, GemmZ g2, GemmZ g3) {
    GemmZ g;
    switch (blockIdx.z) { case 0: g = g0; break; case 1: g = g1; break; case 2: g = g2; break; default: g = g3; }
    __shared__ unsigned short As[64][40];
    const int t = threadIdx.x;
    const int wv = t >> 6, lane = t & 63;
    const int lr = lane & 15, lkg = lane >> 4;
    const int row0 = blockIdx.x * 64;
    const int br = t >> 2;
    const int bk0 = (t & 3) * 8;
    const int arow = row0 + br;

    f32x4 acc[8];
#pragma unroll
    for (int i = 0; i < 8; i++) acc[i] = (f32x4){0.f, 0.f, 0.f, 0.f};

    for (int k0 = 0; k0 < g.K; k0 += 32) {
        s8v av;
        if (arow < g.M) {
            if (g.aks == 1) {
                const float* ap = g.Ap + (long)arow * g.ars + k0 + bk0;
                f32x4 v0 = *reinterpret_cast<const f32x4*>(ap);
                f32x4 v1 = *reinterpret_cast<const f32x4*>(ap + 4);
                av[0] = (short)f2b(v0[0]); av[1] = (short)f2b(v0[1]);
                av[2] = (short)f2b(v0[2]); av[3] = (short)f2b(v0[3]);
                av[4] = (short)f2b(v1[0]); av[5] = (short)f2b(v1[1]);
                av[6] = (short)f2b(v1[2]); av[7] = (short)f2b(v1[3]);
            } else {
#pragma unroll
                for (int j = 0; j < 8; j++)
                    av[j] = (short)f2b(g.Ap[(long)arow * g.ars + (long)(k0 + bk0 + j) * g.aks]);
            }
        } else {
#pragma unroll
            for (int j = 0; j < 8; j++) av[j] = 0;
        }
        __syncthreads();
        *reinterpret_cast<s8v*>(&As[br][bk0]) = av;
        __syncthreads();
        s8v af = *reinterpret_cast<const s8v*>(&As[wv * 16 + lr][lkg * 8]);
#pragma unroll
        for (int ct = 0; ct < 8; ct++) {
            const unsigned short* bp = g.Bt + (long)(ct * 16 + lr) * g.K + k0 + lkg * 8;
            s8v bf = *reinterpret_cast<const s8v*>(bp);
            acc[ct] = __builtin_amdgcn_mfma_f32_16x16x32_bf16(af, bf, acc[ct], 0, 0, 0);
        }
    }
#pragma unroll
    for (int ct = 0; ct < 8; ct++) {
#pragma unroll
        for (int r = 0; r < 4; r++) {
            int row = row0 + wv * 16 + lkg * 4 + r;
            if (row < g.M) {
                int col = ct * 16 + lr;
                if (g.obf16)
                    ((unsigned short*)g.Cp)[(long)row * g.crs + col * g.ccs] = f2b(acc[ct][r] * g.scale);
                else
                    g.Cp[(long)row * g.crs + col * g.ccs] = acc[ct][r] * g.scale;
            }
        }
    }
}

// ---------------- MLP: layer0 VALU, layers 1-2 MFMA ----------------
__global__ __launch_bounds__(256) void k_mlp012(const float* __restrict__ ef, const float* __restrict__ w0,
                                                const unsigned short* __restrict__ w1T,
                                                const unsigned short* __restrict__ w2T,
                                                unsigned short* __restrict__ h2out) {
    __shared__ float efs[64][8];
    __shared__ unsigned short hA[64][72];
    __shared__ unsigned short hB[64][72];
    const int t = threadIdx.x;
    const long e0 = (long)blockIdx.x * 64;
#pragma unroll
    for (int j = 0; j < 2; j++) { int idx = t + j * 256; ((float*)efs)[idx] = ef[e0 * 8 + idx]; }
    const int o = t & 63, ebase = t >> 6;
    float w0r[8];
#pragma unroll
    for (int k = 0; k < 8; k++) w0r[k] = w0[k * 64 + o];
    __syncthreads();
#pragma unroll
    for (int j = 0; j < 16; j++) {
        int e = ebase * 16 + j;
        float acc = 0.f;
#pragma unroll
        for (int k = 0; k < 8; k++) acc += efs[e][k] * w0r[k];
        acc *= 0.35355339059f;
        hA[e][o] = f2b(acc / (1.f + __expf(-acc)));
    }
    __syncthreads();
    const int wv = t >> 6, lane = t & 63, lr = lane & 15, lkg = lane >> 4;
    {
        f32x4 acc1[4];
#pragma unroll
        for (int ct = 0; ct < 4; ct++) acc1[ct] = (f32x4){0.f, 0.f, 0.f, 0.f};
#pragma unroll
        for (int kk = 0; kk < 2; kk++) {
            s8v a = *reinterpret_cast<const s8v*>(&hA[wv * 16 + lr][kk * 32 + lkg * 8]);
#pragma unroll
            for (int ct = 0; ct < 4; ct++) {
                s8v b = *reinterpret_cast<const s8v*>(w1T + (ct * 16 + lr) * 64 + kk * 32 + lkg * 8);
                acc1[ct] = __builtin_amdgcn_mfma_f32_16x16x32_bf16(a, b, acc1[ct], 0, 0, 0);
            }
        }
#pragma unroll
        for (int ct = 0; ct < 4; ct++)
#pragma unroll
            for (int r = 0; r < 4; r++) {
                float v = acc1[ct][r] * 0.125f;
                hB[wv * 16 + lkg * 4 + r][ct * 16 + lr] = f2b(v / (1.f + __expf(-v)));
            }
    }
    __syncthreads();
    {
        f32x4 acc2[4];
#pragma unroll
        for (int ct = 0; ct < 4; ct++) acc2[ct] = (f32x4){0.f, 0.f, 0.f, 0.f};
#pragma unroll
        for (int kk = 0; kk < 2; kk++) {
            s8v a = *reinterpret_cast<const s8v*>(&hB[wv * 16 + lr][kk * 32 + lkg * 8]);
#pragma unroll
            for (int ct = 0; ct < 4; ct++) {
                s8v b = *reinterpret_cast<const s8v*>(w2T + (ct * 16 + lr) * 64 + kk * 32 + lkg * 8);
                acc2[ct] = __builtin_amdgcn_mfma_f32_16x16x32_bf16(a, b, acc2[ct], 0, 0, 0);
            }
        }
#pragma unroll
        for (int ct = 0; ct < 4; ct++)
#pragma unroll
            for (int r = 0; r < 4; r++) {
                float v = acc2[ct][r] * 0.125f;
                int row = wv * 16 + lkg * 4 + r;
                h2out[(e0 + row) * 64 + ct * 16 + lr] = f2b(v / (1.f + __expf(-v)));
            }
    }
}

// ---------------- CSR build ----------------
__global__ void k_hist(const int* __restrict__ rcv, int* __restrict__ cnt) {
    int e = blockIdx.x * 256 + threadIdx.x;
    if (e < N_EDGES) atomicAdd(&cnt[rcv[e]], 1);
}

__global__ __launch_bounds__(256) void k_scan(const int* __restrict__ cnt, int* __restrict__ base, int* __restrict__ cur) {
    __shared__ int s[256];
    const int t = threadIdx.x;
    const int c0 = t * 40;
    int sum = 0;
    for (int i = 0; i < 40; i++) sum += cnt[c0 + i];
    s[t] = sum;
    __syncthreads();
    for (int off = 1; off < 256; off <<= 1) {
        int v = (t >= off) ? s[t - off] : 0;
        __syncthreads();
        s[t] += v;
        __syncthreads();
    }
    int run = t ? s[t - 1] : 0;
    for (int i = 0; i < 40; i++) {
        int idx = c0 + i;
        if (idx <= N_NODES) { base[idx] = run; cur[idx] = run; }
        run += cnt[idx];
    }
}

__global__ void k_scatter(const int* __restrict__ rcv, int* __restrict__ cur, int* __restrict__ order) {
    int e = blockIdx.x * 256 + threadIdx.x;
    if (e < N_EDGES) {
        int p = atomicAdd(&cur[rcv[e]], 1);
        order[p] = e;
    }
}

// ---------------- fused per-edge: b-reuse MFMA, transposed tpw, store-runs ----------------
__global__ __launch_bounds__(256, 3) void k_edge2(const unsigned short* __restrict__ h2,
                                                  const unsigned short* __restrict__ w3T,
                                                  const float* __restrict__ eattr,
                                                  const int* __restrict__ snd, const int* __restrict__ rcv,
                                                  const int* __restrict__ order,
                                                  const int* __restrict__ base,
                                                  const unsigned short* __restrict__ xpack,
                                                  float* __restrict__ msg_s, float* __restrict__ msg_v) {
    __shared__ char smem_u[5760];                 // union: h2s [32][72] u16 | mrg [128][11] f32
    __shared__ unsigned short tpwT[640 * 36];     // [col][edge], stride 36 u16 (72B, 8B-aligned)
    __shared__ float es_l[32];
    __shared__ float ev_l[32][3];
    __shared__ int sn_l[32], rc_l[32];
    __shared__ int bflags[3];
    unsigned short (*h2s)[72] = (unsigned short(*)[72])smem_u;
    float (*mrg)[11] = (float(*)[11])smem_u;
    const int t = threadIdx.x;
    const int j0 = blockIdx.x * 32;
    {
        int r = t >> 3, kk = (t & 7) * 8;
        int e = order[j0 + r];
        s8v v = *reinterpret_cast<const s8v*>(h2 + (long)e * 64 + kk);
        *reinterpret_cast<s8v*>(&h2s[r][kk]) = v;
    }
    if (t < 32) {
        int e = order[j0 + t];
        es_l[t] = eattr[e * 4 + 0];
        ev_l[t][0] = eattr[e * 4 + 1];
        ev_l[t][1] = eattr[e * 4 + 2];
        ev_l[t][2] = eattr[e * 4 + 3];
        sn_l[t] = snd[e];
        int rc = rcv[e];
        rc_l[t] = rc;
        if (t == 0)  bflags[0] = base[rc];
        if (t == 16) bflags[1] = base[rc];
        if (t == 31) bflags[2] = base[rc + 1];
    }
    __syncthreads();
    const int wv = t >> 6, lane = t & 63, lr = lane & 15, lkg = lane >> 4;
    // a-fragments once (edges 0..15 and 16..31)
    s8v a00 = *reinterpret_cast<const s8v*>(&h2s[lr][lkg * 8]);
    s8v a01 = *reinterpret_cast<const s8v*>(&h2s[lr][32 + lkg * 8]);
    s8v a10 = *reinterpret_cast<const s8v*>(&h2s[16 + lr][lkg * 8]);
    s8v a11 = *reinterpret_cast<const s8v*>(&h2s[16 + lr][32 + lkg * 8]);
#pragma unroll
    for (int q = 0; q < 10; q++) {
        int co = (wv + 4 * q) * 16 + lr;
        const unsigned short* bp = w3T + (long)co * 64 + lkg * 8;
        s8v b0 = *reinterpret_cast<const s8v*>(bp);
        s8v b1 = *reinterpret_cast<const s8v*>(bp + 32);
        f32x4 ac0 = (f32x4){0.f, 0.f, 0.f, 0.f};
        f32x4 ac1 = (f32x4){0.f, 0.f, 0.f, 0.f};
        ac0 = __builtin_amdgcn_mfma_f32_16x16x32_bf16(a00, b0, ac0, 0, 0, 0);
        ac0 = __builtin_amdgcn_mfma_f32_16x16x32_bf16(a01, b1, ac0, 0, 0, 0);
        ac1 = __builtin_amdgcn_mfma_f32_16x16x32_bf16(a10, b0, ac1, 0, 0, 0);
        ac1 = __builtin_amdgcn_mfma_f32_16x16x32_bf16(a11, b1, ac1, 0, 0, 0);
        u4s p0, p1;
#pragma unroll
        for (int r = 0; r < 4; r++) {
            p0[r] = f2b(ac0[r] * 0.125f);
            p1[r] = f2b(ac1[r] * 0.125f);
        }
        *reinterpret_cast<u4s*>(&tpwT[co * 36 + lkg * 4]) = p0;
        *reinterpret_cast<u4s*>(&tpwT[co * 36 + 16 + lkg * 4]) = p1;
    }
    __syncthreads();
    const int c = t & 127, seg = t >> 7;

    // prefetch sender gathers (random, long latency) first
    u4s xpr[16];
#pragma unroll
    for (int i = 0; i < 16; i++)
        xpr[i] = *reinterpret_cast<const u4s*>(xpack + (long)sn_l[seg * 16 + i] * 512 + c * 4);
    // hoist all 5 w-vectors (16 edges each) via b64 LDS reads
    s4v wsv[5][4];
#pragma unroll
    for (int q = 0; q < 5; q++)
#pragma unroll
        for (int j = 0; j < 4; j++)
            wsv[q][j] = *reinterpret_cast<const s4v*>(&tpwT[(q * 128 + c) * 36 + seg * 16 + j * 4]);

    float A[11], F[11];
#pragma unroll
    for (int q = 0; q < 11; q++) { A[q] = 0.f; F[q] = 0.f; }
    int cur_rc = rc_l[seg * 16];
    int Frc = -1;

#define STORE_RUN(RC, SRC) do { \
        float* ms = msg_s + (long)(RC) * 256 + c; \
        ms[0] = SRC[0]; ms[128] = SRC[1]; \
        float* mv = msg_v + (long)(RC) * 1152 + c; \
        mv[0] = SRC[2]; mv[128] = SRC[3]; mv[256] = SRC[4]; \
        mv[384] = SRC[5]; mv[512] = SRC[6]; mv[640] = SRC[7]; \
        mv[768] = SRC[8]; mv[896] = SRC[9]; mv[1024] = SRC[10]; \
    } while (0)
#define ATOM_RUN(RC, SRC) do { \
        float* ms = msg_s + (long)(RC) * 256 + c; \
        unsafeAtomicAdd(ms, SRC[0]); unsafeAtomicAdd(ms + 128, SRC[1]); \
        float* mv = msg_v + (long)(RC) * 1152 + c; \
        unsafeAtomicAdd(mv + 0, SRC[2]); unsafeAtomicAdd(mv + 128, SRC[3]); \
        unsafeAtomicAdd(mv + 256, SRC[4]); unsafeAtomicAdd(mv + 384, SRC[5]); \
        unsafeAtomicAdd(mv + 512, SRC[6]); unsafeAtomicAdd(mv + 640, SRC[7]); \
        unsafeAtomicAdd(mv + 768, SRC[8]); unsafeAtomicAdd(mv + 896, SRC[9]); \
        unsafeAtomicAdd(mv + 1024, SRC[10]); \
    } while (0)

#pragma unroll
    for (int i = 0; i < 16; i++) {
        int idx = seg * 16 + i;
        int rc = rc_l[idx];
        if (rc != cur_rc) {
            if (Frc < 0) {
#pragma unroll
                for (int q = 0; q < 11; q++) { F[q] = A[q]; A[q] = 0.f; }
                Frc = cur_rc;
            } else {
                STORE_RUN(cur_rc, A);
#pragma unroll
                for (int q = 0; q < 11; q++) A[q] = 0.f;
            }
            cur_rc = rc;
        }
        float es = es_l[idx], ev0 = ev_l[idx][0], ev1 = ev_l[idx][1], ev2 = ev_l[idx][2];
        float w1 = b2f((unsigned short)wsv[0][i >> 2][i & 3]);
        float w2 = b2f((unsigned short)wsv[1][i >> 2][i & 3]);
        float w3 = b2f((unsigned short)wsv[2][i >> 2][i & 3]);
        float w4 = b2f((unsigned short)wsv[3][i >> 2][i & 3]);
        float w5 = b2f((unsigned short)wsv[4][i >> 2][i & 3]);
        float xsv = b2f(xpr[i][0]);
        float x0 = b2f(xpr[i][1]), x1 = b2f(xpr[i][2]), x2 = b2f(xpr[i][3]);
        A[0] += w1 * xsv * es;
        float dve = x0 * ev0 + x1 * ev1 + x2 * ev2;
        A[1] += w4 * dve * 0.57735026919f;
        float a2 = w2 * xsv;
        A[2] += a2 * ev0;
        A[3] += w3 * x0 * es;
        A[4] += w5 * (x1 * ev2 - x2 * ev1) * 0.70710678119f;
        A[5] += a2 * ev1;
        A[6] += w3 * x1 * es;
        A[7] += w5 * (x2 * ev0 - x0 * ev2) * 0.70710678119f;
        A[8] += a2 * ev2;
        A[9] += w3 * x2 * es;
        A[10] += w5 * (x0 * ev1 - x1 * ev0) * 0.70710678119f;
    }
    const bool merge = (rc_l[15] == rc_l[16]);
    if (seg == 0) {
        if (merge) {
#pragma unroll
            for (int q = 0; q < 11; q++) mrg[c][q] = A[q];
            if (Frc >= 0) {
                if (bflags[0] == j0) STORE_RUN(Frc, F); else ATOM_RUN(Frc, F);
            }
        } else {
            if (Frc < 0) {
                if (bflags[0] == j0) STORE_RUN(cur_rc, A); else ATOM_RUN(cur_rc, A);
            } else {
                if (bflags[0] == j0) STORE_RUN(Frc, F); else ATOM_RUN(Frc, F);
                STORE_RUN(cur_rc, A);
            }
        }
    } else {
        if (!merge) {
            if (Frc < 0) {
                if (bflags[2] == j0 + 32) STORE_RUN(cur_rc, A); else ATOM_RUN(cur_rc, A);
            } else {
                STORE_RUN(Frc, F);
                if (bflags[2] == j0 + 32) STORE_RUN(cur_rc, A); else ATOM_RUN(cur_rc, A);
            }
        }
    }
    __syncthreads();
    if (seg == 1 && merge) {
        if (Frc < 0) {
#pragma unroll
            for (int q = 0; q < 11; q++) A[q] += mrg[c][q];
            bool st = (bflags[1] >= j0) && (bflags[2] == j0 + 32);
            if (st) STORE_RUN(cur_rc, A); else ATOM_RUN(cur_rc, A);
        } else {
#pragma unroll
            for (int q = 0; q < 11; q++) F[q] += mrg[c][q];
            if (bflags[1] >= j0) STORE_RUN(Frc, F); else ATOM_RUN(Frc, F);
            if (bflags[2] == j0 + 32) STORE_RUN(cur_rc, A); else ATOM_RUN(cur_rc, A);
        }
    }
#undef STORE_RUN
#undef ATOM_RUN
}

extern "C" void kernel_launch(void* const* d_in, const int* in_sizes, int n_in,
                              void* d_out, int out_size, void* d_ws, size_t ws_size,
                              hipStream_t stream) {
    const float* node_attrs = (const float*)d_in[0];
    const float* nfs        = (const float*)d_in[1];
    const float* nfv        = (const float*)d_in[2];
    const float* edge_attrs = (const float*)d_in[3];
    const float* edge_feats = (const float*)d_in[4];
    const float* W_sc_s     = (const float*)d_in[5];
    const float* W_sc_v     = (const float*)d_in[6];
    const float* W_lin_s    = (const float*)d_in[7];
    const float* W_lin_v    = (const float*)d_in[8];
    const float* mlp_w0     = (const float*)d_in[9];
    const float* mlp_w1     = (const float*)d_in[10];
    const float* mlp_w2     = (const float*)d_in[11];
    const float* mlp_w3     = (const float*)d_in[12];
    const float* W_out_s    = (const float*)d_in[13];
    const float* W_out_v    = (const float*)d_in[14];
    const int* senders      = (const int*)d_in[15];
    const int* receivers    = (const int*)d_in[16];
    float* dout = (float*)d_out;

    char* W = (char*)d_ws;
    unsigned short* xpack_ws = (unsigned short*)(W + 0);        // 10,240,000
    float* msgs_ws = (float*)(W + 10240000);   // 10,240,000
    float* msgv_ws = (float*)(W + 20480000);   // 46,080,000 -> ends 66,560,000
    unsigned short* h2_ws   = (unsigned short*)(W + 66560000);  // 20,480,000 -> ends 87,040,000
    unsigned short* wsc_s2  = (unsigned short*)(W + 87040000);
    unsigned short* wsc_v2  = (unsigned short*)(W + 87367680);
    unsigned short* wlin_sT = (unsigned short*)(W + 87695360);
    unsigned short* wlin_vT = (unsigned short*)(W + 87728128);
    unsigned short* wout_sT = (unsigned short*)(W + 87760896);
    unsigned short* wout_vT = (unsigned short*)(W + 87826432);
    unsigned short* w3T     = (unsigned short*)(W + 87924736);
    unsigned short* w1T     = (unsigned short*)(W + 88006656);
    unsigned short* w2T     = (unsigned short*)(W + 88014848);
    int* cnt_ws   = (int*)(W + 88023040);
    int* base_ws  = (int*)(W + 88064000);
    int* cur_ws   = (int*)(W + 88104960);
    int* order_ws = (int*)(W + 88145920);   // ends 88,785,920

    const float inv1280 = 0.02795084972f;
    const float inv128  = 0.08838834765f;
    const float scO_s   = 1.f / 256.f;
    const float scO_v   = 1.f / (19.5959179423f * 16.f);

    k_prep<<<dim3(640, 9, 1), 256, 0, stream>>>(W_sc_s, W_sc_v, W_lin_s, W_lin_v, W_out_s, W_out_v, mlp_w3,
                                                mlp_w1, mlp_w2,
                                                wsc_s2, wsc_v2, wlin_sT, wlin_vT, wout_sT, wout_vT, w3T,
                                                w1T, w2T);
    k_mlp012<<<dim3(2500), 256, 0, stream>>>(edge_feats, mlp_w0, w1T, w2T, h2_ws);

    // sc -> d_out second half (factorized tensor-product GEMM)
    k_sc<<<dim3(157, 4), 256, 0, stream>>>(nfs, nfv, node_attrs, wsc_s2, wsc_v2, dout + 5120000, inv1280);

    // x_s / x_v -> xpack (bf16, interleaved [n][c][4])
    {
        GemmZ g0{nfs,     128, 1, wlin_sT, (float*)(xpack_ws + 0), 512, 4, 128, inv128, N_NODES, 1};
        GemmZ g1{nfv + 0, 384, 3, wlin_vT, (float*)(xpack_ws + 1), 512, 4, 128, inv128, N_NODES, 1};
        GemmZ g2{nfv + 1, 384, 3, wlin_vT, (float*)(xpack_ws + 2), 512, 4, 128, inv128, N_NODES, 1};
        GemmZ g3{nfv + 2, 384, 3, wlin_vT, (float*)(xpack_ws + 3), 512, 4, 128, inv128, N_NODES, 1};
        k_gemm<<<dim3(157, 1, 4), 256, 0, stream>>>(g0, g1, g2, g3);
    }

    hipMemsetAsync(msgs_ws, 0, 56320000, stream);  // msg_s + msg_v
    hipMemsetAsync(cnt_ws, 0, 40960, stream);
    k_hist<<<dim3(625), 256, 0, stream>>>(receivers, cnt_ws);
    k_scan<<<dim3(1), 256, 0, stream>>>(cnt_ws, base_ws, cur_ws);
    k_scatter<<<dim3(625), 256, 0, stream>>>(receivers, cur_ws, order_ws);
    k_edge2<<<dim3(5000), 256, 0, stream>>>(h2_ws, w3T, edge_attrs, senders, receivers, order_ws,
                                            base_ws, xpack_ws, msgs_ws, msgv_ws);

    // out = msg @ W_out -> d_out first half
    {
        GemmZ g0{msgs_ws,       256,  1, wout_sT, dout,           512, 1, 256, scO_s, N_NODES, 0};
        GemmZ g1{msgv_ws + 0,   1152, 1, wout_vT, dout + 128 + 0, 512, 3, 384, scO_v, N_NODES, 0};
        GemmZ g2{msgv_ws + 384, 1152, 1, wout_vT, dout + 128 + 1, 512, 3, 384, scO_v, N_NODES, 0};
        GemmZ g3{msgv_ws + 768, 1152, 1, wout_vT, dout + 128 + 2, 512, 3, 384, scO_v, N_NODES, 0};
        k_gemm<<<dim3(157, 1, 4), 256, 0, stream>>>(g0, g1, g2, g3);
    }
}